// Round 7
// baseline (979.844 us; speedup 1.0000x reference)
//
#include <hip/hip_runtime.h>

#define N_NODES 110000
#define NUM_USER 60000
#define MPAD 110016        // N_NODES padded to 64-row GEMM tiles
#define ZROW N_NODES       // dedicated all-zero row (rows N..MPAD-1 zeroed in init)
#define BSHIFT 9           // bucket = dst >> 9  (512 nodes per bucket)
#define NBUCK 256
#define NPB 512            // nodes per bucket
#define EPB 8192           // edges per block in hist/bin
#define CAP 9216           // per-bucket edge capacity in csr_k LDS

typedef __attribute__((ext_vector_type(8))) __bf16 bf16x8;
typedef __attribute__((ext_vector_type(4))) float f32x4;
typedef __attribute__((ext_vector_type(4))) unsigned int uint4v;

union UB { uint4v u; bf16x8 b; };

__device__ __forceinline__ unsigned short f2b(float f) {   // f32 -> bf16 RNE
    unsigned int u = __float_as_uint(f);
    unsigned int r = (u + 0x7FFFu + ((u >> 16) & 1u)) >> 16;
    return (unsigned short)r;
}
__device__ __forceinline__ float b2f(unsigned short h) {
    return __uint_as_float(((unsigned int)h) << 16);
}

// ---------------- init: weight conv + pad-row zero + acc zero ----------------

__global__ __launch_bounds__(256) void init_k(const float* __restrict__ W1, const float* __restrict__ W2,
        ushort* __restrict__ W1h, ushort* __restrict__ W1l,
        ushort* __restrict__ W2h, ushort* __restrict__ W2l,
        ushort* __restrict__ Tp, float* __restrict__ acc) {
    int b = blockIdx.x, tid = threadIdx.x;
    if (b < 128) {
        const float* W = (b < 64) ? W1 : W2;
        ushort* hi = (b < 64) ? W1h : W2h;
        ushort* lo = (b < 64) ? W1l : W2l;
        int i = (b & 63) * 256 + tid;   // 16384 total
        int k = i >> 7, n = i & 127;
        float w = W[i];
        ushort h = f2b(w);
        hi[(n << 7) | k] = h;
        lo[(n << 7) | k] = f2b(w - b2f(h));
    } else if (b == 128) {
        // zero Tp pad rows in slice-major layout: (s, row N..MPAD-1, c)
        for (int j = tid; j < 8 * (MPAD - N_NODES) * 16; j += 256) {
            int s = j >> 8, r = (j >> 4) & 15, c = j & 15;
            Tp[((size_t)s * MPAD + N_NODES + r) * 16 + c] = 0;
        }
    } else {
        if (tid < 16) acc[tid] = 0.f;
    }
}

// ---------------- bucket-sort CSR build (both domains in one launch) ----------------

__global__ __launch_bounds__(256) void hist_k(const int* __restrict__ adj0, const int* __restrict__ adj1,
        int* __restrict__ tbl, int E, int nbE) {
    __shared__ int h[NBUCK];
    int b = blockIdx.x, tid = threadIdx.x;
    int dom = b / nbE, blk = b - dom * nbE;
    const int* dst = (dom ? adj1 : adj0) + E;
    h[tid] = 0;
    __syncthreads();
    int base = blk * EPB, end = min(base + EPB, E);
    for (int i = base + tid * 4; i + 3 < end; i += 1024) {
        int4 d = *(const int4*)&dst[i];
        atomicAdd(&h[d.x >> BSHIFT], 1); atomicAdd(&h[d.y >> BSHIFT], 1);
        atomicAdd(&h[d.z >> BSHIFT], 1); atomicAdd(&h[d.w >> BSHIFT], 1);
    }
    __syncthreads();
    tbl[((size_t)dom * nbE + blk) * NBUCK + tid] = h[tid];
}

// wave-per-(dom,bucket) scan over nbE blocks: tbl -> exclusive per-block offsets; totals -> bcnt
__global__ __launch_bounds__(256) void scan1_k(int* __restrict__ tbl, int* __restrict__ bcnt, int nbE) {
    int w = threadIdx.x >> 6, lane = threadIdx.x & 63;
    int gw = blockIdx.x * 4 + w;         // 512 waves: dom*256 + bucket
    int dom = gw >> 8, t = gw & 255;
    int carry = 0;
    size_t base = (size_t)dom * nbE * NBUCK + t;
    for (int c = 0; c < nbE; c += 64) {
        int idx = c + lane;
        int v = (idx < nbE) ? tbl[base + (size_t)idx * NBUCK] : 0;
        int s = v;
        #pragma unroll
        for (int o = 1; o < 64; o <<= 1) { int x = __shfl_up(s, o); if (lane >= o) s += x; }
        if (idx < nbE) tbl[base + (size_t)idx * NBUCK] = carry + s - v;
        carry += __shfl(s, 63);
    }
    if (lane == 0) bcnt[dom * NBUCK + t] = carry;
}

__global__ __launch_bounds__(256) void scan2_k(const int* __restrict__ bcnt, int* __restrict__ bbase) {
    __shared__ int sh[NBUCK];
    int t = threadIdx.x;
    for (int dom = 0; dom < 2; dom++) {
        int v = bcnt[dom * NBUCK + t];
        sh[t] = v;
        __syncthreads();
        for (int o = 1; o < NBUCK; o <<= 1) {
            int x = (t >= o) ? sh[t - o] : 0;
            __syncthreads();
            sh[t] += x;
            __syncthreads();
        }
        bbase[dom * NBUCK + t] = sh[t] - v;
        __syncthreads();
    }
}

__global__ __launch_bounds__(256) void bin_k(const int* __restrict__ adj0, const int* __restrict__ adj1,
        const int* __restrict__ tbl, const int* __restrict__ bbase,
        unsigned int* __restrict__ stg, int E, int nbE) {
    __shared__ int lcur[NBUCK];
    int b = blockIdx.x, tid = threadIdx.x;
    int dom = b / nbE, blk = b - dom * nbE;
    const int* src = (dom ? adj1 : adj0);
    const int* dst = src + E;
    unsigned int* sg = stg + (size_t)dom * E;
    lcur[tid] = bbase[dom * NBUCK + tid] + tbl[((size_t)dom * nbE + blk) * NBUCK + tid];
    __syncthreads();
    int base = blk * EPB, end = min(base + EPB, E);
    for (int i = base + tid * 4; i + 3 < end; i += 1024) {
        int4 s = *(const int4*)&src[i];
        int4 d = *(const int4*)&dst[i];
        int p;
        p = atomicAdd(&lcur[d.x >> BSHIFT], 1); sg[p] = (unsigned)s.x | ((unsigned)(d.x & (NPB - 1)) << 17);
        p = atomicAdd(&lcur[d.y >> BSHIFT], 1); sg[p] = (unsigned)s.y | ((unsigned)(d.y & (NPB - 1)) << 17);
        p = atomicAdd(&lcur[d.z >> BSHIFT], 1); sg[p] = (unsigned)s.z | ((unsigned)(d.z & (NPB - 1)) << 17);
        p = atomicAdd(&lcur[d.w >> BSHIFT], 1); sg[p] = (unsigned)s.w | ((unsigned)(d.w & (NPB - 1)) << 17);
    }
}

__global__ __launch_bounds__(256) void csr_k(const unsigned int* __restrict__ stg,
        const int* __restrict__ bbase, const int* __restrict__ bcnt,
        int* __restrict__ deg, float* __restrict__ dinv, int* __restrict__ off,
        int* __restrict__ idxb, int N, int nbB, int E) {
    __shared__ int ldeg[NPB];
    __shared__ int lcur[NPB];
    __shared__ int shp[256];
    __shared__ unsigned int lidx[CAP];
    int b = blockIdx.x, tid = threadIdx.x;
    int dom = b / nbB, blk = b - dom * nbB;
    const unsigned int* sg = stg + (size_t)dom * E;
    int* degd = deg + (size_t)dom * N_NODES;
    float* dinvd = dinv + (size_t)dom * N_NODES;
    int* offd = off + (size_t)dom * N_NODES;
    int* idxd = idxb + (size_t)dom * E;
    int node0 = blk * NPB;
    int base = bbase[dom * NBUCK + blk], cnt = bcnt[dom * NBUCK + blk];
    ldeg[tid] = 0; ldeg[tid + 256] = 0;
    __syncthreads();
    for (int i = tid; i < cnt; i += 256)
        atomicAdd(&ldeg[sg[base + i] >> 17], 1);
    __syncthreads();
    int a0 = ldeg[2 * tid], a1 = ldeg[2 * tid + 1];
    shp[tid] = a0 + a1;
    __syncthreads();
    for (int o = 1; o < 256; o <<= 1) {
        int v = (tid >= o) ? shp[tid - o] : 0;
        __syncthreads();
        shp[tid] += v;
        __syncthreads();
    }
    int excl = shp[tid] - a0 - a1;
    lcur[2 * tid] = excl;
    lcur[2 * tid + 1] = excl + a0;
    int n0 = node0 + 2 * tid;
    if (n0 < N)     { degd[n0] = a0;     dinvd[n0] = rsqrtf(a0 + 1.f);     offd[n0] = base + excl; }
    if (n0 + 1 < N) { degd[n0 + 1] = a1; dinvd[n0 + 1] = rsqrtf(a1 + 1.f); offd[n0 + 1] = base + excl + a0; }
    __syncthreads();
    for (int i = tid; i < cnt; i += 256) {
        unsigned e = sg[base + i];
        int p = atomicAdd(&lcur[e >> 17], 1);
        if (p < CAP) lidx[p] = e & 0x1FFFFu;
    }
    __syncthreads();
    for (int i = tid; i < cnt; i += 256)
        idxd[base + i] = (int)lidx[i];
}

// ---------------- GEMM: T'(slice-major bf16) = dinv[row] * (A @ W), split-bf16 MFMA ----------------
// Tp layout: [slice(8)][node(MPAD)][16 dims]; Fhi/Flo (bf16 hi/lo A operand) same layout.

template<bool F32A>
__global__ __launch_bounds__(256) void mm_k(const float* __restrict__ Xf,
        const ushort* __restrict__ Xhi, const ushort* __restrict__ Xlo,
        const ushort* __restrict__ Whi, const ushort* __restrict__ Wlo,   // [n][k]
        const float* __restrict__ dinv, ushort* __restrict__ Tp, int M) {
    int wid = threadIdx.x >> 6, lane = threadIdx.x & 63;
    int row0 = blockIdx.x * 64 + wid * 16;
    int l15 = lane & 15;
    int rA = row0 + l15;
    int kg = (lane >> 4) * 8;
    f32x4 acc[8] = {};
    #pragma unroll
    for (int g = 0; g < 4; g++) {
        int k0 = g * 32 + kg;
        UB ahi, alo;
        if (F32A) {
            float4 f0 = make_float4(0.f, 0.f, 0.f, 0.f), f1 = f0;
            if (rA < M) {
                f0 = *(const float4*)&Xf[(size_t)rA * 128 + k0];
                f1 = *(const float4*)&Xf[(size_t)rA * 128 + k0 + 4];
            }
            float f[8] = {f0.x, f0.y, f0.z, f0.w, f1.x, f1.y, f1.z, f1.w};
            ushort h[8], l[8];
            #pragma unroll
            for (int j = 0; j < 8; j++) { h[j] = f2b(f[j]); l[j] = f2b(f[j] - b2f(h[j])); }
            ahi.u = uint4v{(uint)h[0] | ((uint)h[1] << 16), (uint)h[2] | ((uint)h[3] << 16),
                           (uint)h[4] | ((uint)h[5] << 16), (uint)h[6] | ((uint)h[7] << 16)};
            alo.u = uint4v{(uint)l[0] | ((uint)l[1] << 16), (uint)l[2] | ((uint)l[3] << 16),
                           (uint)l[4] | ((uint)l[5] << 16), (uint)l[6] | ((uint)l[7] << 16)};
        } else {
            size_t ai = ((size_t)((k0 >> 4) * MPAD + rA) << 4) + (k0 & 15);   // slice-major
            ahi.u = *(const uint4v*)&Xhi[ai];
            alo.u = *(const uint4v*)&Xlo[ai];
        }
        #pragma unroll
        for (int n = 0; n < 8; n++) {
            UB bhi, blo;
            bhi.u = *(const uint4v*)&Whi[(n * 16 + l15) * 128 + k0];
            blo.u = *(const uint4v*)&Wlo[(n * 16 + l15) * 128 + k0];
            acc[n] = __builtin_amdgcn_mfma_f32_16x16x32_bf16(ahi.b, bhi.b, acc[n], 0, 0, 0);
            acc[n] = __builtin_amdgcn_mfma_f32_16x16x32_bf16(ahi.b, blo.b, acc[n], 0, 0, 0);
            acc[n] = __builtin_amdgcn_mfma_f32_16x16x32_bf16(alo.b, bhi.b, acc[n], 0, 0, 0);
        }
    }
    int rbase = row0 + (lane >> 4) * 4;
    #pragma unroll
    for (int r = 0; r < 4; r++) {
        int row = rbase + r;
        if (row < M) {
            float dv = dinv[row];
            #pragma unroll
            for (int n = 0; n < 8; n++)
                Tp[((size_t)n * MPAD + row) * 16 + l15] = f2b(dv * acc[n][r]);   // slice n
        }
    }
}

// ---------------- XCD-sliced aggregate + per-slice head-dot partials ----------------
// block b: slice s = b%8 (round-robin -> XCD s; slice table 3.5 MB fits its L2),
// 16 dsts per block (4 waves x 4 dsts); per dst: 8 edges in flight x 2 lanes x 16 B.

__global__ __launch_bounds__(256) void aggregate_k(const ushort* __restrict__ Tp,
        const int* __restrict__ idxb, const int* __restrict__ off, const int* __restrict__ deg,
        const float* __restrict__ dinv, const float* __restrict__ bias,
        const float* __restrict__ Wp, const float* __restrict__ Wdu, const float* __restrict__ Wdi,
        int loff, float4* __restrict__ ndp,
        ushort* __restrict__ ohi, ushort* __restrict__ olo, int N) {
    int b = blockIdx.x;
    int s = b & 7, dgrp = b >> 3;
    int w = threadIdx.x >> 6, lane = threadIdx.x & 63;
    int g = lane >> 4, li = lane & 15;
    int sub = li >> 1, half = li & 1;
    int d = dgrp * 16 + w * 4 + g;
    unsigned sMP = (unsigned)s * MPAD;
    bool pad = d >= N;
    int o = 0, cnt = 0;
    if (!pad) { o = off[d]; cnt = deg[d] + 1; }   // position 0 = self
    int cmax = max(cnt, __shfl_xor(cnt, 16));
    cmax = max(cmax, __shfl_xor(cmax, 32));
    float aE0 = 0.f, aO0 = 0.f, aE1 = 0.f, aO1 = 0.f;
    float aE2 = 0.f, aO2 = 0.f, aE3 = 0.f, aO3 = 0.f;
    const char* tpb = (const char*)Tp;
    unsigned baseaddr = (sMP << 5) + ((unsigned)half << 4);
    for (int c = 0; c < cmax; c += 8) {
        int p = c + sub;
        int id = ZROW;
        if (p < cnt) id = (p == 0) ? d : idxb[o + p - 1];
        uint4 u = *(const uint4*)(tpb + (baseaddr + ((unsigned)id << 5)));
        aO0 += __uint_as_float(u.x & 0xFFFF0000u); aE0 += __uint_as_float(u.x << 16);
        aO1 += __uint_as_float(u.y & 0xFFFF0000u); aE1 += __uint_as_float(u.y << 16);
        aO2 += __uint_as_float(u.z & 0xFFFF0000u); aE2 += __uint_as_float(u.z << 16);
        aO3 += __uint_as_float(u.w & 0xFFFF0000u); aE3 += __uint_as_float(u.w << 16);
    }
    // reduce across the 8 edge slots (masks preserve half parity)
    #define RED(x) { x += __shfl_xor(x, 2); x += __shfl_xor(x, 4); x += __shfl_xor(x, 8); }
    RED(aE0) RED(aO0) RED(aE1) RED(aO1) RED(aE2) RED(aO2) RED(aE3) RED(aO3)
    #undef RED
    size_t fbase = ((size_t)sMP + (unsigned)d) * 16 + half * 8;
    if (pad) {
        if (li < 2) {
            *(uint4*)&ohi[fbase] = make_uint4(0, 0, 0, 0);
            *(uint4*)&olo[fbase] = make_uint4(0, 0, 0, 0);
        }
        return;
    }
    if (li < 2) {
        int kb = s * 16 + half * 8;
        float di = dinv[d];
        float4 b0 = *(const float4*)&bias[kb];
        float4 b1 = *(const float4*)&bias[kb + 4];
        float f0 = fmaxf(di * aE0 + b0.x, 0.f);
        float f1 = fmaxf(di * aO0 + b0.y, 0.f);
        float f2 = fmaxf(di * aE1 + b0.z, 0.f);
        float f3 = fmaxf(di * aO1 + b0.w, 0.f);
        float f4 = fmaxf(di * aE2 + b1.x, 0.f);
        float f5 = fmaxf(di * aO2 + b1.y, 0.f);
        float f6 = fmaxf(di * aE3 + b1.z, 0.f);
        float f7 = fmaxf(di * aO3 + b1.w, 0.f);
        ushort h0 = f2b(f0), h1 = f2b(f1), h2 = f2b(f2), h3 = f2b(f3);
        ushort h4 = f2b(f4), h5 = f2b(f5), h6 = f2b(f6), h7 = f2b(f7);
        *(uint4*)&ohi[fbase] = make_uint4((uint)h0 | ((uint)h1 << 16), (uint)h2 | ((uint)h3 << 16),
                                          (uint)h4 | ((uint)h5 << 16), (uint)h6 | ((uint)h7 << 16));
        ushort l0 = f2b(f0 - b2f(h0)), l1 = f2b(f1 - b2f(h1));
        ushort l2 = f2b(f2 - b2f(h2)), l3 = f2b(f3 - b2f(h3));
        ushort l4 = f2b(f4 - b2f(h4)), l5 = f2b(f5 - b2f(h5));
        ushort l6 = f2b(f6 - b2f(h6)), l7 = f2b(f7 - b2f(h7));
        *(uint4*)&olo[fbase] = make_uint4((uint)l0 | ((uint)l1 << 16), (uint)l2 | ((uint)l3 << 16),
                                          (uint)l4 | ((uint)l5 << 16), (uint)l6 | ((uint)l7 << 16));
        // per-slice head-dot partials over this half's 8 dims
        float4 w0, w1;
        w0 = *(const float4*)&Wp[loff + kb];        w1 = *(const float4*)&Wp[loff + kb + 4];
        float dt0 = f0*w0.x + f1*w0.y + f2*w0.z + f3*w0.w + f4*w1.x + f5*w1.y + f6*w1.z + f7*w1.w;
        w0 = *(const float4*)&Wp[256 + loff + kb];  w1 = *(const float4*)&Wp[256 + loff + kb + 4];
        float dt1 = f0*w0.x + f1*w0.y + f2*w0.z + f3*w0.w + f4*w1.x + f5*w1.y + f6*w1.z + f7*w1.w;
        w0 = *(const float4*)&Wdu[loff + kb];       w1 = *(const float4*)&Wdu[loff + kb + 4];
        float dt2 = f0*w0.x + f1*w0.y + f2*w0.z + f3*w0.w + f4*w1.x + f5*w1.y + f6*w1.z + f7*w1.w;
        w0 = *(const float4*)&Wdi[loff + kb];       w1 = *(const float4*)&Wdi[loff + kb + 4];
        float dt3 = f0*w0.x + f1*w0.y + f2*w0.z + f3*w0.w + f4*w1.x + f5*w1.y + f6*w1.z + f7*w1.w;
        dt0 += __shfl_xor(dt0, 1); dt1 += __shfl_xor(dt1, 1);
        dt2 += __shfl_xor(dt2, 1); dt3 += __shfl_xor(dt3, 1);
        if (half == 0) ndp[sMP + (unsigned)d] = make_float4(dt0, dt1, dt2, dt3);
    }
}

// sum 8 slice partials -> nd[d]
__global__ __launch_bounds__(256) void ndred_k(const float4* __restrict__ ndp,
                                               float4* __restrict__ nd, int N) {
    int d = blockIdx.x * blockDim.x + threadIdx.x;
    if (d >= N) return;
    float4 a = ndp[d];
    #pragma unroll
    for (int s = 1; s < 8; s++) {
        float4 v = ndp[(size_t)s * MPAD + d];
        a.x += v.x; a.y += v.y; a.z += v.z; a.w += v.w;
    }
    nd[d] = a;
}

// ---------------- loss ----------------

__device__ __forceinline__ float sp100(float z) {   // min(softplus(z),100)
    float sp = (z > 0.f) ? (z + log1pf(expf(-z))) : log1pf(expf(z));
    return fminf(sp, 100.f);
}
__device__ __forceinline__ float wred64(float x) {
    #pragma unroll
    for (int o = 32; o > 0; o >>= 1) x += __shfl_xor(x, o);
    return x;
}

__global__ __launch_bounds__(256) void loss_k(const float4* __restrict__ nd1, const float4* __restrict__ nd2,
        const int* __restrict__ user, const int* __restrict__ item, const int* __restrict__ labels,
        const float* __restrict__ bp, const float* __restrict__ bdu, const float* __restrict__ bdi,
        float* __restrict__ acc, int is_target, int B) {
    __shared__ float sh[3][4];
    int gtid = blockIdx.x * blockDim.x + threadIdx.x;
    int nth = gridDim.x * blockDim.x;
    float bpv = bp[0], bduv = bdu[0], bdiv = bdi[0];
    float lp = 0.f, lu = 0.f, li = 0.f;
    for (int s = gtid; s < B; s += nth) {
        int u = user[s];
        int it = item[s] + NUM_USER;
        float4 a = nd1[u], b = nd2[u], c = nd1[it], dd = nd2[it];
        float zp = a.x + b.x + c.y + dd.y + bpv;
        float zu = a.z + b.z + bduv;
        float zi = c.w + dd.w + bdiv;
        lp += labels[s] ? sp100(-zp) : sp100(zp);
        lu += is_target ? sp100(-zu) : sp100(zu);
        li += is_target ? sp100(-zi) : sp100(zi);
    }
    lp = wred64(lp); lu = wred64(lu); li = wred64(li);
    int lane = threadIdx.x & 63, w = threadIdx.x >> 6;
    if (lane == 0) { sh[0][w] = lp; sh[1][w] = lu; sh[2][w] = li; }
    __syncthreads();
    if (threadIdx.x == 0) {
        float s0 = 0.f, s1 = 0.f, s2 = 0.f;
        for (int j = 0; j < 4; j++) { s0 += sh[0][j]; s1 += sh[1][j]; s2 += sh[2][j]; }
        atomicAdd(&acc[is_target ? 1 : 0], s0);
        atomicAdd(&acc[2], s1);
        atomicAdd(&acc[3], s2);
    }
}

__global__ void fin_k(const float* __restrict__ acc, float* __restrict__ out, int B) {
    float invB = 1.f / (float)B;
    out[0] = acc[0] * invB + acc[1] * invB + 0.1f * ((acc[2] + acc[3]) * (0.5f * invB));
}

// ---------------- orchestration ----------------

extern "C" void kernel_launch(void* const* d_in, const int* in_sizes, int n_in,
                              void* d_out, int out_size, void* d_ws, size_t ws_size,
                              hipStream_t stream) {
    const float* feats[2] = {(const float*)d_in[0], (const float*)d_in[1]};
    const int* adj[2]    = {(const int*)d_in[2], (const int*)d_in[3]};
    const int* user[2]   = {(const int*)d_in[4], (const int*)d_in[7]};
    const int* item[2]   = {(const int*)d_in[5], (const int*)d_in[8]};
    const int* labels[2] = {(const int*)d_in[6], (const int*)d_in[9]};
    const float* Wl[2] = {(const float*)d_in[10], (const float*)d_in[12]};
    const float* bl[2] = {(const float*)d_in[11], (const float*)d_in[13]};
    const float* Wp  = (const float*)d_in[14];
    const float* bp  = (const float*)d_in[15];
    const float* Wdu = (const float*)d_in[16];
    const float* bdu = (const float*)d_in[17];
    const float* Wdi = (const float*)d_in[18];
    const float* bdi = (const float*)d_in[19];

    const int E = in_sizes[2] / 2;
    const int B = in_sizes[4];
    const int N = N_NODES;

    char* w = (char*)d_ws;
    ushort* Tp   = (ushort*)w; w += (size_t)MPAD * 128 * 2;   // slice-major
    ushort* Fhi  = (ushort*)w; w += (size_t)MPAD * 128 * 2;   // slice-major
    ushort* Flo  = (ushort*)w; w += (size_t)MPAD * 128 * 2;
    ushort* W1h  = (ushort*)w; w += 16384 * 2;
    ushort* W1l  = (ushort*)w; w += 16384 * 2;
    ushort* W2h  = (ushort*)w; w += 16384 * 2;
    ushort* W2l  = (ushort*)w; w += 16384 * 2;
    float4* ndp  = (float4*)w; w += (size_t)8 * MPAD * 16;
    float4* nd1  = (float4*)w; w += (size_t)MPAD * 16;
    float4* nd2  = (float4*)w; w += (size_t)MPAD * 16;
    int*   deg  = (int*)w;   w += (size_t)2 * N * 4;
    float* dinv = (float*)w; w += (size_t)2 * N * 4;
    int*   off  = (int*)w;   w += (size_t)2 * N * 4;
    int*   idxb = (int*)w;   w += (size_t)2 * E * 4;
    unsigned int* stg = (unsigned int*)w; w += (size_t)2 * E * 4;
    int*   tbl  = (int*)w;   w += (size_t)2 * 256 * NBUCK * 4;
    int*   bbase = (int*)w;  w += 2 * NBUCK * 4;
    int*   bcnt  = (int*)w;  w += 2 * NBUCK * 4;
    float* acc  = (float*)w; w += 64;

    int nbE = (E + EPB - 1) / EPB;
    int nbB = (N + NPB - 1) / NPB;
    int gMM = MPAD / 64;
    int gAG = 8 * (MPAD / 16);

    init_k<<<130, 256, 0, stream>>>(Wl[0], Wl[1], W1h, W1l, W2h, W2l, Tp, acc);

    // CSR build, both domains merged
    hist_k<<<2 * nbE, 256, 0, stream>>>(adj[0], adj[1], tbl, E, nbE);
    scan1_k<<<128, 256, 0, stream>>>(tbl, bcnt, nbE);
    scan2_k<<<1, 256, 0, stream>>>(bcnt, bbase);
    bin_k<<<2 * nbE, 256, 0, stream>>>(adj[0], adj[1], tbl, bbase, stg, E, nbE);
    csr_k<<<2 * nbB, 256, 0, stream>>>(stg, bbase, bcnt, deg, dinv, off, idxb, N, nbB, E);

    for (int dom = 0; dom < 2; dom++) {
        const int* idxd = idxb + (size_t)dom * E;
        const int* offd = off + (size_t)dom * N;
        const int* degd = deg + (size_t)dom * N;
        const float* dinvd = dinv + (size_t)dom * N;

        // layer 1 (f32 input feats, split in-register)
        mm_k<true><<<gMM, 256, 0, stream>>>(feats[dom], nullptr, nullptr, W1h, W1l, dinvd, Tp, N);
        aggregate_k<<<gAG, 256, 0, stream>>>(Tp, idxd, offd, degd, dinvd, bl[0],
                                             Wp, Wdu, Wdi, 0, ndp, Fhi, Flo, N);
        ndred_k<<<(N + 255) / 256, 256, 0, stream>>>(ndp, nd1, N);

        // layer 2 (bf16 hi/lo slice-major input)
        mm_k<false><<<gMM, 256, 0, stream>>>(nullptr, Fhi, Flo, W2h, W2l, dinvd, Tp, N);
        aggregate_k<<<gAG, 256, 0, stream>>>(Tp, idxd, offd, degd, dinvd, bl[1],
                                             Wp, Wdu, Wdi, 128, ndp, Fhi, Flo, N);
        ndred_k<<<(N + 255) / 256, 256, 0, stream>>>(ndp, nd2, N);

        loss_k<<<128, 256, 0, stream>>>(nd1, nd2, user[dom], item[dom], labels[dom],
                                        bp, bdu, bdi, acc, dom, B);
    }
    fin_k<<<1, 1, 0, stream>>>(acc, (float*)d_out, B);
}

// Round 8
// 674.786 us; speedup vs baseline: 1.4521x; 1.4521x over previous
//
#include <hip/hip_runtime.h>

#define N_NODES 110000
#define NUM_USER 60000
#define MPAD 110016        // N_NODES padded to 64-row GEMM tiles
#define ZROW N_NODES       // dedicated all-zero row (rows N..MPAD-1 zeroed in init)
#define BSHIFT 9           // bucket = dst >> 9  (512 nodes per bucket)
#define NBUCK 256
#define NPB 512            // nodes per bucket
#define EPB 8192           // edges per block in hist/bin
#define CAP 9216           // per-bucket edge capacity in csr_k LDS

typedef __attribute__((ext_vector_type(8))) __bf16 bf16x8;
typedef __attribute__((ext_vector_type(4))) float f32x4;
typedef __attribute__((ext_vector_type(4))) unsigned int uint4v;

union UB { uint4v u; bf16x8 b; };

__device__ __forceinline__ unsigned short f2b(float f) {   // f32 -> bf16 RNE
    unsigned int u = __float_as_uint(f);
    unsigned int r = (u + 0x7FFFu + ((u >> 16) & 1u)) >> 16;
    return (unsigned short)r;
}
__device__ __forceinline__ float b2f(unsigned short h) {
    return __uint_as_float(((unsigned int)h) << 16);
}

// ---------------- init: weight conv + pad-row zero + acc zero ----------------

__global__ __launch_bounds__(256) void init_k(const float* __restrict__ W1, const float* __restrict__ W2,
        ushort* __restrict__ W1h, ushort* __restrict__ W1l,
        ushort* __restrict__ W2h, ushort* __restrict__ W2l,
        ushort* __restrict__ Tp, float* __restrict__ acc) {
    int b = blockIdx.x, tid = threadIdx.x;
    if (b < 128) {
        const float* W = (b < 64) ? W1 : W2;
        ushort* hi = (b < 64) ? W1h : W2h;
        ushort* lo = (b < 64) ? W1l : W2l;
        int i = (b & 63) * 256 + tid;   // 16384 total
        int k = i >> 7, n = i & 127;
        float w = W[i];
        ushort h = f2b(w);
        hi[(n << 7) | k] = h;
        lo[(n << 7) | k] = f2b(w - b2f(h));
    } else if (b == 128) {
        // zero Tp pad rows (row-major): rows N..MPAD-1, 128 dims
        for (int j = tid; j < (MPAD - N_NODES) * 128; j += 256)
            Tp[(size_t)N_NODES * 128 + j] = 0;
    } else {
        if (tid < 16) acc[tid] = 0.f;
    }
}

// ---------------- bucket-sort CSR build (both domains in one launch) ----------------

__global__ __launch_bounds__(256) void hist_k(const int* __restrict__ adj0, const int* __restrict__ adj1,
        int* __restrict__ tbl, int E, int nbE) {
    __shared__ int h[NBUCK];
    int b = blockIdx.x, tid = threadIdx.x;
    int dom = b / nbE, blk = b - dom * nbE;
    const int* dst = (dom ? adj1 : adj0) + E;
    h[tid] = 0;
    __syncthreads();
    int base = blk * EPB, end = min(base + EPB, E);
    for (int i = base + tid * 4; i + 3 < end; i += 1024) {
        int4 d = *(const int4*)&dst[i];
        atomicAdd(&h[d.x >> BSHIFT], 1); atomicAdd(&h[d.y >> BSHIFT], 1);
        atomicAdd(&h[d.z >> BSHIFT], 1); atomicAdd(&h[d.w >> BSHIFT], 1);
    }
    __syncthreads();
    tbl[((size_t)b) * NBUCK + tid] = h[tid];
}

// wave-per-(dom,bucket) scan over nbE blocks
__global__ __launch_bounds__(256) void scan1_k(int* __restrict__ tbl, int* __restrict__ bcnt, int nbE) {
    int w = threadIdx.x >> 6, lane = threadIdx.x & 63;
    int gw = blockIdx.x * 4 + w;         // 512 waves: dom*256 + bucket
    int dom = gw >> 8, t = gw & 255;
    int carry = 0;
    size_t base = (size_t)dom * nbE * NBUCK + t;
    for (int c = 0; c < nbE; c += 64) {
        int idx = c + lane;
        int v = (idx < nbE) ? tbl[base + (size_t)idx * NBUCK] : 0;
        int s = v;
        #pragma unroll
        for (int o = 1; o < 64; o <<= 1) { int x = __shfl_up(s, o); if (lane >= o) s += x; }
        if (idx < nbE) tbl[base + (size_t)idx * NBUCK] = carry + s - v;
        carry += __shfl(s, 63);
    }
    if (lane == 0) bcnt[dom * NBUCK + t] = carry;
}

__global__ __launch_bounds__(256) void scan2_k(const int* __restrict__ bcnt, int* __restrict__ bbase) {
    __shared__ int sh[NBUCK];
    int t = threadIdx.x;
    for (int dom = 0; dom < 2; dom++) {
        int v = bcnt[dom * NBUCK + t];
        sh[t] = v;
        __syncthreads();
        for (int o = 1; o < NBUCK; o <<= 1) {
            int x = (t >= o) ? sh[t - o] : 0;
            __syncthreads();
            sh[t] += x;
            __syncthreads();
        }
        bbase[dom * NBUCK + t] = sh[t] - v;
        __syncthreads();
    }
}

__global__ __launch_bounds__(256) void bin_k(const int* __restrict__ adj0, const int* __restrict__ adj1,
        const int* __restrict__ tbl, const int* __restrict__ bbase,
        unsigned int* __restrict__ stg, int E, int nbE) {
    __shared__ int lcur[NBUCK];
    int b = blockIdx.x, tid = threadIdx.x;
    int dom = b / nbE, blk = b - dom * nbE;
    const int* src = (dom ? adj1 : adj0);
    const int* dst = src + E;
    unsigned int* sg = stg + (size_t)dom * E;
    lcur[tid] = bbase[dom * NBUCK + tid] + tbl[((size_t)b) * NBUCK + tid];
    __syncthreads();
    int base = blk * EPB, end = min(base + EPB, E);
    for (int i = base + tid * 4; i + 3 < end; i += 1024) {
        int4 s = *(const int4*)&src[i];
        int4 d = *(const int4*)&dst[i];
        int p;
        p = atomicAdd(&lcur[d.x >> BSHIFT], 1); sg[p] = (unsigned)s.x | ((unsigned)(d.x & (NPB - 1)) << 17);
        p = atomicAdd(&lcur[d.y >> BSHIFT], 1); sg[p] = (unsigned)s.y | ((unsigned)(d.y & (NPB - 1)) << 17);
        p = atomicAdd(&lcur[d.z >> BSHIFT], 1); sg[p] = (unsigned)s.z | ((unsigned)(d.z & (NPB - 1)) << 17);
        p = atomicAdd(&lcur[d.w >> BSHIFT], 1); sg[p] = (unsigned)s.w | ((unsigned)(d.w & (NPB - 1)) << 17);
    }
}

__global__ __launch_bounds__(256) void csr_k(const unsigned int* __restrict__ stg,
        const int* __restrict__ bbase, const int* __restrict__ bcnt,
        int* __restrict__ deg, float* __restrict__ dinv, int* __restrict__ off,
        int* __restrict__ idxb, int N, int nbB, int E) {
    __shared__ int ldeg[NPB];
    __shared__ int lcur[NPB];
    __shared__ int shp[256];
    __shared__ unsigned int lidx[CAP];
    int b = blockIdx.x, tid = threadIdx.x;
    int dom = b / nbB, blk = b - dom * nbB;
    const unsigned int* sg = stg + (size_t)dom * E;
    int* degd = deg + (size_t)dom * N_NODES;
    float* dinvd = dinv + (size_t)dom * N_NODES;
    int* offd = off + (size_t)dom * N_NODES;
    int* idxd = idxb + (size_t)dom * E;
    int node0 = blk * NPB;
    int base = bbase[dom * NBUCK + blk], cnt = bcnt[dom * NBUCK + blk];
    ldeg[tid] = 0; ldeg[tid + 256] = 0;
    __syncthreads();
    for (int i = tid; i < cnt; i += 256)
        atomicAdd(&ldeg[sg[base + i] >> 17], 1);
    __syncthreads();
    int a0 = ldeg[2 * tid], a1 = ldeg[2 * tid + 1];
    shp[tid] = a0 + a1;
    __syncthreads();
    for (int o = 1; o < 256; o <<= 1) {
        int v = (tid >= o) ? shp[tid - o] : 0;
        __syncthreads();
        shp[tid] += v;
        __syncthreads();
    }
    int excl = shp[tid] - a0 - a1;
    lcur[2 * tid] = excl;
    lcur[2 * tid + 1] = excl + a0;
    int n0 = node0 + 2 * tid;
    if (n0 < N)     { degd[n0] = a0;     dinvd[n0] = rsqrtf(a0 + 1.f);     offd[n0] = base + excl; }
    if (n0 + 1 < N) { degd[n0 + 1] = a1; dinvd[n0 + 1] = rsqrtf(a1 + 1.f); offd[n0 + 1] = base + excl + a0; }
    __syncthreads();
    for (int i = tid; i < cnt; i += 256) {
        unsigned e = sg[base + i];
        int p = atomicAdd(&lcur[e >> 17], 1);
        if (p < CAP) lidx[p] = e & 0x1FFFFu;
    }
    __syncthreads();
    for (int i = tid; i < cnt; i += 256)
        idxd[base + i] = (int)lidx[i];
}

// ---------------- GEMM: T'(bf16, Mx128 row-major) = dinv[row] * (A @ W), split-bf16 MFMA ----------

template<bool F32A>
__global__ __launch_bounds__(256) void mm_k(const float* __restrict__ Xf,
        const ushort* __restrict__ Xhi, const ushort* __restrict__ Xlo,
        const ushort* __restrict__ Whi, const ushort* __restrict__ Wlo,   // [n][k]
        const float* __restrict__ dinv, ushort* __restrict__ Tp, int M) {
    int wid = threadIdx.x >> 6, lane = threadIdx.x & 63;
    int row0 = blockIdx.x * 64 + wid * 16;
    int l15 = lane & 15;
    int rA = row0 + l15;
    int kg = (lane >> 4) * 8;
    f32x4 acc[8] = {};
    #pragma unroll
    for (int g = 0; g < 4; g++) {
        int k0 = g * 32 + kg;
        UB ahi, alo;
        if (F32A) {
            float4 f0 = make_float4(0.f, 0.f, 0.f, 0.f), f1 = f0;
            if (rA < M) {
                f0 = *(const float4*)&Xf[(size_t)rA * 128 + k0];
                f1 = *(const float4*)&Xf[(size_t)rA * 128 + k0 + 4];
            }
            float f[8] = {f0.x, f0.y, f0.z, f0.w, f1.x, f1.y, f1.z, f1.w};
            ushort h[8], l[8];
            #pragma unroll
            for (int j = 0; j < 8; j++) { h[j] = f2b(f[j]); l[j] = f2b(f[j] - b2f(h[j])); }
            ahi.u = uint4v{(uint)h[0] | ((uint)h[1] << 16), (uint)h[2] | ((uint)h[3] << 16),
                           (uint)h[4] | ((uint)h[5] << 16), (uint)h[6] | ((uint)h[7] << 16)};
            alo.u = uint4v{(uint)l[0] | ((uint)l[1] << 16), (uint)l[2] | ((uint)l[3] << 16),
                           (uint)l[4] | ((uint)l[5] << 16), (uint)l[6] | ((uint)l[7] << 16)};
        } else {
            ahi.u = *(const uint4v*)&Xhi[(size_t)rA * 128 + k0];
            alo.u = *(const uint4v*)&Xlo[(size_t)rA * 128 + k0];
        }
        #pragma unroll
        for (int n = 0; n < 8; n++) {
            UB bhi, blo;
            bhi.u = *(const uint4v*)&Whi[(n * 16 + l15) * 128 + k0];
            blo.u = *(const uint4v*)&Wlo[(n * 16 + l15) * 128 + k0];
            acc[n] = __builtin_amdgcn_mfma_f32_16x16x32_bf16(ahi.b, bhi.b, acc[n], 0, 0, 0);
            acc[n] = __builtin_amdgcn_mfma_f32_16x16x32_bf16(ahi.b, blo.b, acc[n], 0, 0, 0);
            acc[n] = __builtin_amdgcn_mfma_f32_16x16x32_bf16(alo.b, bhi.b, acc[n], 0, 0, 0);
        }
    }
    int rbase = row0 + (lane >> 4) * 4;
    #pragma unroll
    for (int r = 0; r < 4; r++) {
        int row = rbase + r;
        if (row < M) {
            float dv = dinv[row];
            #pragma unroll
            for (int n = 0; n < 8; n++)
                Tp[(size_t)row * 128 + n * 16 + l15] = f2b(dv * acc[n][r]);
        }
    }
}

// ---------------- aggregate + fused per-node head dots (R6 structure) ----------------
// One wave per dst node. 16 lanes per edge (4 edges in flight); lane holds 16 B (8 dims).
// out[d] = relu(b + dinv[d]*(T'[d] + sum T'[src])), hi/lo split; nd[d*4+g] = head dot g.

__global__ __launch_bounds__(256) void aggregate_k(const ushort* __restrict__ Tp,
        const int* __restrict__ idxb, const int* __restrict__ off, const int* __restrict__ deg,
        const float* __restrict__ dinv, const float* __restrict__ bias,
        const float* __restrict__ Wp, const float* __restrict__ Wdu, const float* __restrict__ Wdi,
        int loff,   // 0 for layer 1, 128 for layer 2
        float* __restrict__ nd,
        ushort* __restrict__ ohi, ushort* __restrict__ olo, int N) {
    int w = threadIdx.x >> 6, lane = threadIdx.x & 63;
    int d = blockIdx.x * 4 + w;
    int grp = lane >> 4, li = lane & 15;
    int db = li * 8;   // first dim this lane owns
    if (d >= N) {   // pad rows for GEMM tiles: keep zeroed
        if (grp == 0) *(uint4*)&ohi[(size_t)d * 128 + db] = make_uint4(0, 0, 0, 0);
        if (grp == 1) *(uint4*)&olo[(size_t)d * 128 + db] = make_uint4(0, 0, 0, 0);
        return;
    }
    float aE0 = 0.f, aO0 = 0.f, aE1 = 0.f, aO1 = 0.f;
    float aE2 = 0.f, aO2 = 0.f, aE3 = 0.f, aO3 = 0.f;
    int o = off[d];
    int cnt = deg[d] + 1;   // position 0 = self
    const unsigned char* tpb = (const unsigned char*)Tp;
    unsigned int laneoff = (unsigned int)(li << 4);
    for (int c = 0; c < cnt; c += 64) {
        int p = c + lane;
        int id = ZROW;
        if (p < cnt) id = (p == 0) ? d : idxb[o + p - 1];
        int m = min(64, cnt - c);
        #pragma unroll 4
        for (int jj = 0; jj * 4 < m; jj++) {
            int s = __shfl(id, jj * 4 + grp);
            uint4 u = *(const uint4*)(tpb + (((unsigned int)s << 8) | laneoff));
            aO0 += __uint_as_float(u.x & 0xFFFF0000u); aE0 += __uint_as_float(u.x << 16);
            aO1 += __uint_as_float(u.y & 0xFFFF0000u); aE1 += __uint_as_float(u.y << 16);
            aO2 += __uint_as_float(u.z & 0xFFFF0000u); aE2 += __uint_as_float(u.z << 16);
            aO3 += __uint_as_float(u.w & 0xFFFF0000u); aE3 += __uint_as_float(u.w << 16);
        }
    }
    // cross-group reduce: all 4 groups end with identical sums for dims db..db+7
    #define RED2(x) { x += __shfl_xor(x, 16); x += __shfl_xor(x, 32); }
    RED2(aE0) RED2(aO0) RED2(aE1) RED2(aO1)
    RED2(aE2) RED2(aO2) RED2(aE3) RED2(aO3)
    #undef RED2
    float di = dinv[d];
    float4 b0 = *(const float4*)&bias[db];
    float4 b1 = *(const float4*)&bias[db + 4];
    float f0 = fmaxf(di * aE0 + b0.x, 0.f);
    float f1 = fmaxf(di * aO0 + b0.y, 0.f);
    float f2 = fmaxf(di * aE1 + b0.z, 0.f);
    float f3 = fmaxf(di * aO1 + b0.w, 0.f);
    float f4 = fmaxf(di * aE2 + b1.x, 0.f);
    float f5 = fmaxf(di * aO2 + b1.y, 0.f);
    float f6 = fmaxf(di * aE3 + b1.z, 0.f);
    float f7 = fmaxf(di * aO3 + b1.w, 0.f);
    if (grp < 2) {
        ushort h0 = f2b(f0), h1 = f2b(f1), h2 = f2b(f2), h3 = f2b(f3);
        ushort h4 = f2b(f4), h5 = f2b(f5), h6 = f2b(f6), h7 = f2b(f7);
        if (grp == 0) {
            uint4 hv = make_uint4((uint)h0 | ((uint)h1 << 16), (uint)h2 | ((uint)h3 << 16),
                                  (uint)h4 | ((uint)h5 << 16), (uint)h6 | ((uint)h7 << 16));
            *(uint4*)&ohi[(size_t)d * 128 + db] = hv;
        } else {
            ushort l0 = f2b(f0 - b2f(h0)), l1 = f2b(f1 - b2f(h1));
            ushort l2 = f2b(f2 - b2f(h2)), l3 = f2b(f3 - b2f(h3));
            ushort l4 = f2b(f4 - b2f(h4)), l5 = f2b(f5 - b2f(h5));
            ushort l6 = f2b(f6 - b2f(h6)), l7 = f2b(f7 - b2f(h7));
            uint4 lv = make_uint4((uint)l0 | ((uint)l1 << 16), (uint)l2 | ((uint)l3 << 16),
                                  (uint)l4 | ((uint)l5 << 16), (uint)l6 | ((uint)l7 << 16));
            *(uint4*)&olo[(size_t)d * 128 + db] = lv;
        }
    }
    // head dots: group g computes dot g over the full 128 dims
    const float* wsel = (grp == 0) ? Wp + loff : (grp == 1) ? Wp + 256 + loff
                      : (grp == 2) ? Wdu + loff : Wdi + loff;
    float4 w0 = *(const float4*)&wsel[db];
    float4 w1 = *(const float4*)&wsel[db + 4];
    float dt = f0 * w0.x + f1 * w0.y + f2 * w0.z + f3 * w0.w
             + f4 * w1.x + f5 * w1.y + f6 * w1.z + f7 * w1.w;
    dt += __shfl_xor(dt, 1); dt += __shfl_xor(dt, 2);
    dt += __shfl_xor(dt, 4); dt += __shfl_xor(dt, 8);
    if (li == 0) nd[(size_t)d * 4 + grp] = dt;
}

// ---------------- loss ----------------

__device__ __forceinline__ float sp100(float z) {   // min(softplus(z),100)
    float sp = (z > 0.f) ? (z + log1pf(expf(-z))) : log1pf(expf(z));
    return fminf(sp, 100.f);
}
__device__ __forceinline__ float wred64(float x) {
    #pragma unroll
    for (int o = 32; o > 0; o >>= 1) x += __shfl_xor(x, o);
    return x;
}

__global__ __launch_bounds__(256) void loss_k(const float4* __restrict__ nd1, const float4* __restrict__ nd2,
        const int* __restrict__ user, const int* __restrict__ item, const int* __restrict__ labels,
        const float* __restrict__ bp, const float* __restrict__ bdu, const float* __restrict__ bdi,
        float* __restrict__ acc, int is_target, int B) {
    __shared__ float sh[3][4];
    int gtid = blockIdx.x * blockDim.x + threadIdx.x;
    int nth = gridDim.x * blockDim.x;
    float bpv = bp[0], bduv = bdu[0], bdiv = bdi[0];
    float lp = 0.f, lu = 0.f, li = 0.f;
    for (int s = gtid; s < B; s += nth) {
        int u = user[s];
        int it = item[s] + NUM_USER;
        float4 a = nd1[u], b = nd2[u], c = nd1[it], dd = nd2[it];
        float zp = a.x + b.x + c.y + dd.y + bpv;
        float zu = a.z + b.z + bduv;
        float zi = c.w + dd.w + bdiv;
        lp += labels[s] ? sp100(-zp) : sp100(zp);
        lu += is_target ? sp100(-zu) : sp100(zu);
        li += is_target ? sp100(-zi) : sp100(zi);
    }
    lp = wred64(lp); lu = wred64(lu); li = wred64(li);
    int lane = threadIdx.x & 63, w = threadIdx.x >> 6;
    if (lane == 0) { sh[0][w] = lp; sh[1][w] = lu; sh[2][w] = li; }
    __syncthreads();
    if (threadIdx.x == 0) {
        float s0 = 0.f, s1 = 0.f, s2 = 0.f;
        for (int j = 0; j < 4; j++) { s0 += sh[0][j]; s1 += sh[1][j]; s2 += sh[2][j]; }
        atomicAdd(&acc[is_target ? 1 : 0], s0);
        atomicAdd(&acc[2], s1);
        atomicAdd(&acc[3], s2);
    }
}

__global__ void fin_k(const float* __restrict__ acc, float* __restrict__ out, int B) {
    float invB = 1.f / (float)B;
    out[0] = acc[0] * invB + acc[1] * invB + 0.1f * ((acc[2] + acc[3]) * (0.5f * invB));
}

// ---------------- orchestration ----------------

extern "C" void kernel_launch(void* const* d_in, const int* in_sizes, int n_in,
                              void* d_out, int out_size, void* d_ws, size_t ws_size,
                              hipStream_t stream) {
    const float* feats[2] = {(const float*)d_in[0], (const float*)d_in[1]};
    const int* adj[2]    = {(const int*)d_in[2], (const int*)d_in[3]};
    const int* user[2]   = {(const int*)d_in[4], (const int*)d_in[7]};
    const int* item[2]   = {(const int*)d_in[5], (const int*)d_in[8]};
    const int* labels[2] = {(const int*)d_in[6], (const int*)d_in[9]};
    const float* Wl[2] = {(const float*)d_in[10], (const float*)d_in[12]};
    const float* bl[2] = {(const float*)d_in[11], (const float*)d_in[13]};
    const float* Wp  = (const float*)d_in[14];
    const float* bp  = (const float*)d_in[15];
    const float* Wdu = (const float*)d_in[16];
    const float* bdu = (const float*)d_in[17];
    const float* Wdi = (const float*)d_in[18];
    const float* bdi = (const float*)d_in[19];

    const int E = in_sizes[2] / 2;
    const int B = in_sizes[4];
    const int N = N_NODES;

    char* w = (char*)d_ws;
    ushort* Tp   = (ushort*)w; w += (size_t)MPAD * 128 * 2;
    ushort* Fhi  = (ushort*)w; w += (size_t)MPAD * 128 * 2;
    ushort* Flo  = (ushort*)w; w += (size_t)MPAD * 128 * 2;
    ushort* W1h  = (ushort*)w; w += 16384 * 2;
    ushort* W1l  = (ushort*)w; w += 16384 * 2;
    ushort* W2h  = (ushort*)w; w += 16384 * 2;
    ushort* W2l  = (ushort*)w; w += 16384 * 2;
    float* nd1  = (float*)w; w += (size_t)MPAD * 16;
    float* nd2  = (float*)w; w += (size_t)MPAD * 16;
    int*   deg  = (int*)w;   w += (size_t)2 * N * 4;
    float* dinv = (float*)w; w += (size_t)2 * N * 4;
    int*   off  = (int*)w;   w += (size_t)2 * N * 4;
    int*   idxb = (int*)w;   w += (size_t)2 * E * 4;
    unsigned int* stg = (unsigned int*)w; w += (size_t)2 * E * 4;
    int*   tbl  = (int*)w;   w += (size_t)2 * 256 * NBUCK * 4;
    int*   bbase = (int*)w;  w += 2 * NBUCK * 4;
    int*   bcnt  = (int*)w;  w += 2 * NBUCK * 4;
    float* acc  = (float*)w; w += 64;

    int nbE = (E + EPB - 1) / EPB;
    int nbB = (N + NPB - 1) / NPB;
    int gMM = MPAD / 64;
    int gAG = MPAD / 4;

    init_k<<<130, 256, 0, stream>>>(Wl[0], Wl[1], W1h, W1l, W2h, W2l, Tp, acc);

    // CSR build, both domains merged
    hist_k<<<2 * nbE, 256, 0, stream>>>(adj[0], adj[1], tbl, E, nbE);
    scan1_k<<<128, 256, 0, stream>>>(tbl, bcnt, nbE);
    scan2_k<<<1, 256, 0, stream>>>(bcnt, bbase);
    bin_k<<<2 * nbE, 256, 0, stream>>>(adj[0], adj[1], tbl, bbase, stg, E, nbE);
    csr_k<<<2 * nbB, 256, 0, stream>>>(stg, bbase, bcnt, deg, dinv, off, idxb, N, nbB, E);

    for (int dom = 0; dom < 2; dom++) {
        const int* idxd = idxb + (size_t)dom * E;
        const int* offd = off + (size_t)dom * N;
        const int* degd = deg + (size_t)dom * N;
        const float* dinvd = dinv + (size_t)dom * N;

        // layer 1 (f32 input feats, split in-register)
        mm_k<true><<<gMM, 256, 0, stream>>>(feats[dom], nullptr, nullptr, W1h, W1l, dinvd, Tp, N);
        aggregate_k<<<gAG, 256, 0, stream>>>(Tp, idxd, offd, degd, dinvd, bl[0],
                                             Wp, Wdu, Wdi, 0, nd1, Fhi, Flo, N);

        // layer 2 (bf16 hi/lo input)
        mm_k<false><<<gMM, 256, 0, stream>>>(nullptr, Fhi, Flo, W2h, W2l, dinvd, Tp, N);
        aggregate_k<<<gAG, 256, 0, stream>>>(Tp, idxd, offd, degd, dinvd, bl[1],
                                             Wp, Wdu, Wdi, 128, nd2, Fhi, Flo, N);

        loss_k<<<128, 256, 0, stream>>>((const float4*)nd1, (const float4*)nd2,
                                        user[dom], item[dom], labels[dom],
                                        bp, bdu, bdi, acc, dom, B);
    }
    fin_k<<<1, 1, 0, stream>>>(acc, (float*)d_out, B);
}

// Round 10
// 593.780 us; speedup vs baseline: 1.6502x; 1.1364x over previous
//
#include <hip/hip_runtime.h>

#define N_NODES 110000
#define NUM_USER 60000
#define MPAD 110016        // N_NODES padded to 64-row GEMM tiles
#define ZROW N_NODES       // dedicated all-zero row (rows N..MPAD-1 zeroed in init)
#define BSHIFT 9           // bucket = dst >> 9  (512 nodes per bucket)
#define NBUCK 256
#define NPB 512            // nodes per bucket
#define EPB 8192           // edges per block in hist/bin
#define CAP 9216           // per-bucket edge capacity in csr_k LDS

typedef __attribute__((ext_vector_type(8))) __bf16 bf16x8;
typedef __attribute__((ext_vector_type(4))) float f32x4;
typedef __attribute__((ext_vector_type(2))) float f32x2;
typedef __attribute__((ext_vector_type(4))) unsigned int uint4v;

union UB { uint4v u; bf16x8 b; };

__device__ __forceinline__ unsigned short f2b(float f) {   // f32 -> bf16 RNE
    unsigned int u = __float_as_uint(f);
    unsigned int r = (u + 0x7FFFu + ((u >> 16) & 1u)) >> 16;
    return (unsigned short)r;
}
__device__ __forceinline__ float b2f(unsigned short h) {
    return __uint_as_float(((unsigned int)h) << 16);
}
// f32 -> fp8 e4m3 (OCP) RNE via exact 2^-120 scaling trick (handles subnormals)
__device__ __forceinline__ unsigned f2e4m3(float x) {
    unsigned u = __float_as_uint(x * 0x1p-120f);
    unsigned r = u + 0x7FFFFu + ((u >> 20) & 1u);
    return ((r >> 20) & 0x7Fu) | ((u >> 24) & 0x80u);
}
__device__ __forceinline__ float e4m3f(unsigned v) {   // fallback decode
    unsigned bits = ((v & 0x80u) << 24) | ((v & 0x7Fu) << 20);
    return __uint_as_float(bits) * 0x1p+120f;
}

// ---------------- init: weight conv + pad-row zero + acc zero ----------------

__global__ __launch_bounds__(256) void init_k(const float* __restrict__ W1, const float* __restrict__ W2,
        ushort* __restrict__ W1h, ushort* __restrict__ W1l,
        ushort* __restrict__ W2h, ushort* __restrict__ W2l,
        unsigned char* __restrict__ Tp, float* __restrict__ acc) {
    int b = blockIdx.x, tid = threadIdx.x;
    if (b < 128) {
        const float* W = (b < 64) ? W1 : W2;
        ushort* hi = (b < 64) ? W1h : W2h;
        ushort* lo = (b < 64) ? W1l : W2l;
        int i = (b & 63) * 256 + tid;   // 16384 total
        int k = i >> 7, n = i & 127;
        float w = W[i];
        ushort h = f2b(w);
        hi[(n << 7) | k] = h;
        lo[(n << 7) | k] = f2b(w - b2f(h));
    } else if (b == 128) {
        // zero Tp pad rows: rows N..MPAD-1, 128 B each
        for (int j = tid; j < (MPAD - N_NODES) * 128; j += 256)
            Tp[(size_t)N_NODES * 128 + j] = 0;
    } else {
        if (tid < 16) acc[tid] = 0.f;
    }
}

// ---------------- bucket-sort CSR build (both domains in one launch) ----------------

__global__ __launch_bounds__(256) void hist_k(const int* __restrict__ adj0, const int* __restrict__ adj1,
        int* __restrict__ tbl, int E, int nbE) {
    __shared__ int h[NBUCK];
    int b = blockIdx.x, tid = threadIdx.x;
    int dom = b / nbE, blk = b - dom * nbE;
    const int* dst = (dom ? adj1 : adj0) + E;
    h[tid] = 0;
    __syncthreads();
    int base = blk * EPB, end = min(base + EPB, E);
    for (int i = base + tid * 4; i + 3 < end; i += 1024) {
        int4 d = *(const int4*)&dst[i];
        atomicAdd(&h[d.x >> BSHIFT], 1); atomicAdd(&h[d.y >> BSHIFT], 1);
        atomicAdd(&h[d.z >> BSHIFT], 1); atomicAdd(&h[d.w >> BSHIFT], 1);
    }
    __syncthreads();
    tbl[((size_t)b) * NBUCK + tid] = h[tid];
}

__global__ __launch_bounds__(256) void scan1_k(int* __restrict__ tbl, int* __restrict__ bcnt, int nbE) {
    int w = threadIdx.x >> 6, lane = threadIdx.x & 63;
    int gw = blockIdx.x * 4 + w;         // 512 waves: dom*256 + bucket
    int dom = gw >> 8, t = gw & 255;
    int carry = 0;
    size_t base = (size_t)dom * nbE * NBUCK + t;
    for (int c = 0; c < nbE; c += 64) {
        int idx = c + lane;
        int v = (idx < nbE) ? tbl[base + (size_t)idx * NBUCK] : 0;
        int s = v;
        #pragma unroll
        for (int o = 1; o < 64; o <<= 1) { int x = __shfl_up(s, o); if (lane >= o) s += x; }
        if (idx < nbE) tbl[base + (size_t)idx * NBUCK] = carry + s - v;
        carry += __shfl(s, 63);
    }
    if (lane == 0) bcnt[dom * NBUCK + t] = carry;
}

__global__ __launch_bounds__(256) void scan2_k(const int* __restrict__ bcnt, int* __restrict__ bbase) {
    __shared__ int sh[NBUCK];
    int t = threadIdx.x;
    for (int dom = 0; dom < 2; dom++) {
        int v = bcnt[dom * NBUCK + t];
        sh[t] = v;
        __syncthreads();
        for (int o = 1; o < NBUCK; o <<= 1) {
            int x = (t >= o) ? sh[t - o] : 0;
            __syncthreads();
            sh[t] += x;
            __syncthreads();
        }
        bbase[dom * NBUCK + t] = sh[t] - v;
        __syncthreads();
    }
}

__global__ __launch_bounds__(256) void bin_k(const int* __restrict__ adj0, const int* __restrict__ adj1,
        const int* __restrict__ tbl, const int* __restrict__ bbase,
        unsigned int* __restrict__ stg, int E, int nbE) {
    __shared__ int lcur[NBUCK];
    int b = blockIdx.x, tid = threadIdx.x;
    int dom = b / nbE, blk = b - dom * nbE;
    const int* src = (dom ? adj1 : adj0);
    const int* dst = src + E;
    unsigned int* sg = stg + (size_t)dom * E;
    lcur[tid] = bbase[dom * NBUCK + tid] + tbl[((size_t)b) * NBUCK + tid];
    __syncthreads();
    int base = blk * EPB, end = min(base + EPB, E);
    for (int i = base + tid * 4; i + 3 < end; i += 1024) {
        int4 s = *(const int4*)&src[i];
        int4 d = *(const int4*)&dst[i];
        int p;
        p = atomicAdd(&lcur[d.x >> BSHIFT], 1); sg[p] = (unsigned)s.x | ((unsigned)(d.x & (NPB - 1)) << 17);
        p = atomicAdd(&lcur[d.y >> BSHIFT], 1); sg[p] = (unsigned)s.y | ((unsigned)(d.y & (NPB - 1)) << 17);
        p = atomicAdd(&lcur[d.z >> BSHIFT], 1); sg[p] = (unsigned)s.z | ((unsigned)(d.z & (NPB - 1)) << 17);
        p = atomicAdd(&lcur[d.w >> BSHIFT], 1); sg[p] = (unsigned)s.w | ((unsigned)(d.w & (NPB - 1)) << 17);
    }
}

__global__ __launch_bounds__(256) void csr_k(const unsigned int* __restrict__ stg,
        const int* __restrict__ bbase, const int* __restrict__ bcnt,
        int* __restrict__ deg, float* __restrict__ dinv, int* __restrict__ off,
        int* __restrict__ idxb, int N, int nbB, int E) {
    __shared__ int ldeg[NPB];
    __shared__ int lcur[NPB];
    __shared__ int shp[256];
    __shared__ unsigned int lidx[CAP];
    int b = blockIdx.x, tid = threadIdx.x;
    int dom = b / nbB, blk = b - dom * nbB;
    const unsigned int* sg = stg + (size_t)dom * E;
    int* degd = deg + (size_t)dom * N_NODES;
    float* dinvd = dinv + (size_t)dom * N_NODES;
    int* offd = off + (size_t)dom * N_NODES;
    int* idxd = idxb + (size_t)dom * E;
    int node0 = blk * NPB;
    int base = bbase[dom * NBUCK + blk], cnt = bcnt[dom * NBUCK + blk];
    ldeg[tid] = 0; ldeg[tid + 256] = 0;
    __syncthreads();
    for (int i = tid; i < cnt; i += 256)
        atomicAdd(&ldeg[sg[base + i] >> 17], 1);
    __syncthreads();
    int a0 = ldeg[2 * tid], a1 = ldeg[2 * tid + 1];
    shp[tid] = a0 + a1;
    __syncthreads();
    for (int o = 1; o < 256; o <<= 1) {
        int v = (tid >= o) ? shp[tid - o] : 0;
        __syncthreads();
        shp[tid] += v;
        __syncthreads();
    }
    int excl = shp[tid] - a0 - a1;
    lcur[2 * tid] = excl;
    lcur[2 * tid + 1] = excl + a0;
    int n0 = node0 + 2 * tid;
    if (n0 < N)     { degd[n0] = a0;     dinvd[n0] = rsqrtf(a0 + 1.f);     offd[n0] = base + excl; }
    if (n0 + 1 < N) { degd[n0 + 1] = a1; dinvd[n0 + 1] = rsqrtf(a1 + 1.f); offd[n0 + 1] = base + excl + a0; }
    __syncthreads();
    for (int i = tid; i < cnt; i += 256) {
        unsigned e = sg[base + i];
        int p = atomicAdd(&lcur[e >> 17], 1);
        if (p < CAP) lidx[p] = e & 0x1FFFFu;
    }
    __syncthreads();
    for (int i = tid; i < cnt; i += 256)
        idxd[base + i] = (int)lidx[i];
}

// ---------------- GEMM: T'(fp8 e4m3, Mx128 row-major) = dinv[row]*(A@W), split-bf16 MFMA -------
// F32A: A = f32 feats, split hi/lo in-register (3 MFMA). else: A = bf16 features Fhi (2 MFMA).

template<bool F32A>
__global__ __launch_bounds__(256) void mm_k(const float* __restrict__ Xf,
        const ushort* __restrict__ Xhi,
        const ushort* __restrict__ Whi, const ushort* __restrict__ Wlo,   // [n][k]
        const float* __restrict__ dinv, unsigned char* __restrict__ Tp, int M) {
    int wid = threadIdx.x >> 6, lane = threadIdx.x & 63;
    int row0 = blockIdx.x * 64 + wid * 16;
    int l15 = lane & 15;
    int rA = row0 + l15;
    int kg = (lane >> 4) * 8;
    f32x4 acc[8] = {};
    #pragma unroll
    for (int g = 0; g < 4; g++) {
        int k0 = g * 32 + kg;
        UB ahi, alo;
        if (F32A) {
            float4 f0 = make_float4(0.f, 0.f, 0.f, 0.f), f1 = f0;
            if (rA < M) {
                f0 = *(const float4*)&Xf[(size_t)rA * 128 + k0];
                f1 = *(const float4*)&Xf[(size_t)rA * 128 + k0 + 4];
            }
            float f[8] = {f0.x, f0.y, f0.z, f0.w, f1.x, f1.y, f1.z, f1.w};
            ushort h[8], l[8];
            #pragma unroll
            for (int j = 0; j < 8; j++) { h[j] = f2b(f[j]); l[j] = f2b(f[j] - b2f(h[j])); }
            ahi.u = uint4v{(uint)h[0] | ((uint)h[1] << 16), (uint)h[2] | ((uint)h[3] << 16),
                           (uint)h[4] | ((uint)h[5] << 16), (uint)h[6] | ((uint)h[7] << 16)};
            alo.u = uint4v{(uint)l[0] | ((uint)l[1] << 16), (uint)l[2] | ((uint)l[3] << 16),
                           (uint)l[4] | ((uint)l[5] << 16), (uint)l[6] | ((uint)l[7] << 16)};
        } else {
            ahi.u = *(const uint4v*)&Xhi[(size_t)rA * 128 + k0];
        }
        #pragma unroll
        for (int n = 0; n < 8; n++) {
            UB bhi, blo;
            bhi.u = *(const uint4v*)&Whi[(n * 16 + l15) * 128 + k0];
            blo.u = *(const uint4v*)&Wlo[(n * 16 + l15) * 128 + k0];
            acc[n] = __builtin_amdgcn_mfma_f32_16x16x32_bf16(ahi.b, bhi.b, acc[n], 0, 0, 0);
            acc[n] = __builtin_amdgcn_mfma_f32_16x16x32_bf16(ahi.b, blo.b, acc[n], 0, 0, 0);
            if (F32A)
                acc[n] = __builtin_amdgcn_mfma_f32_16x16x32_bf16(alo.b, bhi.b, acc[n], 0, 0, 0);
        }
    }
    int rbase = row0 + (lane >> 4) * 4;
    #pragma unroll
    for (int r = 0; r < 4; r++) {
        int row = rbase + r;
        if (row < M) {
            float dv = dinv[row];
            #pragma unroll
            for (int n = 0; n < 8; n++)
                Tp[(size_t)row * 128 + n * 16 + l15] = (unsigned char)f2e4m3(dv * acc[n][r]);
        }
    }
}

// ---------------- aggregate + fused per-node head dots (R6 structure, fp8 gather) -------------
// One wave per dst node. 16 lanes per edge (4 edges in flight); lane holds 8 B = 8 fp8 dims.
// out[d] = relu(b + dinv[d]*(T'[d] + sum T'[src])); STORE_F: write bf16 features for next GEMM.

template<bool STORE_F>
__global__ __launch_bounds__(256) void aggregate_k(const unsigned char* __restrict__ Tp,
        const int* __restrict__ idxb, const int* __restrict__ off, const int* __restrict__ deg,
        const float* __restrict__ dinv, const float* __restrict__ bias,
        const float* __restrict__ Wp, const float* __restrict__ Wdu, const float* __restrict__ Wdi,
        int loff,   // 0 for layer 1, 128 for layer 2
        float* __restrict__ nd, ushort* __restrict__ ohi, int N) {
    int w = threadIdx.x >> 6, lane = threadIdx.x & 63;
    int d = blockIdx.x * 4 + w;
    int grp = lane >> 4, li = lane & 15;
    int db = li * 8;   // first dim this lane owns
    if (d >= N) {   // pad rows for GEMM tiles: keep zeroed
        if (STORE_F && grp == 0) *(uint4*)&ohi[(size_t)d * 128 + db] = make_uint4(0, 0, 0, 0);
        return;
    }
    float a0 = 0.f, a1 = 0.f, a2 = 0.f, a3 = 0.f;
    float a4 = 0.f, a5 = 0.f, a6 = 0.f, a7 = 0.f;
    int o = off[d];
    int cnt = deg[d] + 1;   // position 0 = self
    unsigned laneoff = (unsigned)(li << 3);
    for (int c = 0; c < cnt; c += 64) {
        int p = c + lane;
        int id = ZROW;
        if (p < cnt) id = (p == 0) ? d : idxb[o + p - 1];
        int m = min(64, cnt - c);
        #pragma unroll 4
        for (int jj = 0; jj * 4 < m; jj++) {
            int s = __shfl(id, jj * 4 + grp);
            uint2 u = *(const uint2*)(Tp + (((unsigned)s << 7) | laneoff));
#if __has_builtin(__builtin_amdgcn_cvt_pk_f32_fp8)
            f32x2 p01 = __builtin_amdgcn_cvt_pk_f32_fp8(u.x, false);
            f32x2 p23 = __builtin_amdgcn_cvt_pk_f32_fp8(u.x, true);
            f32x2 p45 = __builtin_amdgcn_cvt_pk_f32_fp8(u.y, false);
            f32x2 p67 = __builtin_amdgcn_cvt_pk_f32_fp8(u.y, true);
            a0 += p01[0]; a1 += p01[1]; a2 += p23[0]; a3 += p23[1];
            a4 += p45[0]; a5 += p45[1]; a6 += p67[0]; a7 += p67[1];
#else
            a0 += e4m3f(u.x & 0xFF);         a1 += e4m3f((u.x >> 8) & 0xFF);
            a2 += e4m3f((u.x >> 16) & 0xFF); a3 += e4m3f(u.x >> 24);
            a4 += e4m3f(u.y & 0xFF);         a5 += e4m3f((u.y >> 8) & 0xFF);
            a6 += e4m3f((u.y >> 16) & 0xFF); a7 += e4m3f(u.y >> 24);
#endif
        }
    }
    // cross-group reduce: all 4 groups end with identical sums for dims db..db+7
    #define RED2(x) { x += __shfl_xor(x, 16); x += __shfl_xor(x, 32); }
    RED2(a0) RED2(a1) RED2(a2) RED2(a3) RED2(a4) RED2(a5) RED2(a6) RED2(a7)
    #undef RED2
    float di = dinv[d];
    float4 b0 = *(const float4*)&bias[db];
    float4 b1 = *(const float4*)&bias[db + 4];
    float f0 = fmaxf(di * a0 + b0.x, 0.f);
    float f1 = fmaxf(di * a1 + b0.y, 0.f);
    float f2 = fmaxf(di * a2 + b0.z, 0.f);
    float f3 = fmaxf(di * a3 + b0.w, 0.f);
    float f4 = fmaxf(di * a4 + b1.x, 0.f);
    float f5 = fmaxf(di * a5 + b1.y, 0.f);
    float f6 = fmaxf(di * a6 + b1.z, 0.f);
    float f7 = fmaxf(di * a7 + b1.w, 0.f);
    if (STORE_F && grp == 0) {
        ushort h0 = f2b(f0), h1 = f2b(f1), h2 = f2b(f2), h3 = f2b(f3);
        ushort h4 = f2b(f4), h5 = f2b(f5), h6 = f2b(f6), h7 = f2b(f7);
        uint4 hv = make_uint4((uint)h0 | ((uint)h1 << 16), (uint)h2 | ((uint)h3 << 16),
                              (uint)h4 | ((uint)h5 << 16), (uint)h6 | ((uint)h7 << 16));
        *(uint4*)&ohi[(size_t)d * 128 + db] = hv;
    }
    // head dots: group g computes dot g over the full 128 dims
    const float* wsel = (grp == 0) ? Wp + loff : (grp == 1) ? Wp + 256 + loff
                      : (grp == 2) ? Wdu + loff : Wdi + loff;
    float4 w0 = *(const float4*)&wsel[db];
    float4 w1 = *(const float4*)&wsel[db + 4];
    float dt = f0 * w0.x + f1 * w0.y + f2 * w0.z + f3 * w0.w
             + f4 * w1.x + f5 * w1.y + f6 * w1.z + f7 * w1.w;
    dt += __shfl_xor(dt, 1); dt += __shfl_xor(dt, 2);
    dt += __shfl_xor(dt, 4); dt += __shfl_xor(dt, 8);
    if (li == 0) nd[(size_t)d * 4 + grp] = dt;
}

// ---------------- loss ----------------

__device__ __forceinline__ float sp100(float z) {   // min(softplus(z),100)
    float sp = (z > 0.f) ? (z + log1pf(expf(-z))) : log1pf(expf(z));
    return fminf(sp, 100.f);
}
__device__ __forceinline__ float wred64(float x) {
    #pragma unroll
    for (int o = 32; o > 0; o >>= 1) x += __shfl_xor(x, o);
    return x;
}

__global__ __launch_bounds__(256) void loss_k(const float4* __restrict__ nd1, const float4* __restrict__ nd2,
        const int* __restrict__ user, const int* __restrict__ item, const int* __restrict__ labels,
        const float* __restrict__ bp, const float* __restrict__ bdu, const float* __restrict__ bdi,
        float* __restrict__ acc, int is_target, int B) {
    __shared__ float sh[3][4];
    int gtid = blockIdx.x * blockDim.x + threadIdx.x;
    int nth = gridDim.x * blockDim.x;
    float bpv = bp[0], bduv = bdu[0], bdiv = bdi[0];
    float lp = 0.f, lu = 0.f, li = 0.f;
    for (int s = gtid; s < B; s += nth) {
        int u = user[s];
        int it = item[s] + NUM_USER;
        float4 a = nd1[u], b = nd2[u], c = nd1[it], dd = nd2[it];
        float zp = a.x + b.x + c.y + dd.y + bpv;
        float zu = a.z + b.z + bduv;
        float zi = c.w + dd.w + bdiv;
        lp += labels[s] ? sp100(-zp) : sp100(zp);
        lu += is_target ? sp100(-zu) : sp100(zu);
        li += is_target ? sp100(-zi) : sp100(zi);
    }
    lp = wred64(lp); lu = wred64(lu); li = wred64(li);
    int lane = threadIdx.x & 63, w = threadIdx.x >> 6;
    if (lane == 0) { sh[0][w] = lp; sh[1][w] = lu; sh[2][w] = li; }
    __syncthreads();
    if (threadIdx.x == 0) {
        float s0 = 0.f, s1 = 0.f, s2 = 0.f;
        for (int j = 0; j < 4; j++) { s0 += sh[0][j]; s1 += sh[1][j]; s2 += sh[2][j]; }
        atomicAdd(&acc[is_target ? 1 : 0], s0);
        atomicAdd(&acc[2], s1);
        atomicAdd(&acc[3], s2);
    }
}

__global__ void fin_k(const float* __restrict__ acc, float* __restrict__ out, int B) {
    float invB = 1.f / (float)B;
    out[0] = acc[0] * invB + acc[1] * invB + 0.1f * ((acc[2] + acc[3]) * (0.5f * invB));
}

// ---------------- orchestration ----------------

extern "C" void kernel_launch(void* const* d_in, const int* in_sizes, int n_in,
                              void* d_out, int out_size, void* d_ws, size_t ws_size,
                              hipStream_t stream) {
    const float* feats[2] = {(const float*)d_in[0], (const float*)d_in[1]};
    const int* adj[2]    = {(const int*)d_in[2], (const int*)d_in[3]};
    const int* user[2]   = {(const int*)d_in[4], (const int*)d_in[7]};
    const int* item[2]   = {(const int*)d_in[5], (const int*)d_in[8]};
    const int* labels[2] = {(const int*)d_in[6], (const int*)d_in[9]};
    const float* Wl[2] = {(const float*)d_in[10], (const float*)d_in[12]};
    const float* bl[2] = {(const float*)d_in[11], (const float*)d_in[13]};
    const float* Wp  = (const float*)d_in[14];
    const float* bp  = (const float*)d_in[15];
    const float* Wdu = (const float*)d_in[16];
    const float* bdu = (const float*)d_in[17];
    const float* Wdi = (const float*)d_in[18];
    const float* bdi = (const float*)d_in[19];

    const int E = in_sizes[2] / 2;
    const int B = in_sizes[4];
    const int N = N_NODES;

    char* w = (char*)d_ws;
    unsigned char* Tp = (unsigned char*)w; w += (size_t)MPAD * 128;   // fp8
    ushort* Fhi  = (ushort*)w; w += (size_t)MPAD * 128 * 2;           // bf16 features
    ushort* W1h  = (ushort*)w; w += 16384 * 2;
    ushort* W1l  = (ushort*)w; w += 16384 * 2;
    ushort* W2h  = (ushort*)w; w += 16384 * 2;
    ushort* W2l  = (ushort*)w; w += 16384 * 2;
    float* nd1  = (float*)w; w += (size_t)MPAD * 16;
    float* nd2  = (float*)w; w += (size_t)MPAD * 16;
    int*   deg  = (int*)w;   w += (size_t)2 * N * 4;
    float* dinv = (float*)w; w += (size_t)2 * N * 4;
    int*   off  = (int*)w;   w += (size_t)2 * N * 4;
    int*   idxb = (int*)w;   w += (size_t)2 * E * 4;
    unsigned int* stg = (unsigned int*)w; w += (size_t)2 * E * 4;
    int*   tbl  = (int*)w;   w += (size_t)2 * 256 * NBUCK * 4;
    int*   bbase = (int*)w;  w += 2 * NBUCK * 4;
    int*   bcnt  = (int*)w;  w += 2 * NBUCK * 4;
    float* acc  = (float*)w; w += 64;

    int nbE = (E + EPB - 1) / EPB;
    int nbB = (N + NPB - 1) / NPB;
    int gMM = MPAD / 64;
    int gAG = MPAD / 4;

    init_k<<<130, 256, 0, stream>>>(Wl[0], Wl[1], W1h, W1l, W2h, W2l, Tp, acc);

    // CSR build, both domains merged
    hist_k<<<2 * nbE, 256, 0, stream>>>(adj[0], adj[1], tbl, E, nbE);
    scan1_k<<<128, 256, 0, stream>>>(tbl, bcnt, nbE);
    scan2_k<<<1, 256, 0, stream>>>(bcnt, bbase);
    bin_k<<<2 * nbE, 256, 0, stream>>>(adj[0], adj[1], tbl, bbase, stg, E, nbE);
    csr_k<<<2 * nbB, 256, 0, stream>>>(stg, bbase, bcnt, deg, dinv, off, idxb, N, nbB, E);

    for (int dom = 0; dom < 2; dom++) {
        const int* idxd = idxb + (size_t)dom * E;
        const int* offd = off + (size_t)dom * N;
        const int* degd = deg + (size_t)dom * N;
        const float* dinvd = dinv + (size_t)dom * N;

        // layer 1 (f32 input feats, split in-register, 3 MFMA)
        mm_k<true><<<gMM, 256, 0, stream>>>(feats[dom], nullptr, W1h, W1l, dinvd, Tp, N);
        aggregate_k<true><<<gAG, 256, 0, stream>>>(Tp, idxd, offd, degd, dinvd, bl[0],
                                                   Wp, Wdu, Wdi, 0, nd1, Fhi, N);

        // layer 2 (bf16 features, 2 MFMA; aggregate emits head dots only)
        mm_k<false><<<gMM, 256, 0, stream>>>(nullptr, Fhi, W2h, W2l, dinvd, Tp, N);
        aggregate_k<false><<<gAG, 256, 0, stream>>>(Tp, idxd, offd, degd, dinvd, bl[1],
                                                    Wp, Wdu, Wdi, 128, nd2, nullptr, N);

        loss_k<<<128, 256, 0, stream>>>((const float4*)nd1, (const float4*)nd2,
                                        user[dom], item[dom], labels[dom],
                                        bp, bdu, bdi, acc, dom, B);
    }
    fin_k<<<1, 1, 0, stream>>>(acc, (float*)d_out, B);
}

// Round 11
// 435.021 us; speedup vs baseline: 2.2524x; 1.3649x over previous
//
#include <hip/hip_runtime.h>

#define N_NODES 110000
#define NUM_USER 60000
#define MPAD 110080        // N_NODES padded to 128-row GEMM tiles
#define ZROW N_NODES       // dedicated all-zero row (rows N..MPAD-1 zeroed in init)
#define BSHIFT 9           // bucket = dst >> 9  (512 nodes per bucket)
#define NBUCK 256
#define NPB 512            // nodes per bucket
#define EPB 8192           // edges per block in hist/bin
#define CAP 9216           // per-bucket edge capacity in csr_k LDS

typedef __attribute__((ext_vector_type(8))) __bf16 bf16x8;
typedef __attribute__((ext_vector_type(4))) float f32x4;
typedef __attribute__((ext_vector_type(2))) float f32x2;
typedef __attribute__((ext_vector_type(4))) unsigned int uint4v;

union UB { uint4v u; bf16x8 b; };

__device__ __forceinline__ unsigned short f2b(float f) {   // f32 -> bf16 RNE
    unsigned int u = __float_as_uint(f);
    unsigned int r = (u + 0x7FFFu + ((u >> 16) & 1u)) >> 16;
    return (unsigned short)r;
}
__device__ __forceinline__ float b2f(unsigned short h) {
    return __uint_as_float(((unsigned int)h) << 16);
}
// f32 -> fp8 e4m3 (OCP) RNE via exact 2^-120 scaling trick (handles subnormals)
__device__ __forceinline__ unsigned f2e4m3(float x) {
    unsigned u = __float_as_uint(x * 0x1p-120f);
    unsigned r = u + 0x7FFFFu + ((u >> 20) & 1u);
    return ((r >> 20) & 0x7Fu) | ((u >> 24) & 0x80u);
}
__device__ __forceinline__ float e4m3f(unsigned v) {   // fallback decode
    unsigned bits = ((v & 0x80u) << 24) | ((v & 0x7Fu) << 20);
    return __uint_as_float(bits) * 0x1p+120f;
}

// ---------------- init: weight conv + pad-row zero + acc zero ----------------

__global__ __launch_bounds__(256) void init_k(const float* __restrict__ W1, const float* __restrict__ W2,
        ushort* __restrict__ W1h, ushort* __restrict__ W1l,
        ushort* __restrict__ W2h, ushort* __restrict__ W2l,
        unsigned char* __restrict__ Tp, float* __restrict__ acc) {
    int b = blockIdx.x, tid = threadIdx.x;
    if (b < 128) {
        const float* W = (b < 64) ? W1 : W2;
        ushort* hi = (b < 64) ? W1h : W2h;
        ushort* lo = (b < 64) ? W1l : W2l;
        int i = (b & 63) * 256 + tid;   // 16384 total
        int k = i >> 7, n = i & 127;
        float w = W[i];
        ushort h = f2b(w);
        hi[(n << 7) | k] = h;
        lo[(n << 7) | k] = f2b(w - b2f(h));
    } else if (b == 128) {
        // zero Tp pad rows: rows N..MPAD-1, 128 B each
        for (int j = tid; j < (MPAD - N_NODES) * 128; j += 256)
            Tp[(size_t)N_NODES * 128 + j] = 0;
    } else {
        if (tid < 16) acc[tid] = 0.f;
    }
}

// ---------------- bucket-sort CSR build (both domains in one launch) ----------------

__global__ __launch_bounds__(256) void hist_k(const int* __restrict__ adj0, const int* __restrict__ adj1,
        int* __restrict__ tbl, int E, int nbE) {
    __shared__ int h[NBUCK];
    int b = blockIdx.x, tid = threadIdx.x;
    int dom = b / nbE, blk = b - dom * nbE;
    const int* dst = (dom ? adj1 : adj0) + E;
    h[tid] = 0;
    __syncthreads();
    int base = blk * EPB, end = min(base + EPB, E);
    for (int i = base + tid * 4; i + 3 < end; i += 1024) {
        int4 d = *(const int4*)&dst[i];
        atomicAdd(&h[d.x >> BSHIFT], 1); atomicAdd(&h[d.y >> BSHIFT], 1);
        atomicAdd(&h[d.z >> BSHIFT], 1); atomicAdd(&h[d.w >> BSHIFT], 1);
    }
    __syncthreads();
    tbl[((size_t)b) * NBUCK + tid] = h[tid];
}

__global__ __launch_bounds__(256) void scan1_k(int* __restrict__ tbl, int* __restrict__ bcnt, int nbE) {
    int w = threadIdx.x >> 6, lane = threadIdx.x & 63;
    int gw = blockIdx.x * 4 + w;         // 512 waves: dom*256 + bucket
    int dom = gw >> 8, t = gw & 255;
    int carry = 0;
    size_t base = (size_t)dom * nbE * NBUCK + t;
    for (int c = 0; c < nbE; c += 64) {
        int idx = c + lane;
        int v = (idx < nbE) ? tbl[base + (size_t)idx * NBUCK] : 0;
        int s = v;
        #pragma unroll
        for (int o = 1; o < 64; o <<= 1) { int x = __shfl_up(s, o); if (lane >= o) s += x; }
        if (idx < nbE) tbl[base + (size_t)idx * NBUCK] = carry + s - v;
        carry += __shfl(s, 63);
    }
    if (lane == 0) bcnt[dom * NBUCK + t] = carry;
}

__global__ __launch_bounds__(256) void scan2_k(const int* __restrict__ bcnt, int* __restrict__ bbase) {
    __shared__ int sh[NBUCK];
    int t = threadIdx.x;
    for (int dom = 0; dom < 2; dom++) {
        int v = bcnt[dom * NBUCK + t];
        sh[t] = v;
        __syncthreads();
        for (int o = 1; o < NBUCK; o <<= 1) {
            int x = (t >= o) ? sh[t - o] : 0;
            __syncthreads();
            sh[t] += x;
            __syncthreads();
        }
        bbase[dom * NBUCK + t] = sh[t] - v;
        __syncthreads();
    }
}

__global__ __launch_bounds__(256) void bin_k(const int* __restrict__ adj0, const int* __restrict__ adj1,
        const int* __restrict__ tbl, const int* __restrict__ bbase,
        unsigned int* __restrict__ stg, int E, int nbE) {
    __shared__ int lcur[NBUCK];
    int b = blockIdx.x, tid = threadIdx.x;
    int dom = b / nbE, blk = b - dom * nbE;
    const int* src = (dom ? adj1 : adj0);
    const int* dst = src + E;
    unsigned int* sg = stg + (size_t)dom * E;
    lcur[tid] = bbase[dom * NBUCK + tid] + tbl[((size_t)b) * NBUCK + tid];
    __syncthreads();
    int base = blk * EPB, end = min(base + EPB, E);
    for (int i = base + tid * 4; i + 3 < end; i += 1024) {
        int4 s = *(const int4*)&src[i];
        int4 d = *(const int4*)&dst[i];
        int p;
        p = atomicAdd(&lcur[d.x >> BSHIFT], 1); sg[p] = (unsigned)s.x | ((unsigned)(d.x & (NPB - 1)) << 17);
        p = atomicAdd(&lcur[d.y >> BSHIFT], 1); sg[p] = (unsigned)s.y | ((unsigned)(d.y & (NPB - 1)) << 17);
        p = atomicAdd(&lcur[d.z >> BSHIFT], 1); sg[p] = (unsigned)s.z | ((unsigned)(d.z & (NPB - 1)) << 17);
        p = atomicAdd(&lcur[d.w >> BSHIFT], 1); sg[p] = (unsigned)s.w | ((unsigned)(d.w & (NPB - 1)) << 17);
    }
}

__global__ __launch_bounds__(256) void csr_k(const unsigned int* __restrict__ stg,
        const int* __restrict__ bbase, const int* __restrict__ bcnt,
        int* __restrict__ deg, float* __restrict__ dinv, int* __restrict__ off,
        int* __restrict__ idxb, int N, int nbB, int E) {
    __shared__ int ldeg[NPB];
    __shared__ int lcur[NPB];
    __shared__ int shp[256];
    __shared__ unsigned int lidx[CAP];
    int b = blockIdx.x, tid = threadIdx.x;
    int dom = b / nbB, blk = b - dom * nbB;
    const unsigned int* sg = stg + (size_t)dom * E;
    int* degd = deg + (size_t)dom * N_NODES;
    float* dinvd = dinv + (size_t)dom * N_NODES;
    int* offd = off + (size_t)dom * N_NODES;
    int* idxd = idxb + (size_t)dom * E;
    int node0 = blk * NPB;
    int base = bbase[dom * NBUCK + blk], cnt = bcnt[dom * NBUCK + blk];
    ldeg[tid] = 0; ldeg[tid + 256] = 0;
    __syncthreads();
    for (int i = tid; i < cnt; i += 256)
        atomicAdd(&ldeg[sg[base + i] >> 17], 1);
    __syncthreads();
    int a0 = ldeg[2 * tid], a1 = ldeg[2 * tid + 1];
    shp[tid] = a0 + a1;
    __syncthreads();
    for (int o = 1; o < 256; o <<= 1) {
        int v = (tid >= o) ? shp[tid - o] : 0;
        __syncthreads();
        shp[tid] += v;
        __syncthreads();
    }
    int excl = shp[tid] - a0 - a1;
    lcur[2 * tid] = excl;
    lcur[2 * tid + 1] = excl + a0;
    int n0 = node0 + 2 * tid;
    if (n0 < N)     { degd[n0] = a0;     dinvd[n0] = rsqrtf(a0 + 1.f);     offd[n0] = base + excl; }
    if (n0 + 1 < N) { degd[n0 + 1] = a1; dinvd[n0 + 1] = rsqrtf(a1 + 1.f); offd[n0 + 1] = base + excl + a0; }
    __syncthreads();
    for (int i = tid; i < cnt; i += 256) {
        unsigned e = sg[base + i];
        int p = atomicAdd(&lcur[e >> 17], 1);
        if (p < CAP) lidx[p] = e & 0x1FFFFu;
    }
    __syncthreads();
    for (int i = tid; i < cnt; i += 256)
        idxd[base + i] = (int)lidx[i];
}

// ---------------- GEMM: T'(fp8 e4m3, Mx128) = dinv[row]*(A@W), LDS-staged W, 2 strips/wave ----
// Block = 4 waves, 128-row tile. W staged in 2 phases (g in {0,1} then {2,3}), 32 KB LDS,
// fragment-major layout: frag f = (gg*8+n)*64 + lane, 16 B each; ds_read_b128 conflict-free.

template<bool F32A>
__global__ __launch_bounds__(256) void mm_k(const float* __restrict__ Xf,
        const ushort* __restrict__ Xhi,
        const ushort* __restrict__ Whi, const ushort* __restrict__ Wlo,   // [n][k]
        const float* __restrict__ dinv, unsigned char* __restrict__ Tp, int M) {
    __shared__ ushort ldsW[2][1024 * 8];   // [hi/lo][1024 frags x 8 ushorts] = 32 KB
    int tid = threadIdx.x;
    int wid = tid >> 6, lane = tid & 63;
    int l15 = lane & 15;
    int kg = (lane >> 4) * 8;
    int row0 = blockIdx.x * 128 + wid * 32;   // wave: rows row0..row0+31 (strips at +0, +16)
    int rA0 = row0 + l15;
    int rA1 = row0 + 16 + l15;
    f32x4 acc[2][8] = {};
    #pragma unroll
    for (int ph = 0; ph < 2; ph++) {
        if (ph) __syncthreads();   // protect LDS before overwrite
        #pragma unroll
        for (int i = 0; i < 8; i++) {
            int arr = i >> 2;
            int f = tid + (i & 3) * 256;            // 0..1023
            int l = f & 63;
            int nr = ((f >> 6) & 7) * 16 + (l & 15);
            int kc = (2 * ph + (f >> 9)) * 32 + (l >> 4) * 8;
            const ushort* srcp = (arr ? Wlo : Whi) + nr * 128 + kc;
            *(uint4v*)&ldsW[arr][(size_t)f * 8] = *(const uint4v*)srcp;
        }
        __syncthreads();
        #pragma unroll
        for (int gg = 0; gg < 2; gg++) {
            int g = 2 * ph + gg;
            int k0 = g * 32 + kg;
            UB a0hi, a0lo, a1hi, a1lo;
            if (F32A) {
                #pragma unroll
                for (int s = 0; s < 2; s++) {
                    int rA = s ? rA1 : rA0;
                    float4 f0 = make_float4(0.f, 0.f, 0.f, 0.f), f1 = f0;
                    if (rA < M) {
                        f0 = *(const float4*)&Xf[(size_t)rA * 128 + k0];
                        f1 = *(const float4*)&Xf[(size_t)rA * 128 + k0 + 4];
                    }
                    float fv[8] = {f0.x, f0.y, f0.z, f0.w, f1.x, f1.y, f1.z, f1.w};
                    ushort h[8], l[8];
                    #pragma unroll
                    for (int j = 0; j < 8; j++) { h[j] = f2b(fv[j]); l[j] = f2b(fv[j] - b2f(h[j])); }
                    uint4v hu = uint4v{(uint)h[0] | ((uint)h[1] << 16), (uint)h[2] | ((uint)h[3] << 16),
                                       (uint)h[4] | ((uint)h[5] << 16), (uint)h[6] | ((uint)h[7] << 16)};
                    uint4v lu = uint4v{(uint)l[0] | ((uint)l[1] << 16), (uint)l[2] | ((uint)l[3] << 16),
                                       (uint)l[4] | ((uint)l[5] << 16), (uint)l[6] | ((uint)l[7] << 16)};
                    if (s) { a1hi.u = hu; a1lo.u = lu; } else { a0hi.u = hu; a0lo.u = lu; }
                }
            } else {
                a0hi.u = *(const uint4v*)&Xhi[(size_t)rA0 * 128 + k0];
                a1hi.u = *(const uint4v*)&Xhi[(size_t)rA1 * 128 + k0];
            }
            #pragma unroll
            for (int n = 0; n < 8; n++) {
                int fbase = ((gg * 8 + n) * 64 + lane) * 8;
                UB bhi, blo;
                bhi.u = *(const uint4v*)&ldsW[0][fbase];
                blo.u = *(const uint4v*)&ldsW[1][fbase];
                acc[0][n] = __builtin_amdgcn_mfma_f32_16x16x32_bf16(a0hi.b, bhi.b, acc[0][n], 0, 0, 0);
                acc[0][n] = __builtin_amdgcn_mfma_f32_16x16x32_bf16(a0hi.b, blo.b, acc[0][n], 0, 0, 0);
                if (F32A)
                    acc[0][n] = __builtin_amdgcn_mfma_f32_16x16x32_bf16(a0lo.b, bhi.b, acc[0][n], 0, 0, 0);
                acc[1][n] = __builtin_amdgcn_mfma_f32_16x16x32_bf16(a1hi.b, bhi.b, acc[1][n], 0, 0, 0);
                acc[1][n] = __builtin_amdgcn_mfma_f32_16x16x32_bf16(a1hi.b, blo.b, acc[1][n], 0, 0, 0);
                if (F32A)
                    acc[1][n] = __builtin_amdgcn_mfma_f32_16x16x32_bf16(a1lo.b, bhi.b, acc[1][n], 0, 0, 0);
            }
        }
    }
    #pragma unroll
    for (int s = 0; s < 2; s++) {
        int rbase = row0 + s * 16 + (lane >> 4) * 4;
        #pragma unroll
        for (int r = 0; r < 4; r++) {
            int row = rbase + r;
            if (row < M) {
                float dv = dinv[row];
                #pragma unroll
                for (int n = 0; n < 8; n++)
                    Tp[(size_t)row * 128 + n * 16 + l15] = (unsigned char)f2e4m3(dv * acc[s][n][r]);
            }
        }
    }
}

// ---------------- aggregate + fused per-node head dots (R6 structure, fp8 gather) -------------

template<bool STORE_F>
__global__ __launch_bounds__(256) void aggregate_k(const unsigned char* __restrict__ Tp,
        const int* __restrict__ idxb, const int* __restrict__ off, const int* __restrict__ deg,
        const float* __restrict__ dinv, const float* __restrict__ bias,
        const float* __restrict__ Wp, const float* __restrict__ Wdu, const float* __restrict__ Wdi,
        int loff,   // 0 for layer 1, 128 for layer 2
        float* __restrict__ nd, ushort* __restrict__ ohi, int N) {
    int w = threadIdx.x >> 6, lane = threadIdx.x & 63;
    int d = blockIdx.x * 4 + w;
    int grp = lane >> 4, li = lane & 15;
    int db = li * 8;   // first dim this lane owns
    if (d >= N) {   // pad rows for GEMM tiles: keep zeroed
        if (STORE_F && grp == 0) *(uint4*)&ohi[(size_t)d * 128 + db] = make_uint4(0, 0, 0, 0);
        return;
    }
    float a0 = 0.f, a1 = 0.f, a2 = 0.f, a3 = 0.f;
    float a4 = 0.f, a5 = 0.f, a6 = 0.f, a7 = 0.f;
    int o = off[d];
    int cnt = deg[d] + 1;   // position 0 = self
    unsigned laneoff = (unsigned)(li << 3);
    for (int c = 0; c < cnt; c += 64) {
        int p = c + lane;
        int id = ZROW;
        if (p < cnt) id = (p == 0) ? d : idxb[o + p - 1];
        int m = min(64, cnt - c);
        #pragma unroll 4
        for (int jj = 0; jj * 4 < m; jj++) {
            int s = __shfl(id, jj * 4 + grp);
            uint2 u = *(const uint2*)(Tp + (((unsigned)s << 7) | laneoff));
#if __has_builtin(__builtin_amdgcn_cvt_pk_f32_fp8)
            f32x2 p01 = __builtin_amdgcn_cvt_pk_f32_fp8(u.x, false);
            f32x2 p23 = __builtin_amdgcn_cvt_pk_f32_fp8(u.x, true);
            f32x2 p45 = __builtin_amdgcn_cvt_pk_f32_fp8(u.y, false);
            f32x2 p67 = __builtin_amdgcn_cvt_pk_f32_fp8(u.y, true);
            a0 += p01[0]; a1 += p01[1]; a2 += p23[0]; a3 += p23[1];
            a4 += p45[0]; a5 += p45[1]; a6 += p67[0]; a7 += p67[1];
#else
            a0 += e4m3f(u.x & 0xFF);         a1 += e4m3f((u.x >> 8) & 0xFF);
            a2 += e4m3f((u.x >> 16) & 0xFF); a3 += e4m3f(u.x >> 24);
            a4 += e4m3f(u.y & 0xFF);         a5 += e4m3f((u.y >> 8) & 0xFF);
            a6 += e4m3f((u.y >> 16) & 0xFF); a7 += e4m3f(u.y >> 24);
#endif
        }
    }
    // cross-group reduce: all 4 groups end with identical sums for dims db..db+7
    #define RED2(x) { x += __shfl_xor(x, 16); x += __shfl_xor(x, 32); }
    RED2(a0) RED2(a1) RED2(a2) RED2(a3) RED2(a4) RED2(a5) RED2(a6) RED2(a7)
    #undef RED2
    float di = dinv[d];
    float4 b0 = *(const float4*)&bias[db];
    float4 b1 = *(const float4*)&bias[db + 4];
    float f0 = fmaxf(di * a0 + b0.x, 0.f);
    float f1 = fmaxf(di * a1 + b0.y, 0.f);
    float f2 = fmaxf(di * a2 + b0.z, 0.f);
    float f3 = fmaxf(di * a3 + b0.w, 0.f);
    float f4 = fmaxf(di * a4 + b1.x, 0.f);
    float f5 = fmaxf(di * a5 + b1.y, 0.f);
    float f6 = fmaxf(di * a6 + b1.z, 0.f);
    float f7 = fmaxf(di * a7 + b1.w, 0.f);
    if (STORE_F && grp == 0) {
        ushort h0 = f2b(f0), h1 = f2b(f1), h2 = f2b(f2), h3 = f2b(f3);
        ushort h4 = f2b(f4), h5 = f2b(f5), h6 = f2b(f6), h7 = f2b(f7);
        uint4 hv = make_uint4((uint)h0 | ((uint)h1 << 16), (uint)h2 | ((uint)h3 << 16),
                              (uint)h4 | ((uint)h5 << 16), (uint)h6 | ((uint)h7 << 16));
        *(uint4*)&ohi[(size_t)d * 128 + db] = hv;
    }
    // head dots: group g computes dot g over the full 128 dims
    const float* wsel = (grp == 0) ? Wp + loff : (grp == 1) ? Wp + 256 + loff
                      : (grp == 2) ? Wdu + loff : Wdi + loff;
    float4 w0 = *(const float4*)&wsel[db];
    float4 w1 = *(const float4*)&wsel[db + 4];
    float dt = f0 * w0.x + f1 * w0.y + f2 * w0.z + f3 * w0.w
             + f4 * w1.x + f5 * w1.y + f6 * w1.z + f7 * w1.w;
    dt += __shfl_xor(dt, 1); dt += __shfl_xor(dt, 2);
    dt += __shfl_xor(dt, 4); dt += __shfl_xor(dt, 8);
    if (li == 0) nd[(size_t)d * 4 + grp] = dt;
}

// ---------------- loss ----------------

__device__ __forceinline__ float sp100(float z) {   // min(softplus(z),100)
    float sp = (z > 0.f) ? (z + log1pf(expf(-z))) : log1pf(expf(z));
    return fminf(sp, 100.f);
}
__device__ __forceinline__ float wred64(float x) {
    #pragma unroll
    for (int o = 32; o > 0; o >>= 1) x += __shfl_xor(x, o);
    return x;
}

__global__ __launch_bounds__(256) void loss_k(const float4* __restrict__ nd1, const float4* __restrict__ nd2,
        const int* __restrict__ user, const int* __restrict__ item, const int* __restrict__ labels,
        const float* __restrict__ bp, const float* __restrict__ bdu, const float* __restrict__ bdi,
        float* __restrict__ acc, int is_target, int B) {
    __shared__ float sh[3][4];
    int gtid = blockIdx.x * blockDim.x + threadIdx.x;
    int nth = gridDim.x * blockDim.x;
    float bpv = bp[0], bduv = bdu[0], bdiv = bdi[0];
    float lp = 0.f, lu = 0.f, li = 0.f;
    for (int s = gtid; s < B; s += nth) {
        int u = user[s];
        int it = item[s] + NUM_USER;
        float4 a = nd1[u], b = nd2[u], c = nd1[it], dd = nd2[it];
        float zp = a.x + b.x + c.y + dd.y + bpv;
        float zu = a.z + b.z + bduv;
        float zi = c.w + dd.w + bdiv;
        lp += labels[s] ? sp100(-zp) : sp100(zp);
        lu += is_target ? sp100(-zu) : sp100(zu);
        li += is_target ? sp100(-zi) : sp100(zi);
    }
    lp = wred64(lp); lu = wred64(lu); li = wred64(li);
    int lane = threadIdx.x & 63, w = threadIdx.x >> 6;
    if (lane == 0) { sh[0][w] = lp; sh[1][w] = lu; sh[2][w] = li; }
    __syncthreads();
    if (threadIdx.x == 0) {
        float s0 = 0.f, s1 = 0.f, s2 = 0.f;
        for (int j = 0; j < 4; j++) { s0 += sh[0][j]; s1 += sh[1][j]; s2 += sh[2][j]; }
        atomicAdd(&acc[is_target ? 1 : 0], s0);
        atomicAdd(&acc[2], s1);
        atomicAdd(&acc[3], s2);
    }
}

__global__ void fin_k(const float* __restrict__ acc, float* __restrict__ out, int B) {
    float invB = 1.f / (float)B;
    out[0] = acc[0] * invB + acc[1] * invB + 0.1f * ((acc[2] + acc[3]) * (0.5f * invB));
}

// ---------------- orchestration ----------------

extern "C" void kernel_launch(void* const* d_in, const int* in_sizes, int n_in,
                              void* d_out, int out_size, void* d_ws, size_t ws_size,
                              hipStream_t stream) {
    const float* feats[2] = {(const float*)d_in[0], (const float*)d_in[1]};
    const int* adj[2]    = {(const int*)d_in[2], (const int*)d_in[3]};
    const int* user[2]   = {(const int*)d_in[4], (const int*)d_in[7]};
    const int* item[2]   = {(const int*)d_in[5], (const int*)d_in[8]};
    const int* labels[2] = {(const int*)d_in[6], (const int*)d_in[9]};
    const float* Wl[2] = {(const float*)d_in[10], (const float*)d_in[12]};
    const float* bl[2] = {(const float*)d_in[11], (const float*)d_in[13]};
    const float* Wp  = (const float*)d_in[14];
    const float* bp  = (const float*)d_in[15];
    const float* Wdu = (const float*)d_in[16];
    const float* bdu = (const float*)d_in[17];
    const float* Wdi = (const float*)d_in[18];
    const float* bdi = (const float*)d_in[19];

    const int E = in_sizes[2] / 2;
    const int B = in_sizes[4];
    const int N = N_NODES;

    char* w = (char*)d_ws;
    unsigned char* Tp = (unsigned char*)w; w += (size_t)MPAD * 128;   // fp8
    ushort* Fhi  = (ushort*)w; w += (size_t)MPAD * 128 * 2;           // bf16 features
    ushort* W1h  = (ushort*)w; w += 16384 * 2;
    ushort* W1l  = (ushort*)w; w += 16384 * 2;
    ushort* W2h  = (ushort*)w; w += 16384 * 2;
    ushort* W2l  = (ushort*)w; w += 16384 * 2;
    float* nd1  = (float*)w; w += (size_t)MPAD * 16;
    float* nd2  = (float*)w; w += (size_t)MPAD * 16;
    int*   deg  = (int*)w;   w += (size_t)2 * N * 4;
    float* dinv = (float*)w; w += (size_t)2 * N * 4;
    int*   off  = (int*)w;   w += (size_t)2 * N * 4;
    int*   idxb = (int*)w;   w += (size_t)2 * E * 4;
    unsigned int* stg = (unsigned int*)w; w += (size_t)2 * E * 4;
    int*   tbl  = (int*)w;   w += (size_t)2 * 256 * NBUCK * 4;
    int*   bbase = (int*)w;  w += 2 * NBUCK * 4;
    int*   bcnt  = (int*)w;  w += 2 * NBUCK * 4;
    float* acc  = (float*)w; w += 64;

    int nbE = (E + EPB - 1) / EPB;
    int nbB = (N + NPB - 1) / NPB;
    int gMM = MPAD / 128;
    int gAG = MPAD / 4;

    init_k<<<130, 256, 0, stream>>>(Wl[0], Wl[1], W1h, W1l, W2h, W2l, Tp, acc);

    // CSR build, both domains merged
    hist_k<<<2 * nbE, 256, 0, stream>>>(adj[0], adj[1], tbl, E, nbE);
    scan1_k<<<128, 256, 0, stream>>>(tbl, bcnt, nbE);
    scan2_k<<<1, 256, 0, stream>>>(bcnt, bbase);
    bin_k<<<2 * nbE, 256, 0, stream>>>(adj[0], adj[1], tbl, bbase, stg, E, nbE);
    csr_k<<<2 * nbB, 256, 0, stream>>>(stg, bbase, bcnt, deg, dinv, off, idxb, N, nbB, E);

    for (int dom = 0; dom < 2; dom++) {
        const int* idxd = idxb + (size_t)dom * E;
        const int* offd = off + (size_t)dom * N;
        const int* degd = deg + (size_t)dom * N;
        const float* dinvd = dinv + (size_t)dom * N;

        // layer 1 (f32 input feats, split in-register, 3 MFMA)
        mm_k<true><<<gMM, 256, 0, stream>>>(feats[dom], nullptr, W1h, W1l, dinvd, Tp, N);
        aggregate_k<true><<<gAG, 256, 0, stream>>>(Tp, idxd, offd, degd, dinvd, bl[0],
                                                   Wp, Wdu, Wdi, 0, nd1, Fhi, N);

        // layer 2 (bf16 features, 2 MFMA; aggregate emits head dots only)
        mm_k<false><<<gMM, 256, 0, stream>>>(nullptr, Fhi, W2h, W2l, dinvd, Tp, N);
        aggregate_k<false><<<gAG, 256, 0, stream>>>(Tp, idxd, offd, degd, dinvd, bl[1],
                                                    Wp, Wdu, Wdi, 128, nd2, nullptr, N);

        loss_k<<<128, 256, 0, stream>>>((const float4*)nd1, (const float4*)nd2,
                                        user[dom], item[dom], labels[dom],
                                        bp, bdu, bdi, acc, dom, B);
    }
    fin_k<<<1, 1, 0, stream>>>(acc, (float*)d_out, B);
}

// Round 12
// 433.074 us; speedup vs baseline: 2.2625x; 1.0045x over previous
//
#include <hip/hip_runtime.h>

#define N_NODES 110000
#define NUM_USER 60000
#define MPAD 110080        // N_NODES padded to 128-row GEMM tiles
#define ZROW N_NODES       // dedicated all-zero row (rows N..MPAD-1 zeroed in init)
#define BSHIFT 9           // bucket = dst >> 9  (512 nodes per bucket)
#define NBUCK 256
#define NPB 512            // nodes per bucket
#define EPB 8192           // edges per block in hist/bin
#define CAP 9216           // per-bucket edge capacity in csr_k LDS

typedef __attribute__((ext_vector_type(8))) __bf16 bf16x8;
typedef __attribute__((ext_vector_type(4))) float f32x4;
typedef __attribute__((ext_vector_type(2))) float f32x2;
typedef __attribute__((ext_vector_type(4))) unsigned int uint4v;

union UB { uint4v u; bf16x8 b; };

__device__ __forceinline__ unsigned short f2b(float f) {   // f32 -> bf16 RNE
    unsigned int u = __float_as_uint(f);
    unsigned int r = (u + 0x7FFFu + ((u >> 16) & 1u)) >> 16;
    return (unsigned short)r;
}
__device__ __forceinline__ float b2f(unsigned short h) {
    return __uint_as_float(((unsigned int)h) << 16);
}
// f32 -> fp8 e4m3 (OCP) RNE via exact 2^-120 scaling trick (handles subnormals)
__device__ __forceinline__ unsigned f2e4m3(float x) {
    unsigned u = __float_as_uint(x * 0x1p-120f);
    unsigned r = u + 0x7FFFFu + ((u >> 20) & 1u);
    return ((r >> 20) & 0x7Fu) | ((u >> 24) & 0x80u);
}
__device__ __forceinline__ float e4m3f(unsigned v) {   // fallback decode
    unsigned bits = ((v & 0x80u) << 24) | ((v & 0x7Fu) << 20);
    return __uint_as_float(bits) * 0x1p+120f;
}

// ---------------- init: weight conv + pad-row zero + counters zero ----------------

__global__ __launch_bounds__(256) void init_k(const float* __restrict__ W1, const float* __restrict__ W2,
        ushort* __restrict__ W1h, ushort* __restrict__ W1l,
        ushort* __restrict__ W2h, ushort* __restrict__ W2l,
        unsigned char* __restrict__ Tp, float* __restrict__ acc, int* __restrict__ bcnt) {
    int b = blockIdx.x, tid = threadIdx.x;
    if (b < 128) {
        const float* W = (b < 64) ? W1 : W2;
        ushort* hi = (b < 64) ? W1h : W2h;
        ushort* lo = (b < 64) ? W1l : W2l;
        int i = (b & 63) * 256 + tid;   // 16384 total
        int k = i >> 7, n = i & 127;
        float w = W[i];
        ushort h = f2b(w);
        hi[(n << 7) | k] = h;
        lo[(n << 7) | k] = f2b(w - b2f(h));
    } else if (b == 128) {
        // zero Tp pad rows: rows N..MPAD-1, 128 B each
        for (int j = tid; j < (MPAD - N_NODES) * 128; j += 256)
            Tp[(size_t)N_NODES * 128 + j] = 0;
    } else {
        if (tid < 16) acc[tid] = 0.f;
        bcnt[tid] = 0;          // dom 0
        bcnt[256 + tid] = 0;    // dom 1
    }
}

// ---------------- bucket-sort CSR build (both domains in one launch) ----------------
// hist_k: LDS histogram; per-block base within bucket via atomicAdd return (no scan1 needed)

__global__ __launch_bounds__(256) void hist_k(const int* __restrict__ adj0, const int* __restrict__ adj1,
        int* __restrict__ tbl, int* __restrict__ bcnt, int E, int nbE) {
    __shared__ int h[NBUCK];
    int b = blockIdx.x, tid = threadIdx.x;
    int dom = b / nbE, blk = b - dom * nbE;
    const int* dst = (dom ? adj1 : adj0) + E;
    h[tid] = 0;
    __syncthreads();
    int base = blk * EPB, end = min(base + EPB, E);
    for (int i = base + tid * 4; i + 3 < end; i += 1024) {
        int4 d = *(const int4*)&dst[i];
        atomicAdd(&h[d.x >> BSHIFT], 1); atomicAdd(&h[d.y >> BSHIFT], 1);
        atomicAdd(&h[d.z >> BSHIFT], 1); atomicAdd(&h[d.w >> BSHIFT], 1);
    }
    __syncthreads();
    tbl[((size_t)b) * NBUCK + tid] = atomicAdd(&bcnt[dom * NBUCK + tid], h[tid]);
}

__global__ __launch_bounds__(256) void scan2_k(const int* __restrict__ bcnt, int* __restrict__ bbase) {
    __shared__ int sh[NBUCK];
    int t = threadIdx.x;
    for (int dom = 0; dom < 2; dom++) {
        int v = bcnt[dom * NBUCK + t];
        sh[t] = v;
        __syncthreads();
        for (int o = 1; o < NBUCK; o <<= 1) {
            int x = (t >= o) ? sh[t - o] : 0;
            __syncthreads();
            sh[t] += x;
            __syncthreads();
        }
        bbase[dom * NBUCK + t] = sh[t] - v;
        __syncthreads();
    }
}

__global__ __launch_bounds__(256) void bin_k(const int* __restrict__ adj0, const int* __restrict__ adj1,
        const int* __restrict__ tbl, const int* __restrict__ bbase,
        unsigned int* __restrict__ stg, int E, int nbE) {
    __shared__ int lcur[NBUCK];
    int b = blockIdx.x, tid = threadIdx.x;
    int dom = b / nbE, blk = b - dom * nbE;
    const int* src = (dom ? adj1 : adj0);
    const int* dst = src + E;
    unsigned int* sg = stg + (size_t)dom * E;
    lcur[tid] = bbase[dom * NBUCK + tid] + tbl[((size_t)b) * NBUCK + tid];
    __syncthreads();
    int base = blk * EPB, end = min(base + EPB, E);
    for (int i = base + tid * 4; i + 3 < end; i += 1024) {
        int4 s = *(const int4*)&src[i];
        int4 d = *(const int4*)&dst[i];
        int p;
        p = atomicAdd(&lcur[d.x >> BSHIFT], 1); sg[p] = (unsigned)s.x | ((unsigned)(d.x & (NPB - 1)) << 17);
        p = atomicAdd(&lcur[d.y >> BSHIFT], 1); sg[p] = (unsigned)s.y | ((unsigned)(d.y & (NPB - 1)) << 17);
        p = atomicAdd(&lcur[d.z >> BSHIFT], 1); sg[p] = (unsigned)s.z | ((unsigned)(d.z & (NPB - 1)) << 17);
        p = atomicAdd(&lcur[d.w >> BSHIFT], 1); sg[p] = (unsigned)s.w | ((unsigned)(d.w & (NPB - 1)) << 17);
    }
}

__global__ __launch_bounds__(256) void csr_k(const unsigned int* __restrict__ stg,
        const int* __restrict__ bbase, const int* __restrict__ bcnt,
        int* __restrict__ deg, float* __restrict__ dinv, int* __restrict__ off,
        int* __restrict__ idxb, int N, int nbB, int E) {
    __shared__ int ldeg[NPB];
    __shared__ int lcur[NPB];
    __shared__ int shp[256];
    __shared__ unsigned int lidx[CAP];
    int b = blockIdx.x, tid = threadIdx.x;
    int dom = b / nbB, blk = b - dom * nbB;
    const unsigned int* sg = stg + (size_t)dom * E;
    int* degd = deg + (size_t)dom * N_NODES;
    float* dinvd = dinv + (size_t)dom * N_NODES;
    int* offd = off + (size_t)dom * N_NODES;
    int* idxd = idxb + (size_t)dom * E;
    int node0 = blk * NPB;
    int base = bbase[dom * NBUCK + blk], cnt = bcnt[dom * NBUCK + blk];
    ldeg[tid] = 0; ldeg[tid + 256] = 0;
    __syncthreads();
    for (int i = tid; i < cnt; i += 256)
        atomicAdd(&ldeg[sg[base + i] >> 17], 1);
    __syncthreads();
    int a0 = ldeg[2 * tid], a1 = ldeg[2 * tid + 1];
    shp[tid] = a0 + a1;
    __syncthreads();
    for (int o = 1; o < 256; o <<= 1) {
        int v = (tid >= o) ? shp[tid - o] : 0;
        __syncthreads();
        shp[tid] += v;
        __syncthreads();
    }
    int excl = shp[tid] - a0 - a1;
    lcur[2 * tid] = excl;
    lcur[2 * tid + 1] = excl + a0;
    int n0 = node0 + 2 * tid;
    if (n0 < N)     { degd[n0] = a0;     dinvd[n0] = rsqrtf(a0 + 1.f);     offd[n0] = base + excl; }
    if (n0 + 1 < N) { degd[n0 + 1] = a1; dinvd[n0 + 1] = rsqrtf(a1 + 1.f); offd[n0 + 1] = base + excl + a0; }
    __syncthreads();
    for (int i = tid; i < cnt; i += 256) {
        unsigned e = sg[base + i];
        int p = atomicAdd(&lcur[e >> 17], 1);
        if (p < CAP) lidx[p] = e & 0x1FFFFu;
    }
    __syncthreads();
    for (int i = tid; i < cnt; i += 256)
        idxd[base + i] = (int)lidx[i];
}

// ---------------- GEMM: T'(fp8 e4m3, Mx128) = dinv[row]*(A@W), LDS-staged W, 2 strips/wave ----

template<bool F32A>
__global__ __launch_bounds__(256) void mm_k(const float* __restrict__ Xf,
        const ushort* __restrict__ Xhi,
        const ushort* __restrict__ Whi, const ushort* __restrict__ Wlo,   // [n][k]
        const float* __restrict__ dinv, unsigned char* __restrict__ Tp, int M) {
    __shared__ ushort ldsW[2][1024 * 8];   // [hi/lo][1024 frags x 8 ushorts] = 32 KB
    int tid = threadIdx.x;
    int wid = tid >> 6, lane = tid & 63;
    int l15 = lane & 15;
    int kg = (lane >> 4) * 8;
    int row0 = blockIdx.x * 128 + wid * 32;   // wave: rows row0..row0+31 (strips at +0, +16)
    int rA0 = row0 + l15;
    int rA1 = row0 + 16 + l15;
    f32x4 acc[2][8] = {};
    #pragma unroll
    for (int ph = 0; ph < 2; ph++) {
        if (ph) __syncthreads();   // protect LDS before overwrite
        #pragma unroll
        for (int i = 0; i < 8; i++) {
            int arr = i >> 2;
            int f = tid + (i & 3) * 256;            // 0..1023
            int l = f & 63;
            int nr = ((f >> 6) & 7) * 16 + (l & 15);
            int kc = (2 * ph + (f >> 9)) * 32 + (l >> 4) * 8;
            const ushort* srcp = (arr ? Wlo : Whi) + nr * 128 + kc;
            *(uint4v*)&ldsW[arr][(size_t)f * 8] = *(const uint4v*)srcp;
        }
        __syncthreads();
        #pragma unroll
        for (int gg = 0; gg < 2; gg++) {
            int g = 2 * ph + gg;
            int k0 = g * 32 + kg;
            UB a0hi, a0lo, a1hi, a1lo;
            if (F32A) {
                #pragma unroll
                for (int s = 0; s < 2; s++) {
                    int rA = s ? rA1 : rA0;
                    float4 f0 = make_float4(0.f, 0.f, 0.f, 0.f), f1 = f0;
                    if (rA < M) {
                        f0 = *(const float4*)&Xf[(size_t)rA * 128 + k0];
                        f1 = *(const float4*)&Xf[(size_t)rA * 128 + k0 + 4];
                    }
                    float fv[8] = {f0.x, f0.y, f0.z, f0.w, f1.x, f1.y, f1.z, f1.w};
                    ushort h[8], l[8];
                    #pragma unroll
                    for (int j = 0; j < 8; j++) { h[j] = f2b(fv[j]); l[j] = f2b(fv[j] - b2f(h[j])); }
                    uint4v hu = uint4v{(uint)h[0] | ((uint)h[1] << 16), (uint)h[2] | ((uint)h[3] << 16),
                                       (uint)h[4] | ((uint)h[5] << 16), (uint)h[6] | ((uint)h[7] << 16)};
                    uint4v lu = uint4v{(uint)l[0] | ((uint)l[1] << 16), (uint)l[2] | ((uint)l[3] << 16),
                                       (uint)l[4] | ((uint)l[5] << 16), (uint)l[6] | ((uint)l[7] << 16)};
                    if (s) { a1hi.u = hu; a1lo.u = lu; } else { a0hi.u = hu; a0lo.u = lu; }
                }
            } else {
                a0hi.u = *(const uint4v*)&Xhi[(size_t)rA0 * 128 + k0];
                a1hi.u = *(const uint4v*)&Xhi[(size_t)rA1 * 128 + k0];
            }
            #pragma unroll
            for (int n = 0; n < 8; n++) {
                int fbase = ((gg * 8 + n) * 64 + lane) * 8;
                UB bhi, blo;
                bhi.u = *(const uint4v*)&ldsW[0][fbase];
                blo.u = *(const uint4v*)&ldsW[1][fbase];
                acc[0][n] = __builtin_amdgcn_mfma_f32_16x16x32_bf16(a0hi.b, bhi.b, acc[0][n], 0, 0, 0);
                acc[0][n] = __builtin_amdgcn_mfma_f32_16x16x32_bf16(a0hi.b, blo.b, acc[0][n], 0, 0, 0);
                if (F32A)
                    acc[0][n] = __builtin_amdgcn_mfma_f32_16x16x32_bf16(a0lo.b, bhi.b, acc[0][n], 0, 0, 0);
                acc[1][n] = __builtin_amdgcn_mfma_f32_16x16x32_bf16(a1hi.b, bhi.b, acc[1][n], 0, 0, 0);
                acc[1][n] = __builtin_amdgcn_mfma_f32_16x16x32_bf16(a1hi.b, blo.b, acc[1][n], 0, 0, 0);
                if (F32A)
                    acc[1][n] = __builtin_amdgcn_mfma_f32_16x16x32_bf16(a1lo.b, bhi.b, acc[1][n], 0, 0, 0);
            }
        }
    }
    #pragma unroll
    for (int s = 0; s < 2; s++) {
        int rbase = row0 + s * 16 + (lane >> 4) * 4;
        #pragma unroll
        for (int r = 0; r < 4; r++) {
            int row = rbase + r;
            if (row < M) {
                float dv = dinv[row];
                #pragma unroll
                for (int n = 0; n < 8; n++)
                    Tp[(size_t)row * 128 + n * 16 + l15] = (unsigned char)f2e4m3(dv * acc[s][n][r]);
            }
        }
    }
}

// ---------------- aggregate + fused per-node head dots (fp8 gather, packed-f32 accum) ---------

template<bool STORE_F>
__global__ __launch_bounds__(256) void aggregate_k(const unsigned char* __restrict__ Tp,
        const int* __restrict__ idxb, const int* __restrict__ off, const int* __restrict__ deg,
        const float* __restrict__ dinv, const float* __restrict__ bias,
        const float* __restrict__ Wp, const float* __restrict__ Wdu, const float* __restrict__ Wdi,
        int loff,   // 0 for layer 1, 128 for layer 2
        float* __restrict__ nd, ushort* __restrict__ ohi, int N) {
    int w = threadIdx.x >> 6, lane = threadIdx.x & 63;
    int d = blockIdx.x * 4 + w;
    int grp = lane >> 4, li = lane & 15;
    int db = li * 8;   // first dim this lane owns
    if (d >= N) {   // pad rows for GEMM tiles: keep zeroed
        if (STORE_F && grp == 0) *(uint4*)&ohi[(size_t)d * 128 + db] = make_uint4(0, 0, 0, 0);
        return;
    }
    f32x2 A0 = {0.f, 0.f}, A1 = {0.f, 0.f}, A2 = {0.f, 0.f}, A3 = {0.f, 0.f};
    int o = off[d];
    int cnt = deg[d] + 1;   // position 0 = self
    unsigned laneoff = (unsigned)(li << 3);
    for (int c = 0; c < cnt; c += 64) {
        int p = c + lane;
        int id = ZROW;
        if (p < cnt) id = (p == 0) ? d : idxb[o + p - 1];
        int m = min(64, cnt - c);
        #pragma unroll 4
        for (int jj = 0; jj * 4 < m; jj++) {
            int s = __shfl(id, jj * 4 + grp);
            uint2 u = *(const uint2*)(Tp + (((unsigned)s << 7) | laneoff));
#if __has_builtin(__builtin_amdgcn_cvt_pk_f32_fp8)
            A0 += __builtin_amdgcn_cvt_pk_f32_fp8(u.x, false);
            A1 += __builtin_amdgcn_cvt_pk_f32_fp8(u.x, true);
            A2 += __builtin_amdgcn_cvt_pk_f32_fp8(u.y, false);
            A3 += __builtin_amdgcn_cvt_pk_f32_fp8(u.y, true);
#else
            A0 += f32x2{e4m3f(u.x & 0xFF),         e4m3f((u.x >> 8) & 0xFF)};
            A1 += f32x2{e4m3f((u.x >> 16) & 0xFF), e4m3f(u.x >> 24)};
            A2 += f32x2{e4m3f(u.y & 0xFF),         e4m3f((u.y >> 8) & 0xFF)};
            A3 += f32x2{e4m3f((u.y >> 16) & 0xFF), e4m3f(u.y >> 24)};
#endif
        }
    }
    float a0 = A0[0], a1 = A0[1], a2 = A1[0], a3 = A1[1];
    float a4 = A2[0], a5 = A2[1], a6 = A3[0], a7 = A3[1];
    // cross-group reduce: all 4 groups end with identical sums for dims db..db+7
    #define RED2(x) { x += __shfl_xor(x, 16); x += __shfl_xor(x, 32); }
    RED2(a0) RED2(a1) RED2(a2) RED2(a3) RED2(a4) RED2(a5) RED2(a6) RED2(a7)
    #undef RED2
    float di = dinv[d];
    float4 b0 = *(const float4*)&bias[db];
    float4 b1 = *(const float4*)&bias[db + 4];
    float f0 = fmaxf(di * a0 + b0.x, 0.f);
    float f1 = fmaxf(di * a1 + b0.y, 0.f);
    float f2 = fmaxf(di * a2 + b0.z, 0.f);
    float f3 = fmaxf(di * a3 + b0.w, 0.f);
    float f4 = fmaxf(di * a4 + b1.x, 0.f);
    float f5 = fmaxf(di * a5 + b1.y, 0.f);
    float f6 = fmaxf(di * a6 + b1.z, 0.f);
    float f7 = fmaxf(di * a7 + b1.w, 0.f);
    if (STORE_F && grp == 0) {
        ushort h0 = f2b(f0), h1 = f2b(f1), h2 = f2b(f2), h3 = f2b(f3);
        ushort h4 = f2b(f4), h5 = f2b(f5), h6 = f2b(f6), h7 = f2b(f7);
        uint4 hv = make_uint4((uint)h0 | ((uint)h1 << 16), (uint)h2 | ((uint)h3 << 16),
                              (uint)h4 | ((uint)h5 << 16), (uint)h6 | ((uint)h7 << 16));
        *(uint4*)&ohi[(size_t)d * 128 + db] = hv;
    }
    // head dots: group g computes dot g over the full 128 dims
    const float* wsel = (grp == 0) ? Wp + loff : (grp == 1) ? Wp + 256 + loff
                      : (grp == 2) ? Wdu + loff : Wdi + loff;
    float4 w0 = *(const float4*)&wsel[db];
    float4 w1 = *(const float4*)&wsel[db + 4];
    float dt = f0 * w0.x + f1 * w0.y + f2 * w0.z + f3 * w0.w
             + f4 * w1.x + f5 * w1.y + f6 * w1.z + f7 * w1.w;
    dt += __shfl_xor(dt, 1); dt += __shfl_xor(dt, 2);
    dt += __shfl_xor(dt, 4); dt += __shfl_xor(dt, 8);
    if (li == 0) nd[(size_t)d * 4 + grp] = dt;
}

// ---------------- loss ----------------

__device__ __forceinline__ float sp100(float z) {   // min(softplus(z),100)
    float sp = (z > 0.f) ? (z + log1pf(expf(-z))) : log1pf(expf(z));
    return fminf(sp, 100.f);
}
__device__ __forceinline__ float wred64(float x) {
    #pragma unroll
    for (int o = 32; o > 0; o >>= 1) x += __shfl_xor(x, o);
    return x;
}

__global__ __launch_bounds__(256) void loss_k(const float4* __restrict__ nd1, const float4* __restrict__ nd2,
        const int* __restrict__ user, const int* __restrict__ item, const int* __restrict__ labels,
        const float* __restrict__ bp, const float* __restrict__ bdu, const float* __restrict__ bdi,
        float* __restrict__ acc, int is_target, int B) {
    __shared__ float sh[3][4];
    int gtid = blockIdx.x * blockDim.x + threadIdx.x;
    int nth = gridDim.x * blockDim.x;
    float bpv = bp[0], bduv = bdu[0], bdiv = bdi[0];
    float lp = 0.f, lu = 0.f, li = 0.f;
    for (int s = gtid; s < B; s += nth) {
        int u = user[s];
        int it = item[s] + NUM_USER;
        float4 a = nd1[u], b = nd2[u], c = nd1[it], dd = nd2[it];
        float zp = a.x + b.x + c.y + dd.y + bpv;
        float zu = a.z + b.z + bduv;
        float zi = c.w + dd.w + bdiv;
        lp += labels[s] ? sp100(-zp) : sp100(zp);
        lu += is_target ? sp100(-zu) : sp100(zu);
        li += is_target ? sp100(-zi) : sp100(zi);
    }
    lp = wred64(lp); lu = wred64(lu); li = wred64(li);
    int lane = threadIdx.x & 63, w = threadIdx.x >> 6;
    if (lane == 0) { sh[0][w] = lp; sh[1][w] = lu; sh[2][w] = li; }
    __syncthreads();
    if (threadIdx.x == 0) {
        float s0 = 0.f, s1 = 0.f, s2 = 0.f;
        for (int j = 0; j < 4; j++) { s0 += sh[0][j]; s1 += sh[1][j]; s2 += sh[2][j]; }
        atomicAdd(&acc[is_target ? 1 : 0], s0);
        atomicAdd(&acc[2], s1);
        atomicAdd(&acc[3], s2);
    }
}

__global__ void fin_k(const float* __restrict__ acc, float* __restrict__ out, int B) {
    float invB = 1.f / (float)B;
    out[0] = acc[0] * invB + acc[1] * invB + 0.1f * ((acc[2] + acc[3]) * (0.5f * invB));
}

// ---------------- orchestration ----------------

extern "C" void kernel_launch(void* const* d_in, const int* in_sizes, int n_in,
                              void* d_out, int out_size, void* d_ws, size_t ws_size,
                              hipStream_t stream) {
    const float* feats[2] = {(const float*)d_in[0], (const float*)d_in[1]};
    const int* adj[2]    = {(const int*)d_in[2], (const int*)d_in[3]};
    const int* user[2]   = {(const int*)d_in[4], (const int*)d_in[7]};
    const int* item[2]   = {(const int*)d_in[5], (const int*)d_in[8]};
    const int* labels[2] = {(const int*)d_in[6], (const int*)d_in[9]};
    const float* Wl[2] = {(const float*)d_in[10], (const float*)d_in[12]};
    const float* bl[2] = {(const float*)d_in[11], (const float*)d_in[13]};
    const float* Wp  = (const float*)d_in[14];
    const float* bp  = (const float*)d_in[15];
    const float* Wdu = (const float*)d_in[16];
    const float* bdu = (const float*)d_in[17];
    const float* Wdi = (const float*)d_in[18];
    const float* bdi = (const float*)d_in[19];

    const int E = in_sizes[2] / 2;
    const int B = in_sizes[4];
    const int N = N_NODES;

    char* w = (char*)d_ws;
    unsigned char* Tp = (unsigned char*)w; w += (size_t)MPAD * 128;   // fp8
    ushort* Fhi  = (ushort*)w; w += (size_t)MPAD * 128 * 2;           // bf16 features
    ushort* W1h  = (ushort*)w; w += 16384 * 2;
    ushort* W1l  = (ushort*)w; w += 16384 * 2;
    ushort* W2h  = (ushort*)w; w += 16384 * 2;
    ushort* W2l  = (ushort*)w; w += 16384 * 2;
    float* nd1  = (float*)w; w += (size_t)MPAD * 16;
    float* nd2  = (float*)w; w += (size_t)MPAD * 16;
    int*   deg  = (int*)w;   w += (size_t)2 * N * 4;
    float* dinv = (float*)w; w += (size_t)2 * N * 4;
    int*   off  = (int*)w;   w += (size_t)2 * N * 4;
    int*   idxb = (int*)w;   w += (size_t)2 * E * 4;
    unsigned int* stg = (unsigned int*)w; w += (size_t)2 * E * 4;
    int*   tbl  = (int*)w;   w += (size_t)2 * 256 * NBUCK * 4;
    int*   bbase = (int*)w;  w += 2 * NBUCK * 4;
    int*   bcnt  = (int*)w;  w += 2 * NBUCK * 4;
    float* acc  = (float*)w; w += 64;

    int nbE = (E + EPB - 1) / EPB;
    int nbB = (N + NPB - 1) / NPB;
    int gMM = MPAD / 128;
    int gAG = MPAD / 4;

    init_k<<<130, 256, 0, stream>>>(Wl[0], Wl[1], W1h, W1l, W2h, W2l, Tp, acc, bcnt);

    // CSR build, both domains merged (hist assigns per-block bases via atomic return)
    hist_k<<<2 * nbE, 256, 0, stream>>>(adj[0], adj[1], tbl, bcnt, E, nbE);
    scan2_k<<<1, 256, 0, stream>>>(bcnt, bbase);
    bin_k<<<2 * nbE, 256, 0, stream>>>(adj[0], adj[1], tbl, bbase, stg, E, nbE);
    csr_k<<<2 * nbB, 256, 0, stream>>>(stg, bbase, bcnt, deg, dinv, off, idxb, N, nbB, E);

    for (int dom = 0; dom < 2; dom++) {
        const int* idxd = idxb + (size_t)dom * E;
        const int* offd = off + (size_t)dom * N;
        const int* degd = deg + (size_t)dom * N;
        const float* dinvd = dinv + (size_t)dom * N;

        // layer 1 (f32 input feats, split in-register, 3 MFMA)
        mm_k<true><<<gMM, 256, 0, stream>>>(feats[dom], nullptr, W1h, W1l, dinvd, Tp, N);
        aggregate_k<true><<<gAG, 256, 0, stream>>>(Tp, idxd, offd, degd, dinvd, bl[0],
                                                   Wp, Wdu, Wdi, 0, nd1, Fhi, N);

        // layer 2 (bf16 features, 2 MFMA; aggregate emits head dots only)
        mm_k<false><<<gMM, 256, 0, stream>>>(nullptr, Fhi, W2h, W2l, dinvd, Tp, N);
        aggregate_k<false><<<gAG, 256, 0, stream>>>(Tp, idxd, offd, degd, dinvd, bl[1],
                                                    Wp, Wdu, Wdi, 128, nd2, nullptr, N);

        loss_k<<<128, 256, 0, stream>>>((const float4*)nd1, (const float4*)nd2,
                                        user[dom], item[dom], labels[dom],
                                        bp, bdu, bdi, acc, dom, B);
    }
    fin_k<<<1, 1, 0, stream>>>(acc, (float*)d_out, B);
}

// Round 13
// 406.528 us; speedup vs baseline: 2.4103x; 1.0653x over previous
//
#include <hip/hip_runtime.h>

#define N_NODES 110000
#define NUM_USER 60000
#define MPAD 110080        // N_NODES padded to 128-row GEMM tiles
#define ZROW N_NODES       // dedicated all-zero row (rows N..MPAD-1 zeroed in init)
#define BSHIFT 9           // bucket = dst >> 9  (512 nodes per bucket)
#define NBUCK 256
#define NPB 512            // nodes per bucket
#define EPB 8192           // edges per block in bin
#define SCAP 9216          // fixed per-bucket capacity (mean 7447, sigma 86 -> +20 sigma)

typedef __attribute__((ext_vector_type(8))) __bf16 bf16x8;
typedef __attribute__((ext_vector_type(4))) float f32x4;
typedef __attribute__((ext_vector_type(2))) float f32x2;
typedef __attribute__((ext_vector_type(4))) unsigned int uint4v;

union UB { uint4v u; bf16x8 b; };

__device__ __forceinline__ unsigned short f2b(float f) {   // f32 -> bf16 RNE
    unsigned int u = __float_as_uint(f);
    unsigned int r = (u + 0x7FFFu + ((u >> 16) & 1u)) >> 16;
    return (unsigned short)r;
}
__device__ __forceinline__ float b2f(unsigned short h) {
    return __uint_as_float(((unsigned int)h) << 16);
}
// f32 -> fp8 e4m3 (OCP) RNE via exact 2^-120 scaling trick (handles subnormals)
__device__ __forceinline__ unsigned f2e4m3(float x) {
    unsigned u = __float_as_uint(x * 0x1p-120f);
    unsigned r = u + 0x7FFFFu + ((u >> 20) & 1u);
    return ((r >> 20) & 0x7Fu) | ((u >> 24) & 0x80u);
}
__device__ __forceinline__ float e4m3f(unsigned v) {   // fallback decode
    unsigned bits = ((v & 0x80u) << 24) | ((v & 0x7Fu) << 20);
    return __uint_as_float(bits) * 0x1p+120f;
}

// ---------------- init: weight conv + pad-row zero + counters zero ----------------

__global__ __launch_bounds__(256) void init_k(const float* __restrict__ W1, const float* __restrict__ W2,
        ushort* __restrict__ W1h, ushort* __restrict__ W1l,
        ushort* __restrict__ W2h, ushort* __restrict__ W2l,
        unsigned char* __restrict__ Tp0, unsigned char* __restrict__ Tp1,
        float* __restrict__ acc, int* __restrict__ bcnt) {
    int b = blockIdx.x, tid = threadIdx.x;
    if (b < 128) {
        const float* W = (b < 64) ? W1 : W2;
        ushort* hi = (b < 64) ? W1h : W2h;
        ushort* lo = (b < 64) ? W1l : W2l;
        int i = (b & 63) * 256 + tid;   // 16384 total
        int k = i >> 7, n = i & 127;
        float w = W[i];
        ushort h = f2b(w);
        hi[(n << 7) | k] = h;
        lo[(n << 7) | k] = f2b(w - b2f(h));
    } else if (b < 130) {
        unsigned char* Tp = (b == 128) ? Tp0 : Tp1;
        for (int j = tid; j < (MPAD - N_NODES) * 128; j += 256)
            Tp[(size_t)N_NODES * 128 + j] = 0;
    } else {
        if (tid < 16) acc[tid] = 0.f;
        bcnt[tid] = 0;          // dom 0
        bcnt[256 + tid] = 0;    // dom 1
    }
}

// ---------------- single-pass binning: LDS hist + atomic region grab + scatter ----------------
// stg layout: (dom*NBUCK + bucket) * SCAP fixed regions; no global scan needed.

__global__ __launch_bounds__(256) void bin2_k(const int* __restrict__ adj0, const int* __restrict__ adj1,
        int* __restrict__ bcnt, unsigned int* __restrict__ stg, int E, int nbE) {
    __shared__ int h[NBUCK];
    __shared__ int lcur[NBUCK];
    int b = blockIdx.x, tid = threadIdx.x;
    int dom = b / nbE, blk = b - dom * nbE;
    const int* src = (dom ? adj1 : adj0);
    const int* dst = src + E;
    unsigned int* sg = stg + (size_t)dom * NBUCK * SCAP;
    h[tid] = 0;
    __syncthreads();
    int base = blk * EPB, end = min(base + EPB, E);
    for (int i = base + tid * 4; i + 3 < end; i += 1024) {
        int4 d = *(const int4*)&dst[i];
        atomicAdd(&h[d.x >> BSHIFT], 1); atomicAdd(&h[d.y >> BSHIFT], 1);
        atomicAdd(&h[d.z >> BSHIFT], 1); atomicAdd(&h[d.w >> BSHIFT], 1);
    }
    __syncthreads();
    lcur[tid] = tid * SCAP + atomicAdd(&bcnt[dom * NBUCK + tid], h[tid]);
    __syncthreads();
    for (int i = base + tid * 4; i + 3 < end; i += 1024) {
        int4 s = *(const int4*)&src[i];
        int4 d = *(const int4*)&dst[i];
        int p;
        p = atomicAdd(&lcur[d.x >> BSHIFT], 1); sg[p] = (unsigned)s.x | ((unsigned)(d.x & (NPB - 1)) << 17);
        p = atomicAdd(&lcur[d.y >> BSHIFT], 1); sg[p] = (unsigned)s.y | ((unsigned)(d.y & (NPB - 1)) << 17);
        p = atomicAdd(&lcur[d.z >> BSHIFT], 1); sg[p] = (unsigned)s.z | ((unsigned)(d.z & (NPB - 1)) << 17);
        p = atomicAdd(&lcur[d.w >> BSHIFT], 1); sg[p] = (unsigned)s.w | ((unsigned)(d.w & (NPB - 1)) << 17);
    }
}

__global__ __launch_bounds__(256) void csr_k(const unsigned int* __restrict__ stg,
        const int* __restrict__ bcnt,
        int* __restrict__ deg, float* __restrict__ dinv, int* __restrict__ off,
        int* __restrict__ idxb, int N, int nbB) {
    __shared__ int ldeg[NPB];
    __shared__ int lcur[NPB];
    __shared__ int shp[256];
    __shared__ unsigned int lidx[SCAP];
    int b = blockIdx.x, tid = threadIdx.x;
    int dom = b / nbB, blk = b - dom * nbB;
    const unsigned int* sg = stg + ((size_t)dom * NBUCK + blk) * SCAP;
    int* degd = deg + (size_t)dom * N_NODES;
    float* dinvd = dinv + (size_t)dom * N_NODES;
    int* offd = off + (size_t)dom * N_NODES;
    int* idxd = idxb + (size_t)dom * NBUCK * SCAP;
    int node0 = blk * NPB;
    int base = blk * SCAP;                       // within-dom padded offset
    int cnt = bcnt[dom * NBUCK + blk];
    ldeg[tid] = 0; ldeg[tid + 256] = 0;
    __syncthreads();
    for (int i = tid; i < cnt; i += 256)
        atomicAdd(&ldeg[sg[i] >> 17], 1);
    __syncthreads();
    int a0 = ldeg[2 * tid], a1 = ldeg[2 * tid + 1];
    shp[tid] = a0 + a1;
    __syncthreads();
    for (int o = 1; o < 256; o <<= 1) {
        int v = (tid >= o) ? shp[tid - o] : 0;
        __syncthreads();
        shp[tid] += v;
        __syncthreads();
    }
    int excl = shp[tid] - a0 - a1;
    lcur[2 * tid] = excl;
    lcur[2 * tid + 1] = excl + a0;
    int n0 = node0 + 2 * tid;
    if (n0 < N)     { degd[n0] = a0;     dinvd[n0] = rsqrtf(a0 + 1.f);     offd[n0] = base + excl; }
    if (n0 + 1 < N) { degd[n0 + 1] = a1; dinvd[n0 + 1] = rsqrtf(a1 + 1.f); offd[n0 + 1] = base + excl + a0; }
    __syncthreads();
    for (int i = tid; i < cnt; i += 256) {
        unsigned e = sg[i];
        int p = atomicAdd(&lcur[e >> 17], 1);
        if (p < SCAP) lidx[p] = e & 0x1FFFFu;
    }
    __syncthreads();
    for (int i = tid; i < cnt; i += 256)
        idxd[base + i] = (int)lidx[i];
}

// ---------------- GEMM (merged doms): T'(fp8) = dinv[row]*(A@W), LDS-staged W, 2 strips/wave --

template<bool F32A>
__global__ __launch_bounds__(256) void mm_k(const float* __restrict__ Xf0, const float* __restrict__ Xf1,
        const ushort* __restrict__ Xhi0, const ushort* __restrict__ Xhi1,
        const ushort* __restrict__ Whi, const ushort* __restrict__ Wlo,   // [n][k]
        const float* __restrict__ dinv2, unsigned char* __restrict__ Tp0, unsigned char* __restrict__ Tp1,
        int M, int gHalf) {
    __shared__ ushort ldsW[2][1024 * 8];   // [hi/lo][1024 frags x 8 ushorts] = 32 KB
    int bid = blockIdx.x;
    int dom = bid >= gHalf;
    bid -= dom * gHalf;
    const float* Xf = dom ? Xf1 : Xf0;
    const ushort* Xhi = dom ? Xhi1 : Xhi0;
    const float* dinv = dinv2 + (size_t)dom * N_NODES;
    unsigned char* Tp = dom ? Tp1 : Tp0;
    int tid = threadIdx.x;
    int wid = tid >> 6, lane = tid & 63;
    int l15 = lane & 15;
    int kg = (lane >> 4) * 8;
    int row0 = bid * 128 + wid * 32;   // wave: rows row0..row0+31 (strips at +0, +16)
    int rA0 = row0 + l15;
    int rA1 = row0 + 16 + l15;
    f32x4 acc[2][8] = {};
    #pragma unroll
    for (int ph = 0; ph < 2; ph++) {
        if (ph) __syncthreads();   // protect LDS before overwrite
        #pragma unroll
        for (int i = 0; i < 8; i++) {
            int arr = i >> 2;
            int f = tid + (i & 3) * 256;            // 0..1023
            int l = f & 63;
            int nr = ((f >> 6) & 7) * 16 + (l & 15);
            int kc = (2 * ph + (f >> 9)) * 32 + (l >> 4) * 8;
            const ushort* srcp = (arr ? Wlo : Whi) + nr * 128 + kc;
            *(uint4v*)&ldsW[arr][(size_t)f * 8] = *(const uint4v*)srcp;
        }
        __syncthreads();
        #pragma unroll
        for (int gg = 0; gg < 2; gg++) {
            int g = 2 * ph + gg;
            int k0 = g * 32 + kg;
            UB a0hi, a0lo, a1hi, a1lo;
            if (F32A) {
                #pragma unroll
                for (int s = 0; s < 2; s++) {
                    int rA = s ? rA1 : rA0;
                    float4 f0 = make_float4(0.f, 0.f, 0.f, 0.f), f1 = f0;
                    if (rA < M) {
                        f0 = *(const float4*)&Xf[(size_t)rA * 128 + k0];
                        f1 = *(const float4*)&Xf[(size_t)rA * 128 + k0 + 4];
                    }
                    float fv[8] = {f0.x, f0.y, f0.z, f0.w, f1.x, f1.y, f1.z, f1.w};
                    ushort h[8], l[8];
                    #pragma unroll
                    for (int j = 0; j < 8; j++) { h[j] = f2b(fv[j]); l[j] = f2b(fv[j] - b2f(h[j])); }
                    uint4v hu = uint4v{(uint)h[0] | ((uint)h[1] << 16), (uint)h[2] | ((uint)h[3] << 16),
                                       (uint)h[4] | ((uint)h[5] << 16), (uint)h[6] | ((uint)h[7] << 16)};
                    uint4v lu = uint4v{(uint)l[0] | ((uint)l[1] << 16), (uint)l[2] | ((uint)l[3] << 16),
                                       (uint)l[4] | ((uint)l[5] << 16), (uint)l[6] | ((uint)l[7] << 16)};
                    if (s) { a1hi.u = hu; a1lo.u = lu; } else { a0hi.u = hu; a0lo.u = lu; }
                }
            } else {
                a0hi.u = *(const uint4v*)&Xhi[(size_t)rA0 * 128 + k0];
                a1hi.u = *(const uint4v*)&Xhi[(size_t)rA1 * 128 + k0];
            }
            #pragma unroll
            for (int n = 0; n < 8; n++) {
                int fbase = ((gg * 8 + n) * 64 + lane) * 8;
                UB bhi, blo;
                bhi.u = *(const uint4v*)&ldsW[0][fbase];
                blo.u = *(const uint4v*)&ldsW[1][fbase];
                acc[0][n] = __builtin_amdgcn_mfma_f32_16x16x32_bf16(a0hi.b, bhi.b, acc[0][n], 0, 0, 0);
                acc[0][n] = __builtin_amdgcn_mfma_f32_16x16x32_bf16(a0hi.b, blo.b, acc[0][n], 0, 0, 0);
                if (F32A)
                    acc[0][n] = __builtin_amdgcn_mfma_f32_16x16x32_bf16(a0lo.b, bhi.b, acc[0][n], 0, 0, 0);
                acc[1][n] = __builtin_amdgcn_mfma_f32_16x16x32_bf16(a1hi.b, bhi.b, acc[1][n], 0, 0, 0);
                acc[1][n] = __builtin_amdgcn_mfma_f32_16x16x32_bf16(a1hi.b, blo.b, acc[1][n], 0, 0, 0);
                if (F32A)
                    acc[1][n] = __builtin_amdgcn_mfma_f32_16x16x32_bf16(a1lo.b, bhi.b, acc[1][n], 0, 0, 0);
            }
        }
    }
    #pragma unroll
    for (int s = 0; s < 2; s++) {
        int rbase = row0 + s * 16 + (lane >> 4) * 4;
        #pragma unroll
        for (int r = 0; r < 4; r++) {
            int row = rbase + r;
            if (row < M) {
                float dv = dinv[row];
                #pragma unroll
                for (int n = 0; n < 8; n++)
                    Tp[(size_t)row * 128 + n * 16 + l15] = (unsigned char)f2e4m3(dv * acc[s][n][r]);
            }
        }
    }
}

// ---------------- aggregate (merged doms) + fused per-node head dots ----------------

template<bool STORE_F>
__global__ __launch_bounds__(256) void aggregate_k(
        const unsigned char* __restrict__ Tp0, const unsigned char* __restrict__ Tp1,
        const int* __restrict__ idxb, const int* __restrict__ off, const int* __restrict__ deg,
        const float* __restrict__ dinv2, const float* __restrict__ bias,
        const float* __restrict__ Wp, const float* __restrict__ Wdu, const float* __restrict__ Wdi,
        int loff, float* __restrict__ nd0, float* __restrict__ nd1,
        ushort* __restrict__ ohi0, ushort* __restrict__ ohi1, int N, int gHalf) {
    int bid = blockIdx.x;
    int dom = bid >= gHalf;
    bid -= dom * gHalf;
    const unsigned char* Tp = dom ? Tp1 : Tp0;
    const int* idxd = idxb + (size_t)dom * NBUCK * SCAP;
    const int* offd = off + (size_t)dom * N_NODES;
    const int* degd = deg + (size_t)dom * N_NODES;
    const float* dinv = dinv2 + (size_t)dom * N_NODES;
    float* nd = dom ? nd1 : nd0;
    ushort* ohi = dom ? ohi1 : ohi0;

    int w = threadIdx.x >> 6, lane = threadIdx.x & 63;
    int d = bid * 4 + w;
    int grp = lane >> 4, li = lane & 15;
    int db = li * 8;   // first dim this lane owns
    if (d >= N) {   // pad rows for GEMM tiles: keep zeroed
        if (STORE_F && grp == 0) *(uint4*)&ohi[(size_t)d * 128 + db] = make_uint4(0, 0, 0, 0);
        return;
    }
    f32x2 A0 = {0.f, 0.f}, A1 = {0.f, 0.f}, A2 = {0.f, 0.f}, A3 = {0.f, 0.f};
    int o = offd[d];
    int cnt = degd[d] + 1;   // position 0 = self
    unsigned laneoff = (unsigned)(li << 3);
    for (int c = 0; c < cnt; c += 64) {
        int p = c + lane;
        int id = ZROW;
        if (p < cnt) id = (p == 0) ? d : idxd[o + p - 1];
        int m = min(64, cnt - c);
        #pragma unroll 4
        for (int jj = 0; jj * 4 < m; jj++) {
            int s = __shfl(id, jj * 4 + grp);
            uint2 u = *(const uint2*)(Tp + (((unsigned)s << 7) | laneoff));
#if __has_builtin(__builtin_amdgcn_cvt_pk_f32_fp8)
            A0 += __builtin_amdgcn_cvt_pk_f32_fp8(u.x, false);
            A1 += __builtin_amdgcn_cvt_pk_f32_fp8(u.x, true);
            A2 += __builtin_amdgcn_cvt_pk_f32_fp8(u.y, false);
            A3 += __builtin_amdgcn_cvt_pk_f32_fp8(u.y, true);
#else
            A0 += f32x2{e4m3f(u.x & 0xFF),         e4m3f((u.x >> 8) & 0xFF)};
            A1 += f32x2{e4m3f((u.x >> 16) & 0xFF), e4m3f(u.x >> 24)};
            A2 += f32x2{e4m3f(u.y & 0xFF),         e4m3f((u.y >> 8) & 0xFF)};
            A3 += f32x2{e4m3f((u.y >> 16) & 0xFF), e4m3f(u.y >> 24)};
#endif
        }
    }
    float a0 = A0[0], a1 = A0[1], a2 = A1[0], a3 = A1[1];
    float a4 = A2[0], a5 = A2[1], a6 = A3[0], a7 = A3[1];
    #define RED2(x) { x += __shfl_xor(x, 16); x += __shfl_xor(x, 32); }
    RED2(a0) RED2(a1) RED2(a2) RED2(a3) RED2(a4) RED2(a5) RED2(a6) RED2(a7)
    #undef RED2
    float di = dinv[d];
    float4 b0 = *(const float4*)&bias[db];
    float4 b1 = *(const float4*)&bias[db + 4];
    float f0 = fmaxf(di * a0 + b0.x, 0.f);
    float f1 = fmaxf(di * a1 + b0.y, 0.f);
    float f2 = fmaxf(di * a2 + b0.z, 0.f);
    float f3 = fmaxf(di * a3 + b0.w, 0.f);
    float f4 = fmaxf(di * a4 + b1.x, 0.f);
    float f5 = fmaxf(di * a5 + b1.y, 0.f);
    float f6 = fmaxf(di * a6 + b1.z, 0.f);
    float f7 = fmaxf(di * a7 + b1.w, 0.f);
    if (STORE_F && grp == 0) {
        ushort h0 = f2b(f0), h1 = f2b(f1), h2 = f2b(f2), h3 = f2b(f3);
        ushort h4 = f2b(f4), h5 = f2b(f5), h6 = f2b(f6), h7 = f2b(f7);
        uint4 hv = make_uint4((uint)h0 | ((uint)h1 << 16), (uint)h2 | ((uint)h3 << 16),
                              (uint)h4 | ((uint)h5 << 16), (uint)h6 | ((uint)h7 << 16));
        *(uint4*)&ohi[(size_t)d * 128 + db] = hv;
    }
    const float* wsel = (grp == 0) ? Wp + loff : (grp == 1) ? Wp + 256 + loff
                      : (grp == 2) ? Wdu + loff : Wdi + loff;
    float4 w0 = *(const float4*)&wsel[db];
    float4 w1 = *(const float4*)&wsel[db + 4];
    float dt = f0 * w0.x + f1 * w0.y + f2 * w0.z + f3 * w0.w
             + f4 * w1.x + f5 * w1.y + f6 * w1.z + f7 * w1.w;
    dt += __shfl_xor(dt, 1); dt += __shfl_xor(dt, 2);
    dt += __shfl_xor(dt, 4); dt += __shfl_xor(dt, 8);
    if (li == 0) nd[(size_t)d * 4 + grp] = dt;
}

// ---------------- loss (merged doms) ----------------

__device__ __forceinline__ float sp100(float z) {   // min(softplus(z),100)
    float sp = (z > 0.f) ? (z + log1pf(expf(-z))) : log1pf(expf(z));
    return fminf(sp, 100.f);
}
__device__ __forceinline__ float wred64(float x) {
    #pragma unroll
    for (int o = 32; o > 0; o >>= 1) x += __shfl_xor(x, o);
    return x;
}

__global__ __launch_bounds__(256) void loss_k(
        const float4* __restrict__ nd1_0, const float4* __restrict__ nd1_1,
        const float4* __restrict__ nd2_0, const float4* __restrict__ nd2_1,
        const int* __restrict__ user0, const int* __restrict__ user1,
        const int* __restrict__ item0, const int* __restrict__ item1,
        const int* __restrict__ lab0, const int* __restrict__ lab1,
        const float* __restrict__ bp, const float* __restrict__ bdu, const float* __restrict__ bdi,
        float* __restrict__ acc, int B, int gHalf) {
    __shared__ float sh[3][4];
    int bid = blockIdx.x;
    int dom = bid >= gHalf;
    bid -= dom * gHalf;
    const float4* nd1 = dom ? nd1_1 : nd1_0;
    const float4* nd2 = dom ? nd2_1 : nd2_0;
    const int* user = dom ? user1 : user0;
    const int* item = dom ? item1 : item0;
    const int* labels = dom ? lab1 : lab0;
    int gtid = bid * blockDim.x + threadIdx.x;
    int nth = gHalf * blockDim.x;
    float bpv = bp[0], bduv = bdu[0], bdiv = bdi[0];
    float lp = 0.f, lu = 0.f, li = 0.f;
    for (int s = gtid; s < B; s += nth) {
        int u = user[s];
        int it = item[s] + NUM_USER;
        float4 a = nd1[u], b = nd2[u], c = nd1[it], dd = nd2[it];
        float zp = a.x + b.x + c.y + dd.y + bpv;
        float zu = a.z + b.z + bduv;
        float zi = c.w + dd.w + bdiv;
        lp += labels[s] ? sp100(-zp) : sp100(zp);
        lu += dom ? sp100(-zu) : sp100(zu);
        li += dom ? sp100(-zi) : sp100(zi);
    }
    lp = wred64(lp); lu = wred64(lu); li = wred64(li);
    int lane = threadIdx.x & 63, w = threadIdx.x >> 6;
    if (lane == 0) { sh[0][w] = lp; sh[1][w] = lu; sh[2][w] = li; }
    __syncthreads();
    if (threadIdx.x == 0) {
        float s0 = 0.f, s1 = 0.f, s2 = 0.f;
        for (int j = 0; j < 4; j++) { s0 += sh[0][j]; s1 += sh[1][j]; s2 += sh[2][j]; }
        atomicAdd(&acc[dom], s0);
        atomicAdd(&acc[2], s1);
        atomicAdd(&acc[3], s2);
    }
}

__global__ void fin_k(const float* __restrict__ acc, float* __restrict__ out, int B) {
    float invB = 1.f / (float)B;
    out[0] = acc[0] * invB + acc[1] * invB + 0.1f * ((acc[2] + acc[3]) * (0.5f * invB));
}

// ---------------- orchestration ----------------

extern "C" void kernel_launch(void* const* d_in, const int* in_sizes, int n_in,
                              void* d_out, int out_size, void* d_ws, size_t ws_size,
                              hipStream_t stream) {
    const float* feats[2] = {(const float*)d_in[0], (const float*)d_in[1]};
    const int* adj[2]    = {(const int*)d_in[2], (const int*)d_in[3]};
    const int* user[2]   = {(const int*)d_in[4], (const int*)d_in[7]};
    const int* item[2]   = {(const int*)d_in[5], (const int*)d_in[8]};
    const int* labels[2] = {(const int*)d_in[6], (const int*)d_in[9]};
    const float* Wl[2] = {(const float*)d_in[10], (const float*)d_in[12]};
    const float* bl[2] = {(const float*)d_in[11], (const float*)d_in[13]};
    const float* Wp  = (const float*)d_in[14];
    const float* bp  = (const float*)d_in[15];
    const float* Wdu = (const float*)d_in[16];
    const float* bdu = (const float*)d_in[17];
    const float* Wdi = (const float*)d_in[18];
    const float* bdi = (const float*)d_in[19];

    const int E = in_sizes[2] / 2;
    const int B = in_sizes[4];
    const int N = N_NODES;

    char* w = (char*)d_ws;
    unsigned char* Tp0 = (unsigned char*)w; w += (size_t)MPAD * 128;
    unsigned char* Tp1 = (unsigned char*)w; w += (size_t)MPAD * 128;
    ushort* Fhi0 = (ushort*)w; w += (size_t)MPAD * 128 * 2;
    ushort* Fhi1 = (ushort*)w; w += (size_t)MPAD * 128 * 2;
    ushort* W1h  = (ushort*)w; w += 16384 * 2;
    ushort* W1l  = (ushort*)w; w += 16384 * 2;
    ushort* W2h  = (ushort*)w; w += 16384 * 2;
    ushort* W2l  = (ushort*)w; w += 16384 * 2;
    float* nd1_0 = (float*)w; w += (size_t)MPAD * 16;
    float* nd1_1 = (float*)w; w += (size_t)MPAD * 16;
    float* nd2_0 = (float*)w; w += (size_t)MPAD * 16;
    float* nd2_1 = (float*)w; w += (size_t)MPAD * 16;
    int*   deg  = (int*)w;   w += (size_t)2 * N * 4;
    float* dinv = (float*)w; w += (size_t)2 * N * 4;
    int*   off  = (int*)w;   w += (size_t)2 * N * 4;
    int*   idxb = (int*)w;   w += (size_t)2 * NBUCK * SCAP * 4;
    unsigned int* stg = (unsigned int*)w; w += (size_t)2 * NBUCK * SCAP * 4;
    int*   bcnt = (int*)w;   w += 2 * NBUCK * 4;
    float* acc  = (float*)w; w += 64;

    int nbE = (E + EPB - 1) / EPB;
    int nbB = (N + NPB - 1) / NPB;
    int gMM = MPAD / 128;
    int gAG = MPAD / 4;

    init_k<<<131, 256, 0, stream>>>(Wl[0], Wl[1], W1h, W1l, W2h, W2l, Tp0, Tp1, acc, bcnt);

    bin2_k<<<2 * nbE, 256, 0, stream>>>(adj[0], adj[1], bcnt, stg, E, nbE);
    csr_k<<<2 * nbB, 256, 0, stream>>>(stg, bcnt, deg, dinv, off, idxb, N, nbB);

    // layer 1 (both domains merged per stage)
    mm_k<true><<<2 * gMM, 256, 0, stream>>>(feats[0], feats[1], nullptr, nullptr,
                                            W1h, W1l, dinv, Tp0, Tp1, N, gMM);
    aggregate_k<true><<<2 * gAG, 256, 0, stream>>>(Tp0, Tp1, idxb, off, deg, dinv, bl[0],
                                                   Wp, Wdu, Wdi, 0, nd1_0, nd1_1, Fhi0, Fhi1, N, gAG);
    // layer 2
    mm_k<false><<<2 * gMM, 256, 0, stream>>>(nullptr, nullptr, Fhi0, Fhi1,
                                             W2h, W2l, dinv, Tp0, Tp1, N, gMM);
    aggregate_k<false><<<2 * gAG, 256, 0, stream>>>(Tp0, Tp1, idxb, off, deg, dinv, bl[1],
                                                    Wp, Wdu, Wdi, 128, nd2_0, nd2_1, nullptr, nullptr, N, gAG);

    loss_k<<<256, 256, 0, stream>>>((const float4*)nd1_0, (const float4*)nd1_1,
                                    (const float4*)nd2_0, (const float4*)nd2_1,
                                    user[0], user[1], item[0], item[1], labels[0], labels[1],
                                    bp, bdu, bdi, acc, B, 128);
    fin_k<<<1, 1, 0, stream>>>(acc, (float*)d_out, B);
}

// Round 14
// 334.956 us; speedup vs baseline: 2.9253x; 1.2137x over previous
//
#include <hip/hip_runtime.h>

#define N_NODES 110000
#define NUM_USER 60000
#define MPAD 110080        // N_NODES padded to 128-row GEMM tiles
#define ZROW N_NODES       // dedicated all-zero row (rows N..MPAD-1 zeroed in init)
#define BSHIFT 9           // bucket = dst >> 9  (512 nodes per bucket)
#define NBUCK 256
#define NPB 512            // nodes per bucket
#define EPB 8192           // edges per block in bin
#define SCAP 9216          // fixed per-bucket capacity (mean 7447, sigma 86 -> +20 sigma)

typedef __attribute__((ext_vector_type(8))) __bf16 bf16x8;
typedef __attribute__((ext_vector_type(4))) float f32x4;
typedef __attribute__((ext_vector_type(2))) float f32x2;
typedef __attribute__((ext_vector_type(4))) unsigned int uint4v;

union UB { uint4v u; bf16x8 b; };

__device__ __forceinline__ unsigned short f2b(float f) {   // f32 -> bf16 RNE
    unsigned int u = __float_as_uint(f);
    unsigned int r = (u + 0x7FFFu + ((u >> 16) & 1u)) >> 16;
    return (unsigned short)r;
}
__device__ __forceinline__ float b2f(unsigned short h) {
    return __uint_as_float(((unsigned int)h) << 16);
}
// f32 -> fp8 e4m3 (OCP) RNE via exact 2^-120 scaling trick (handles subnormals)
__device__ __forceinline__ unsigned f2e4m3(float x) {
    unsigned u = __float_as_uint(x * 0x1p-120f);
    unsigned r = u + 0x7FFFFu + ((u >> 20) & 1u);
    return ((r >> 20) & 0x7Fu) | ((u >> 24) & 0x80u);
}
__device__ __forceinline__ float e4m3f(unsigned v) {   // fallback decode
    unsigned bits = ((v & 0x80u) << 24) | ((v & 0x7Fu) << 20);
    return __uint_as_float(bits) * 0x1p+120f;
}

// ---------------- init: weight conv + pad-row zero + counters zero ----------------

__global__ __launch_bounds__(256) void init_k(const float* __restrict__ W1, const float* __restrict__ W2,
        ushort* __restrict__ W1h, ushort* __restrict__ W1l,
        ushort* __restrict__ W2h, ushort* __restrict__ W2l,
        unsigned char* __restrict__ Tp0, unsigned char* __restrict__ Tp1,
        float* __restrict__ acc, int* __restrict__ bcnt) {
    int b = blockIdx.x, tid = threadIdx.x;
    if (b < 128) {
        const float* W = (b < 64) ? W1 : W2;
        ushort* hi = (b < 64) ? W1h : W2h;
        ushort* lo = (b < 64) ? W1l : W2l;
        int i = (b & 63) * 256 + tid;   // 16384 total
        int k = i >> 7, n = i & 127;
        float w = W[i];
        ushort h = f2b(w);
        hi[(n << 7) | k] = h;
        lo[(n << 7) | k] = f2b(w - b2f(h));
    } else if (b < 130) {
        unsigned char* Tp = (b == 128) ? Tp0 : Tp1;
        for (int j = tid; j < (MPAD - N_NODES) * 128; j += 256)
            Tp[(size_t)N_NODES * 128 + j] = 0;
    } else {
        if (tid < 16) acc[tid] = 0.f;
        bcnt[tid] = 0;          // dom 0
        bcnt[256 + tid] = 0;    // dom 1
    }
}

// ---------------- single-pass binning: LDS hist + atomic region grab + scatter ----------------

__global__ __launch_bounds__(256) void bin2_k(const int* __restrict__ adj0, const int* __restrict__ adj1,
        int* __restrict__ bcnt, unsigned int* __restrict__ stg, int E, int nbE) {
    __shared__ int h[NBUCK];
    __shared__ int lcur[NBUCK];
    int b = blockIdx.x, tid = threadIdx.x;
    int dom = b / nbE, blk = b - dom * nbE;
    const int* src = (dom ? adj1 : adj0);
    const int* dst = src + E;
    unsigned int* sg = stg + (size_t)dom * NBUCK * SCAP;
    h[tid] = 0;
    __syncthreads();
    int base = blk * EPB, end = min(base + EPB, E);
    for (int i = base + tid * 4; i + 3 < end; i += 1024) {
        int4 d = *(const int4*)&dst[i];
        atomicAdd(&h[d.x >> BSHIFT], 1); atomicAdd(&h[d.y >> BSHIFT], 1);
        atomicAdd(&h[d.z >> BSHIFT], 1); atomicAdd(&h[d.w >> BSHIFT], 1);
    }
    __syncthreads();
    lcur[tid] = tid * SCAP + atomicAdd(&bcnt[dom * NBUCK + tid], h[tid]);
    __syncthreads();
    for (int i = base + tid * 4; i + 3 < end; i += 1024) {
        int4 s = *(const int4*)&src[i];
        int4 d = *(const int4*)&dst[i];
        int p;
        p = atomicAdd(&lcur[d.x >> BSHIFT], 1); sg[p] = (unsigned)s.x | ((unsigned)(d.x & (NPB - 1)) << 17);
        p = atomicAdd(&lcur[d.y >> BSHIFT], 1); sg[p] = (unsigned)s.y | ((unsigned)(d.y & (NPB - 1)) << 17);
        p = atomicAdd(&lcur[d.z >> BSHIFT], 1); sg[p] = (unsigned)s.z | ((unsigned)(d.z & (NPB - 1)) << 17);
        p = atomicAdd(&lcur[d.w >> BSHIFT], 1); sg[p] = (unsigned)s.w | ((unsigned)(d.w & (NPB - 1)) << 17);
    }
}

__global__ __launch_bounds__(256) void csr_k(const unsigned int* __restrict__ stg,
        const int* __restrict__ bcnt,
        int* __restrict__ deg, float* __restrict__ dinv, int* __restrict__ off,
        int* __restrict__ idxb, int N, int nbB) {
    __shared__ int ldeg[NPB];
    __shared__ int lcur[NPB];
    __shared__ int shp[256];
    __shared__ unsigned int lidx[SCAP];
    int b = blockIdx.x, tid = threadIdx.x;
    int dom = b / nbB, blk = b - dom * nbB;
    const unsigned int* sg = stg + ((size_t)dom * NBUCK + blk) * SCAP;
    int* degd = deg + (size_t)dom * N_NODES;
    float* dinvd = dinv + (size_t)dom * N_NODES;
    int* offd = off + (size_t)dom * N_NODES;
    int* idxd = idxb + (size_t)dom * NBUCK * SCAP;
    int node0 = blk * NPB;
    int base = blk * SCAP;                       // within-dom padded offset
    int cnt = bcnt[dom * NBUCK + blk];
    ldeg[tid] = 0; ldeg[tid + 256] = 0;
    __syncthreads();
    for (int i = tid; i < cnt; i += 256)
        atomicAdd(&ldeg[sg[i] >> 17], 1);
    __syncthreads();
    int a0 = ldeg[2 * tid], a1 = ldeg[2 * tid + 1];
    shp[tid] = a0 + a1;
    __syncthreads();
    for (int o = 1; o < 256; o <<= 1) {
        int v = (tid >= o) ? shp[tid - o] : 0;
        __syncthreads();
        shp[tid] += v;
        __syncthreads();
    }
    int excl = shp[tid] - a0 - a1;
    lcur[2 * tid] = excl;
    lcur[2 * tid + 1] = excl + a0;
    int n0 = node0 + 2 * tid;
    if (n0 < N)     { degd[n0] = a0;     dinvd[n0] = rsqrtf(a0 + 1.f);     offd[n0] = base + excl; }
    if (n0 + 1 < N) { degd[n0 + 1] = a1; dinvd[n0 + 1] = rsqrtf(a1 + 1.f); offd[n0 + 1] = base + excl + a0; }
    __syncthreads();
    for (int i = tid; i < cnt; i += 256) {
        unsigned e = sg[i];
        int p = atomicAdd(&lcur[e >> 17], 1);
        if (p < SCAP) lidx[p] = e & 0x1FFFFu;
    }
    __syncthreads();
    for (int i = tid; i < cnt; i += 256)
        idxd[base + i] = (int)lidx[i];
}

// ---------------- GEMM (merged doms): T'(fp8) = dinv[row]*(A@W), LDS-staged W, 2 strips/wave --

template<bool F32A>
__global__ __launch_bounds__(256) void mm_k(const float* __restrict__ Xf0, const float* __restrict__ Xf1,
        const ushort* __restrict__ Xhi0, const ushort* __restrict__ Xhi1,
        const ushort* __restrict__ Whi, const ushort* __restrict__ Wlo,   // [n][k]
        const float* __restrict__ dinv2, unsigned char* __restrict__ Tp0, unsigned char* __restrict__ Tp1,
        int M, int gHalf) {
    __shared__ ushort ldsW[2][1024 * 8];   // [hi/lo][1024 frags x 8 ushorts] = 32 KB
    int bid = blockIdx.x;
    int dom = bid >= gHalf;
    bid -= dom * gHalf;
    const float* Xf = dom ? Xf1 : Xf0;
    const ushort* Xhi = dom ? Xhi1 : Xhi0;
    const float* dinv = dinv2 + (size_t)dom * N_NODES;
    unsigned char* Tp = dom ? Tp1 : Tp0;
    int tid = threadIdx.x;
    int wid = tid >> 6, lane = tid & 63;
    int l15 = lane & 15;
    int kg = (lane >> 4) * 8;
    int row0 = bid * 128 + wid * 32;   // wave: rows row0..row0+31 (strips at +0, +16)
    int rA0 = row0 + l15;
    int rA1 = row0 + 16 + l15;
    f32x4 acc[2][8] = {};
    #pragma unroll
    for (int ph = 0; ph < 2; ph++) {
        if (ph) __syncthreads();   // protect LDS before overwrite
        #pragma unroll
        for (int i = 0; i < 8; i++) {
            int arr = i >> 2;
            int f = tid + (i & 3) * 256;            // 0..1023
            int l = f & 63;
            int nr = ((f >> 6) & 7) * 16 + (l & 15);
            int kc = (2 * ph + (f >> 9)) * 32 + (l >> 4) * 8;
            const ushort* srcp = (arr ? Wlo : Whi) + nr * 128 + kc;
            *(uint4v*)&ldsW[arr][(size_t)f * 8] = *(const uint4v*)srcp;
        }
        __syncthreads();
        #pragma unroll
        for (int gg = 0; gg < 2; gg++) {
            int g = 2 * ph + gg;
            int k0 = g * 32 + kg;
            UB a0hi, a0lo, a1hi, a1lo;
            if (F32A) {
                #pragma unroll
                for (int s = 0; s < 2; s++) {
                    int rA = s ? rA1 : rA0;
                    float4 f0 = make_float4(0.f, 0.f, 0.f, 0.f), f1 = f0;
                    if (rA < M) {
                        f0 = *(const float4*)&Xf[(size_t)rA * 128 + k0];
                        f1 = *(const float4*)&Xf[(size_t)rA * 128 + k0 + 4];
                    }
                    float fv[8] = {f0.x, f0.y, f0.z, f0.w, f1.x, f1.y, f1.z, f1.w};
                    ushort h[8], l[8];
                    #pragma unroll
                    for (int j = 0; j < 8; j++) { h[j] = f2b(fv[j]); l[j] = f2b(fv[j] - b2f(h[j])); }
                    uint4v hu = uint4v{(uint)h[0] | ((uint)h[1] << 16), (uint)h[2] | ((uint)h[3] << 16),
                                       (uint)h[4] | ((uint)h[5] << 16), (uint)h[6] | ((uint)h[7] << 16)};
                    uint4v lu = uint4v{(uint)l[0] | ((uint)l[1] << 16), (uint)l[2] | ((uint)l[3] << 16),
                                       (uint)l[4] | ((uint)l[5] << 16), (uint)l[6] | ((uint)l[7] << 16)};
                    if (s) { a1hi.u = hu; a1lo.u = lu; } else { a0hi.u = hu; a0lo.u = lu; }
                }
            } else {
                a0hi.u = *(const uint4v*)&Xhi[(size_t)rA0 * 128 + k0];
                a1hi.u = *(const uint4v*)&Xhi[(size_t)rA1 * 128 + k0];
            }
            #pragma unroll
            for (int n = 0; n < 8; n++) {
                int fbase = ((gg * 8 + n) * 64 + lane) * 8;
                UB bhi, blo;
                bhi.u = *(const uint4v*)&ldsW[0][fbase];
                blo.u = *(const uint4v*)&ldsW[1][fbase];
                acc[0][n] = __builtin_amdgcn_mfma_f32_16x16x32_bf16(a0hi.b, bhi.b, acc[0][n], 0, 0, 0);
                acc[0][n] = __builtin_amdgcn_mfma_f32_16x16x32_bf16(a0hi.b, blo.b, acc[0][n], 0, 0, 0);
                if (F32A)
                    acc[0][n] = __builtin_amdgcn_mfma_f32_16x16x32_bf16(a0lo.b, bhi.b, acc[0][n], 0, 0, 0);
                acc[1][n] = __builtin_amdgcn_mfma_f32_16x16x32_bf16(a1hi.b, bhi.b, acc[1][n], 0, 0, 0);
                acc[1][n] = __builtin_amdgcn_mfma_f32_16x16x32_bf16(a1hi.b, blo.b, acc[1][n], 0, 0, 0);
                if (F32A)
                    acc[1][n] = __builtin_amdgcn_mfma_f32_16x16x32_bf16(a1lo.b, bhi.b, acc[1][n], 0, 0, 0);
            }
        }
    }
    #pragma unroll
    for (int s = 0; s < 2; s++) {
        int rbase = row0 + s * 16 + (lane >> 4) * 4;
        #pragma unroll
        for (int r = 0; r < 4; r++) {
            int row = rbase + r;
            if (row < M) {
                float dv = dinv[row];
                #pragma unroll
                for (int n = 0; n < 8; n++)
                    Tp[(size_t)row * 128 + n * 16 + l15] = (unsigned char)f2e4m3(dv * acc[s][n][r]);
            }
        }
    }
}

// ---------------- aggregate (merged doms): 2 dsts/wave, direct idxb broadcast loads ----------
// Wave: lanes 0-31 -> dst A, lanes 32-63 -> dst B. Per half: 2 groups of 16 lanes, each group
// one edge in flight; lane li owns 8 fp8 dims (8 B of the 128-B row). Epilogue per half-wave.

template<bool STORE_F>
__global__ __launch_bounds__(256) void aggregate_k(
        const unsigned char* __restrict__ Tp0, const unsigned char* __restrict__ Tp1,
        const int* __restrict__ idxb, const int* __restrict__ off, const int* __restrict__ deg,
        const float* __restrict__ dinv2, const float* __restrict__ bias,
        const float* __restrict__ Wp, const float* __restrict__ Wdu, const float* __restrict__ Wdi,
        int loff, float* __restrict__ nd0, float* __restrict__ nd1,
        ushort* __restrict__ ohi0, ushort* __restrict__ ohi1, int N, int gHalf) {
    int bid = blockIdx.x;
    int dom = bid >= gHalf;
    bid -= dom * gHalf;
    const unsigned char* Tp = dom ? Tp1 : Tp0;
    const int* idxd = idxb + (size_t)dom * NBUCK * SCAP;
    const int* offd = off + (size_t)dom * N_NODES;
    const int* degd = deg + (size_t)dom * N_NODES;
    const float* dinv = dinv2 + (size_t)dom * N_NODES;
    float* nd = dom ? nd1 : nd0;
    ushort* ohi = dom ? ohi1 : ohi0;

    int w = threadIdx.x >> 6, lane = threadIdx.x & 63;
    int half = lane >> 5;              // 0: dst A, 1: dst B
    int grp = (lane >> 4) & 1;         // group within half
    int li = lane & 15;
    int d = bid * 8 + w * 2 + half;
    int db = li * 8;                   // first dim this lane owns
    bool valid = d < N;
    int o = 0, cnt = 0;
    if (valid) { o = offd[d]; cnt = degd[d] + 1; }   // position 0 = self
    int cmax = max(cnt, __shfl_xor(cnt, 32));
    if (!valid) {
        if (STORE_F && grp == 0) *(uint4*)&ohi[(size_t)d * 128 + db] = make_uint4(0, 0, 0, 0);
        return;
    }
    f32x2 A0 = {0.f, 0.f}, A1 = {0.f, 0.f}, A2 = {0.f, 0.f}, A3 = {0.f, 0.f};
    unsigned laneoff = (unsigned)(li << 3);
    int ob = o + grp - 1;   // idxb index for p = c + jj*2 + grp is ob + c + jj*2
    for (int c = 0; c < cmax; c += 32) {
        int m = min(32, cmax - c);
        #pragma unroll 4
        for (int jj = 0; jj * 2 < m; jj++) {
            int p = c + jj * 2 + grp;
            int ia = max(ob + c + jj * 2, 0);
            int iv = idxd[ia];                       // same addr across 16 lanes -> broadcast
            int id = (p == 0) ? d : ((p < cnt) ? iv : ZROW);
            uint2 u = *(const uint2*)(Tp + (((unsigned)id << 7) | laneoff));
#if __has_builtin(__builtin_amdgcn_cvt_pk_f32_fp8)
            A0 += __builtin_amdgcn_cvt_pk_f32_fp8(u.x, false);
            A1 += __builtin_amdgcn_cvt_pk_f32_fp8(u.x, true);
            A2 += __builtin_amdgcn_cvt_pk_f32_fp8(u.y, false);
            A3 += __builtin_amdgcn_cvt_pk_f32_fp8(u.y, true);
#else
            A0 += f32x2{e4m3f(u.x & 0xFF),         e4m3f((u.x >> 8) & 0xFF)};
            A1 += f32x2{e4m3f((u.x >> 16) & 0xFF), e4m3f(u.x >> 24)};
            A2 += f32x2{e4m3f(u.y & 0xFF),         e4m3f((u.y >> 8) & 0xFF)};
            A3 += f32x2{e4m3f((u.y >> 16) & 0xFF), e4m3f(u.y >> 24)};
#endif
        }
    }
    float a0 = A0[0], a1 = A0[1], a2 = A1[0], a3 = A1[1];
    float a4 = A2[0], a5 = A2[1], a6 = A3[0], a7 = A3[1];
    // reduce across the 2 groups of this half (xor16 stays within the half)
    #define RED1(x) { x += __shfl_xor(x, 16); }
    RED1(a0) RED1(a1) RED1(a2) RED1(a3) RED1(a4) RED1(a5) RED1(a6) RED1(a7)
    #undef RED1
    float di = dinv[d];
    float4 b0 = *(const float4*)&bias[db];
    float4 b1 = *(const float4*)&bias[db + 4];
    float f0 = fmaxf(di * a0 + b0.x, 0.f);
    float f1 = fmaxf(di * a1 + b0.y, 0.f);
    float f2 = fmaxf(di * a2 + b0.z, 0.f);
    float f3 = fmaxf(di * a3 + b0.w, 0.f);
    float f4 = fmaxf(di * a4 + b1.x, 0.f);
    float f5 = fmaxf(di * a5 + b1.y, 0.f);
    float f6 = fmaxf(di * a6 + b1.z, 0.f);
    float f7 = fmaxf(di * a7 + b1.w, 0.f);
    if (STORE_F && grp == 0) {
        ushort h0 = f2b(f0), h1 = f2b(f1), h2 = f2b(f2), h3 = f2b(f3);
        ushort h4 = f2b(f4), h5 = f2b(f5), h6 = f2b(f6), h7 = f2b(f7);
        uint4 hv = make_uint4((uint)h0 | ((uint)h1 << 16), (uint)h2 | ((uint)h3 << 16),
                              (uint)h4 | ((uint)h5 << 16), (uint)h6 | ((uint)h7 << 16));
        *(uint4*)&ohi[(size_t)d * 128 + db] = hv;
    }
    // head dots: group 0 -> {Wp_user, Wp_item}; group 1 -> {Wdu, Wdi}
    const float* ws0 = grp ? Wdu + loff : Wp + loff;
    const float* ws1 = grp ? Wdi + loff : Wp + 256 + loff;
    float4 w00 = *(const float4*)&ws0[db];
    float4 w01 = *(const float4*)&ws0[db + 4];
    float4 w10 = *(const float4*)&ws1[db];
    float4 w11 = *(const float4*)&ws1[db + 4];
    float dt0 = f0 * w00.x + f1 * w00.y + f2 * w00.z + f3 * w00.w
              + f4 * w01.x + f5 * w01.y + f6 * w01.z + f7 * w01.w;
    float dt1 = f0 * w10.x + f1 * w10.y + f2 * w10.z + f3 * w10.w
              + f4 * w11.x + f5 * w11.y + f6 * w11.z + f7 * w11.w;
    dt0 += __shfl_xor(dt0, 1); dt1 += __shfl_xor(dt1, 1);
    dt0 += __shfl_xor(dt0, 2); dt1 += __shfl_xor(dt1, 2);
    dt0 += __shfl_xor(dt0, 4); dt1 += __shfl_xor(dt1, 4);
    dt0 += __shfl_xor(dt0, 8); dt1 += __shfl_xor(dt1, 8);
    if (li == 0) *(float2*)&nd[(size_t)d * 4 + grp * 2] = make_float2(dt0, dt1);
}

// ---------------- loss (merged doms) ----------------

__device__ __forceinline__ float sp100(float z) {   // min(softplus(z),100)
    float sp = (z > 0.f) ? (z + log1pf(expf(-z))) : log1pf(expf(z));
    return fminf(sp, 100.f);
}
__device__ __forceinline__ float wred64(float x) {
    #pragma unroll
    for (int o = 32; o > 0; o >>= 1) x += __shfl_xor(x, o);
    return x;
}

__global__ __launch_bounds__(256) void loss_k(
        const float4* __restrict__ nd1_0, const float4* __restrict__ nd1_1,
        const float4* __restrict__ nd2_0, const float4* __restrict__ nd2_1,
        const int* __restrict__ user0, const int* __restrict__ user1,
        const int* __restrict__ item0, const int* __restrict__ item1,
        const int* __restrict__ lab0, const int* __restrict__ lab1,
        const float* __restrict__ bp, const float* __restrict__ bdu, const float* __restrict__ bdi,
        float* __restrict__ acc, int B, int gHalf) {
    __shared__ float sh[3][4];
    int bid = blockIdx.x;
    int dom = bid >= gHalf;
    bid -= dom * gHalf;
    const float4* nd1 = dom ? nd1_1 : nd1_0;
    const float4* nd2 = dom ? nd2_1 : nd2_0;
    const int* user = dom ? user1 : user0;
    const int* item = dom ? item1 : item0;
    const int* labels = dom ? lab1 : lab0;
    int gtid = bid * blockDim.x + threadIdx.x;
    int nth = gHalf * blockDim.x;
    float bpv = bp[0], bduv = bdu[0], bdiv = bdi[0];
    float lp = 0.f, lu = 0.f, li = 0.f;
    for (int s = gtid; s < B; s += nth) {
        int u = user[s];
        int it = item[s] + NUM_USER;
        float4 a = nd1[u], b = nd2[u], c = nd1[it], dd = nd2[it];
        float zp = a.x + b.x + c.y + dd.y + bpv;
        float zu = a.z + b.z + bduv;
        float zi = c.w + dd.w + bdiv;
        lp += labels[s] ? sp100(-zp) : sp100(zp);
        lu += dom ? sp100(-zu) : sp100(zu);
        li += dom ? sp100(-zi) : sp100(zi);
    }
    lp = wred64(lp); lu = wred64(lu); li = wred64(li);
    int lane = threadIdx.x & 63, w = threadIdx.x >> 6;
    if (lane == 0) { sh[0][w] = lp; sh[1][w] = lu; sh[2][w] = li; }
    __syncthreads();
    if (threadIdx.x == 0) {
        float s0 = 0.f, s1 = 0.f, s2 = 0.f;
        for (int j = 0; j < 4; j++) { s0 += sh[0][j]; s1 += sh[1][j]; s2 += sh[2][j]; }
        atomicAdd(&acc[dom], s0);
        atomicAdd(&acc[2], s1);
        atomicAdd(&acc[3], s2);
    }
}

__global__ void fin_k(const float* __restrict__ acc, float* __restrict__ out, int B) {
    float invB = 1.f / (float)B;
    out[0] = acc[0] * invB + acc[1] * invB + 0.1f * ((acc[2] + acc[3]) * (0.5f * invB));
}

// ---------------- orchestration ----------------

extern "C" void kernel_launch(void* const* d_in, const int* in_sizes, int n_in,
                              void* d_out, int out_size, void* d_ws, size_t ws_size,
                              hipStream_t stream) {
    const float* feats[2] = {(const float*)d_in[0], (const float*)d_in[1]};
    const int* adj[2]    = {(const int*)d_in[2], (const int*)d_in[3]};
    const int* user[2]   = {(const int*)d_in[4], (const int*)d_in[7]};
    const int* item[2]   = {(const int*)d_in[5], (const int*)d_in[8]};
    const int* labels[2] = {(const int*)d_in[6], (const int*)d_in[9]};
    const float* Wl[2] = {(const float*)d_in[10], (const float*)d_in[12]};
    const float* bl[2] = {(const float*)d_in[11], (const float*)d_in[13]};
    const float* Wp  = (const float*)d_in[14];
    const float* bp  = (const float*)d_in[15];
    const float* Wdu = (const float*)d_in[16];
    const float* bdu = (const float*)d_in[17];
    const float* Wdi = (const float*)d_in[18];
    const float* bdi = (const float*)d_in[19];

    const int E = in_sizes[2] / 2;
    const int B = in_sizes[4];
    const int N = N_NODES;

    char* w = (char*)d_ws;
    unsigned char* Tp0 = (unsigned char*)w; w += (size_t)MPAD * 128;
    unsigned char* Tp1 = (unsigned char*)w; w += (size_t)MPAD * 128;
    ushort* Fhi0 = (ushort*)w; w += (size_t)MPAD * 128 * 2;
    ushort* Fhi1 = (ushort*)w; w += (size_t)MPAD * 128 * 2;
    ushort* W1h  = (ushort*)w; w += 16384 * 2;
    ushort* W1l  = (ushort*)w; w += 16384 * 2;
    ushort* W2h  = (ushort*)w; w += 16384 * 2;
    ushort* W2l  = (ushort*)w; w += 16384 * 2;
    float* nd1_0 = (float*)w; w += (size_t)MPAD * 16;
    float* nd1_1 = (float*)w; w += (size_t)MPAD * 16;
    float* nd2_0 = (float*)w; w += (size_t)MPAD * 16;
    float* nd2_1 = (float*)w; w += (size_t)MPAD * 16;
    int*   deg  = (int*)w;   w += (size_t)2 * N * 4;
    float* dinv = (float*)w; w += (size_t)2 * N * 4;
    int*   off  = (int*)w;   w += (size_t)2 * N * 4;
    int*   idxb = (int*)w;   w += (size_t)2 * NBUCK * SCAP * 4;
    unsigned int* stg = (unsigned int*)w; w += (size_t)2 * NBUCK * SCAP * 4;
    int*   bcnt = (int*)w;   w += 2 * NBUCK * 4;
    float* acc  = (float*)w; w += 64;

    int nbE = (E + EPB - 1) / EPB;
    int nbB = (N + NPB - 1) / NPB;
    int gMM = MPAD / 128;
    int gAG = MPAD / 8;   // 8 dsts per block (2 per wave)

    init_k<<<131, 256, 0, stream>>>(Wl[0], Wl[1], W1h, W1l, W2h, W2l, Tp0, Tp1, acc, bcnt);

    bin2_k<<<2 * nbE, 256, 0, stream>>>(adj[0], adj[1], bcnt, stg, E, nbE);
    csr_k<<<2 * nbB, 256, 0, stream>>>(stg, bcnt, deg, dinv, off, idxb, N, nbB);

    // layer 1 (both domains merged per stage)
    mm_k<true><<<2 * gMM, 256, 0, stream>>>(feats[0], feats[1], nullptr, nullptr,
                                            W1h, W1l, dinv, Tp0, Tp1, N, gMM);
    aggregate_k<true><<<2 * gAG, 256, 0, stream>>>(Tp0, Tp1, idxb, off, deg, dinv, bl[0],
                                                   Wp, Wdu, Wdi, 0, nd1_0, nd1_1, Fhi0, Fhi1, N, gAG);
    // layer 2
    mm_k<false><<<2 * gMM, 256, 0, stream>>>(nullptr, nullptr, Fhi0, Fhi1,
                                             W2h, W2l, dinv, Tp0, Tp1, N, gMM);
    aggregate_k<false><<<2 * gAG, 256, 0, stream>>>(Tp0, Tp1, idxb, off, deg, dinv, bl[1],
                                                    Wp, Wdu, Wdi, 128, nd2_0, nd2_1, nullptr, nullptr, N, gAG);

    loss_k<<<256, 256, 0, stream>>>((const float4*)nd1_0, (const float4*)nd1_1,
                                    (const float4*)nd2_0, (const float4*)nd2_1,
                                    user[0], user[1], item[0], item[1], labels[0], labels[1],
                                    bp, bdu, bdi, acc, B, 128);
    fin_k<<<1, 1, 0, stream>>>(acc, (float*)d_out, B);
}

// Round 15
// 326.488 us; speedup vs baseline: 3.0012x; 1.0259x over previous
//
#include <hip/hip_runtime.h>

#define N_NODES 110000
#define NUM_USER 60000
#define MPAD 110080        // N_NODES padded to 128-row GEMM tiles
#define ZROW N_NODES       // dedicated all-zero row (rows N..MPAD-1 zeroed in init)
#define BSHIFT 9           // bucket = dst >> 9  (512 nodes per bucket)
#define NBUCK 256
#define NPB 512            // nodes per bucket
#define EPB 8192           // edges per block in bin
#define SCAP 9216          // fixed per-bucket capacity (mean 7447, sigma 86 -> +20 sigma)

typedef __attribute__((ext_vector_type(8))) __bf16 bf16x8;
typedef __attribute__((ext_vector_type(4))) float f32x4;
typedef __attribute__((ext_vector_type(2))) float f32x2;
typedef __attribute__((ext_vector_type(4))) unsigned int uint4v;

union UB { uint4v u; bf16x8 b; };

__device__ __forceinline__ unsigned short f2b(float f) {   // f32 -> bf16 RNE
    unsigned int u = __float_as_uint(f);
    unsigned int r = (u + 0x7FFFu + ((u >> 16) & 1u)) >> 16;
    return (unsigned short)r;
}
__device__ __forceinline__ float b2f(unsigned short h) {
    return __uint_as_float(((unsigned int)h) << 16);
}
// f32 -> fp8 e4m3 (OCP) RNE via exact 2^-120 scaling trick (handles subnormals)
__device__ __forceinline__ unsigned f2e4m3(float x) {
    unsigned u = __float_as_uint(x * 0x1p-120f);
    unsigned r = u + 0x7FFFFu + ((u >> 20) & 1u);
    return ((r >> 20) & 0x7Fu) | ((u >> 24) & 0x80u);
}
__device__ __forceinline__ float e4m3f(unsigned v) {   // fallback decode
    unsigned bits = ((v & 0x80u) << 24) | ((v & 0x7Fu) << 20);
    return __uint_as_float(bits) * 0x1p+120f;
}

// ---------------- init: weight conv + pad-row zero + counters zero ----------------

__global__ __launch_bounds__(256) void init_k(const float* __restrict__ W1, const float* __restrict__ W2,
        ushort* __restrict__ W1h, ushort* __restrict__ W1l,
        ushort* __restrict__ W2h, ushort* __restrict__ W2l,
        unsigned char* __restrict__ Tp0, unsigned char* __restrict__ Tp1,
        float* __restrict__ acc, int* __restrict__ bcnt) {
    int b = blockIdx.x, tid = threadIdx.x;
    if (b < 128) {
        const float* W = (b < 64) ? W1 : W2;
        ushort* hi = (b < 64) ? W1h : W2h;
        ushort* lo = (b < 64) ? W1l : W2l;
        int i = (b & 63) * 256 + tid;   // 16384 total
        int k = i >> 7, n = i & 127;
        float w = W[i];
        ushort h = f2b(w);
        hi[(n << 7) | k] = h;
        lo[(n << 7) | k] = f2b(w - b2f(h));
    } else if (b < 130) {
        unsigned char* Tp = (b == 128) ? Tp0 : Tp1;
        for (int j = tid; j < (MPAD - N_NODES) * 128; j += 256)
            Tp[(size_t)N_NODES * 128 + j] = 0;
    } else {
        if (tid < 16) acc[tid] = 0.f;
        bcnt[tid] = 0;          // dom 0
        bcnt[256 + tid] = 0;    // dom 1
    }
}

// ---------------- single-pass binning: LDS hist + atomic region grab + scatter ----------------

__global__ __launch_bounds__(256) void bin2_k(const int* __restrict__ adj0, const int* __restrict__ adj1,
        int* __restrict__ bcnt, unsigned int* __restrict__ stg, int E, int nbE) {
    __shared__ int h[NBUCK];
    __shared__ int lcur[NBUCK];
    int b = blockIdx.x, tid = threadIdx.x;
    int dom = b / nbE, blk = b - dom * nbE;
    const int* src = (dom ? adj1 : adj0);
    const int* dst = src + E;
    unsigned int* sg = stg + (size_t)dom * NBUCK * SCAP;
    h[tid] = 0;
    __syncthreads();
    int base = blk * EPB, end = min(base + EPB, E);
    for (int i = base + tid * 4; i + 3 < end; i += 1024) {
        int4 d = *(const int4*)&dst[i];
        atomicAdd(&h[d.x >> BSHIFT], 1); atomicAdd(&h[d.y >> BSHIFT], 1);
        atomicAdd(&h[d.z >> BSHIFT], 1); atomicAdd(&h[d.w >> BSHIFT], 1);
    }
    __syncthreads();
    lcur[tid] = tid * SCAP + atomicAdd(&bcnt[dom * NBUCK + tid], h[tid]);
    __syncthreads();
    for (int i = base + tid * 4; i + 3 < end; i += 1024) {
        int4 s = *(const int4*)&src[i];
        int4 d = *(const int4*)&dst[i];
        int p;
        p = atomicAdd(&lcur[d.x >> BSHIFT], 1); sg[p] = (unsigned)s.x | ((unsigned)(d.x & (NPB - 1)) << 17);
        p = atomicAdd(&lcur[d.y >> BSHIFT], 1); sg[p] = (unsigned)s.y | ((unsigned)(d.y & (NPB - 1)) << 17);
        p = atomicAdd(&lcur[d.z >> BSHIFT], 1); sg[p] = (unsigned)s.z | ((unsigned)(d.z & (NPB - 1)) << 17);
        p = atomicAdd(&lcur[d.w >> BSHIFT], 1); sg[p] = (unsigned)s.w | ((unsigned)(d.w & (NPB - 1)) << 17);
    }
}

__global__ __launch_bounds__(256) void csr_k(const unsigned int* __restrict__ stg,
        const int* __restrict__ bcnt,
        int* __restrict__ deg, float* __restrict__ dinv, int* __restrict__ off,
        int* __restrict__ idxb, int N, int nbB) {
    __shared__ int ldeg[NPB];
    __shared__ int lcur[NPB];
    __shared__ int shp[256];
    __shared__ unsigned int lidx[SCAP];
    int b = blockIdx.x, tid = threadIdx.x;
    int dom = b / nbB, blk = b - dom * nbB;
    const unsigned int* sg = stg + ((size_t)dom * NBUCK + blk) * SCAP;
    int* degd = deg + (size_t)dom * N_NODES;
    float* dinvd = dinv + (size_t)dom * N_NODES;
    int* offd = off + (size_t)dom * N_NODES;
    int* idxd = idxb + (size_t)dom * NBUCK * SCAP;
    int node0 = blk * NPB;
    int base = blk * SCAP;                       // within-dom padded offset
    int cnt = bcnt[dom * NBUCK + blk];
    ldeg[tid] = 0; ldeg[tid + 256] = 0;
    __syncthreads();
    for (int i = tid; i < cnt; i += 256)
        atomicAdd(&ldeg[sg[i] >> 17], 1);
    __syncthreads();
    int a0 = ldeg[2 * tid], a1 = ldeg[2 * tid + 1];
    shp[tid] = a0 + a1;
    __syncthreads();
    for (int o = 1; o < 256; o <<= 1) {
        int v = (tid >= o) ? shp[tid - o] : 0;
        __syncthreads();
        shp[tid] += v;
        __syncthreads();
    }
    int excl = shp[tid] - a0 - a1;
    lcur[2 * tid] = excl;
    lcur[2 * tid + 1] = excl + a0;
    int n0 = node0 + 2 * tid;
    if (n0 < N)     { degd[n0] = a0;     dinvd[n0] = rsqrtf(a0 + 1.f);     offd[n0] = base + excl; }
    if (n0 + 1 < N) { degd[n0 + 1] = a1; dinvd[n0 + 1] = rsqrtf(a1 + 1.f); offd[n0 + 1] = base + excl + a0; }
    __syncthreads();
    for (int i = tid; i < cnt; i += 256) {
        unsigned e = sg[i];
        int p = atomicAdd(&lcur[e >> 17], 1);
        if (p < SCAP) lidx[p] = e & 0x1FFFFu;
    }
    __syncthreads();
    for (int i = tid; i < cnt; i += 256)
        idxd[base + i] = (int)lidx[i];
}

// ---------------- GEMM (merged doms): T'(fp8) = dinv[row]*(A@W), LDS-staged W, 2 strips/wave --

template<bool F32A>
__global__ __launch_bounds__(256) void mm_k(const float* __restrict__ Xf0, const float* __restrict__ Xf1,
        const ushort* __restrict__ Xhi0, const ushort* __restrict__ Xhi1,
        const ushort* __restrict__ Whi, const ushort* __restrict__ Wlo,   // [n][k]
        const float* __restrict__ dinv2, unsigned char* __restrict__ Tp0, unsigned char* __restrict__ Tp1,
        int M, int gHalf) {
    __shared__ ushort ldsW[2][1024 * 8];   // [hi/lo][1024 frags x 8 ushorts] = 32 KB
    int bid = blockIdx.x;
    int dom = bid >= gHalf;
    bid -= dom * gHalf;
    const float* Xf = dom ? Xf1 : Xf0;
    const ushort* Xhi = dom ? Xhi1 : Xhi0;
    const float* dinv = dinv2 + (size_t)dom * N_NODES;
    unsigned char* Tp = dom ? Tp1 : Tp0;
    int tid = threadIdx.x;
    int wid = tid >> 6, lane = tid & 63;
    int l15 = lane & 15;
    int kg = (lane >> 4) * 8;
    int row0 = bid * 128 + wid * 32;   // wave: rows row0..row0+31 (strips at +0, +16)
    int rA0 = row0 + l15;
    int rA1 = row0 + 16 + l15;
    f32x4 acc[2][8] = {};
    #pragma unroll
    for (int ph = 0; ph < 2; ph++) {
        if (ph) __syncthreads();   // protect LDS before overwrite
        #pragma unroll
        for (int i = 0; i < 8; i++) {
            int arr = i >> 2;
            int f = tid + (i & 3) * 256;            // 0..1023
            int l = f & 63;
            int nr = ((f >> 6) & 7) * 16 + (l & 15);
            int kc = (2 * ph + (f >> 9)) * 32 + (l >> 4) * 8;
            const ushort* srcp = (arr ? Wlo : Whi) + nr * 128 + kc;
            *(uint4v*)&ldsW[arr][(size_t)f * 8] = *(const uint4v*)srcp;
        }
        __syncthreads();
        #pragma unroll
        for (int gg = 0; gg < 2; gg++) {
            int g = 2 * ph + gg;
            int k0 = g * 32 + kg;
            UB a0hi, a0lo, a1hi, a1lo;
            if (F32A) {
                #pragma unroll
                for (int s = 0; s < 2; s++) {
                    int rA = s ? rA1 : rA0;
                    float4 f0 = make_float4(0.f, 0.f, 0.f, 0.f), f1 = f0;
                    if (rA < M) {
                        f0 = *(const float4*)&Xf[(size_t)rA * 128 + k0];
                        f1 = *(const float4*)&Xf[(size_t)rA * 128 + k0 + 4];
                    }
                    float fv[8] = {f0.x, f0.y, f0.z, f0.w, f1.x, f1.y, f1.z, f1.w};
                    ushort h[8], l[8];
                    #pragma unroll
                    for (int j = 0; j < 8; j++) { h[j] = f2b(fv[j]); l[j] = f2b(fv[j] - b2f(h[j])); }
                    uint4v hu = uint4v{(uint)h[0] | ((uint)h[1] << 16), (uint)h[2] | ((uint)h[3] << 16),
                                       (uint)h[4] | ((uint)h[5] << 16), (uint)h[6] | ((uint)h[7] << 16)};
                    uint4v lu = uint4v{(uint)l[0] | ((uint)l[1] << 16), (uint)l[2] | ((uint)l[3] << 16),
                                       (uint)l[4] | ((uint)l[5] << 16), (uint)l[6] | ((uint)l[7] << 16)};
                    if (s) { a1hi.u = hu; a1lo.u = lu; } else { a0hi.u = hu; a0lo.u = lu; }
                }
            } else {
                a0hi.u = *(const uint4v*)&Xhi[(size_t)rA0 * 128 + k0];
                a1hi.u = *(const uint4v*)&Xhi[(size_t)rA1 * 128 + k0];
            }
            #pragma unroll
            for (int n = 0; n < 8; n++) {
                int fbase = ((gg * 8 + n) * 64 + lane) * 8;
                UB bhi, blo;
                bhi.u = *(const uint4v*)&ldsW[0][fbase];
                blo.u = *(const uint4v*)&ldsW[1][fbase];
                acc[0][n] = __builtin_amdgcn_mfma_f32_16x16x32_bf16(a0hi.b, bhi.b, acc[0][n], 0, 0, 0);
                acc[0][n] = __builtin_amdgcn_mfma_f32_16x16x32_bf16(a0hi.b, blo.b, acc[0][n], 0, 0, 0);
                if (F32A)
                    acc[0][n] = __builtin_amdgcn_mfma_f32_16x16x32_bf16(a0lo.b, bhi.b, acc[0][n], 0, 0, 0);
                acc[1][n] = __builtin_amdgcn_mfma_f32_16x16x32_bf16(a1hi.b, bhi.b, acc[1][n], 0, 0, 0);
                acc[1][n] = __builtin_amdgcn_mfma_f32_16x16x32_bf16(a1hi.b, blo.b, acc[1][n], 0, 0, 0);
                if (F32A)
                    acc[1][n] = __builtin_amdgcn_mfma_f32_16x16x32_bf16(a1lo.b, bhi.b, acc[1][n], 0, 0, 0);
            }
        }
    }
    #pragma unroll
    for (int s = 0; s < 2; s++) {
        int rbase = row0 + s * 16 + (lane >> 4) * 4;
        #pragma unroll
        for (int r = 0; r < 4; r++) {
            int row = rbase + r;
            if (row < M) {
                float dv = dinv[row];
                #pragma unroll
                for (int n = 0; n < 8; n++)
                    Tp[(size_t)row * 128 + n * 16 + l15] = (unsigned char)f2e4m3(dv * acc[s][n][r]);
            }
        }
    }
}

// ---------------- aggregate (merged doms): 2 dsts/wave, self-loop peeled ----------
// Wave: lanes 0-31 -> dst A, lanes 32-63 -> dst B. Per half: 2 groups of 16 lanes, each group
// one edge in flight; lane li owns 8 fp8 dims. Self row added by group 0 before the loop.

template<bool STORE_F>
__global__ __launch_bounds__(256) void aggregate_k(
        const unsigned char* __restrict__ Tp0, const unsigned char* __restrict__ Tp1,
        const int* __restrict__ idxb, const int* __restrict__ off, const int* __restrict__ deg,
        const float* __restrict__ dinv2, const float* __restrict__ bias,
        const float* __restrict__ Wp, const float* __restrict__ Wdu, const float* __restrict__ Wdi,
        int loff, float* __restrict__ nd0, float* __restrict__ nd1,
        ushort* __restrict__ ohi0, ushort* __restrict__ ohi1, int N, int gHalf) {
    int bid = blockIdx.x;
    int dom = bid >= gHalf;
    bid -= dom * gHalf;
    const unsigned char* Tp = dom ? Tp1 : Tp0;
    const int* idxd = idxb + (size_t)dom * NBUCK * SCAP;
    const int* offd = off + (size_t)dom * N_NODES;
    const int* degd = deg + (size_t)dom * N_NODES;
    const float* dinv = dinv2 + (size_t)dom * N_NODES;
    float* nd = dom ? nd1 : nd0;
    ushort* ohi = dom ? ohi1 : ohi0;

    int w = threadIdx.x >> 6, lane = threadIdx.x & 63;
    int half = lane >> 5;              // 0: dst A, 1: dst B
    int grp = (lane >> 4) & 1;         // group within half
    int li = lane & 15;
    int d = bid * 8 + w * 2 + half;
    int db = li * 8;                   // first dim this lane owns
    bool valid = d < N;
    int o = 0, dg = 0;
    if (valid) { o = offd[d]; dg = degd[d]; }   // dg edges (self handled separately)
    int dmax = max(dg, __shfl_xor(dg, 32));
    if (!valid) {
        if (STORE_F && grp == 0) *(uint4*)&ohi[(size_t)d * 128 + db] = make_uint4(0, 0, 0, 0);
        return;
    }
    f32x2 A0 = {0.f, 0.f}, A1 = {0.f, 0.f}, A2 = {0.f, 0.f}, A3 = {0.f, 0.f};
    unsigned laneoff = (unsigned)(li << 3);
    // self row: group 0 only (RED1 sums both groups)
    {
        int id = grp ? ZROW : d;
        uint2 u = *(const uint2*)(Tp + (((unsigned)id << 7) | laneoff));
#if __has_builtin(__builtin_amdgcn_cvt_pk_f32_fp8)
        A0 += __builtin_amdgcn_cvt_pk_f32_fp8(u.x, false);
        A1 += __builtin_amdgcn_cvt_pk_f32_fp8(u.x, true);
        A2 += __builtin_amdgcn_cvt_pk_f32_fp8(u.y, false);
        A3 += __builtin_amdgcn_cvt_pk_f32_fp8(u.y, true);
#else
        A0 += f32x2{e4m3f(u.x & 0xFF),         e4m3f((u.x >> 8) & 0xFF)};
        A1 += f32x2{e4m3f((u.x >> 16) & 0xFF), e4m3f(u.x >> 24)};
        A2 += f32x2{e4m3f(u.y & 0xFF),         e4m3f((u.y >> 8) & 0xFF)};
        A3 += f32x2{e4m3f((u.y >> 16) & 0xFF), e4m3f(u.y >> 24)};
#endif
    }
    int ob = o + grp;   // edge e = c + jj*2 + grp -> idxd[ob + c + jj*2]
    for (int c = 0; c < dmax; c += 32) {
        int m = min(32, dmax - c);
        #pragma unroll 4
        for (int jj = 0; jj * 2 < m; jj++) {
            int e = c + jj * 2 + grp;
            int iv = idxd[ob + c + jj * 2];          // same addr across 16 lanes -> broadcast
            int id = (e < dg) ? iv : ZROW;
            uint2 u = *(const uint2*)(Tp + (((unsigned)id << 7) | laneoff));
#if __has_builtin(__builtin_amdgcn_cvt_pk_f32_fp8)
            A0 += __builtin_amdgcn_cvt_pk_f32_fp8(u.x, false);
            A1 += __builtin_amdgcn_cvt_pk_f32_fp8(u.x, true);
            A2 += __builtin_amdgcn_cvt_pk_f32_fp8(u.y, false);
            A3 += __builtin_amdgcn_cvt_pk_f32_fp8(u.y, true);
#else
            A0 += f32x2{e4m3f(u.x & 0xFF),         e4m3f((u.x >> 8) & 0xFF)};
            A1 += f32x2{e4m3f((u.x >> 16) & 0xFF), e4m3f(u.x >> 24)};
            A2 += f32x2{e4m3f(u.y & 0xFF),         e4m3f((u.y >> 8) & 0xFF)};
            A3 += f32x2{e4m3f((u.y >> 16) & 0xFF), e4m3f(u.y >> 24)};
#endif
        }
    }
    float a0 = A0[0], a1 = A0[1], a2 = A1[0], a3 = A1[1];
    float a4 = A2[0], a5 = A2[1], a6 = A3[0], a7 = A3[1];
    // reduce across the 2 groups of this half (xor16 stays within the half)
    #define RED1(x) { x += __shfl_xor(x, 16); }
    RED1(a0) RED1(a1) RED1(a2) RED1(a3) RED1(a4) RED1(a5) RED1(a6) RED1(a7)
    #undef RED1
    float di = dinv[d];
    float4 b0 = *(const float4*)&bias[db];
    float4 b1 = *(const float4*)&bias[db + 4];
    float f0 = fmaxf(di * a0 + b0.x, 0.f);
    float f1 = fmaxf(di * a1 + b0.y, 0.f);
    float f2 = fmaxf(di * a2 + b0.z, 0.f);
    float f3 = fmaxf(di * a3 + b0.w, 0.f);
    float f4 = fmaxf(di * a4 + b1.x, 0.f);
    float f5 = fmaxf(di * a5 + b1.y, 0.f);
    float f6 = fmaxf(di * a6 + b1.z, 0.f);
    float f7 = fmaxf(di * a7 + b1.w, 0.f);
    if (STORE_F && grp == 0) {
        ushort h0 = f2b(f0), h1 = f2b(f1), h2 = f2b(f2), h3 = f2b(f3);
        ushort h4 = f2b(f4), h5 = f2b(f5), h6 = f2b(f6), h7 = f2b(f7);
        uint4 hv = make_uint4((uint)h0 | ((uint)h1 << 16), (uint)h2 | ((uint)h3 << 16),
                              (uint)h4 | ((uint)h5 << 16), (uint)h6 | ((uint)h7 << 16));
        *(uint4*)&ohi[(size_t)d * 128 + db] = hv;
    }
    // head dots: group 0 -> {Wp_user, Wp_item}; group 1 -> {Wdu, Wdi}
    const float* ws0 = grp ? Wdu + loff : Wp + loff;
    const float* ws1 = grp ? Wdi + loff : Wp + 256 + loff;
    float4 w00 = *(const float4*)&ws0[db];
    float4 w01 = *(const float4*)&ws0[db + 4];
    float4 w10 = *(const float4*)&ws1[db];
    float4 w11 = *(const float4*)&ws1[db + 4];
    float dt0 = f0 * w00.x + f1 * w00.y + f2 * w00.z + f3 * w00.w
              + f4 * w01.x + f5 * w01.y + f6 * w01.z + f7 * w01.w;
    float dt1 = f0 * w10.x + f1 * w10.y + f2 * w10.z + f3 * w10.w
              + f4 * w11.x + f5 * w11.y + f6 * w11.z + f7 * w11.w;
    dt0 += __shfl_xor(dt0, 1); dt1 += __shfl_xor(dt1, 1);
    dt0 += __shfl_xor(dt0, 2); dt1 += __shfl_xor(dt1, 2);
    dt0 += __shfl_xor(dt0, 4); dt1 += __shfl_xor(dt1, 4);
    dt0 += __shfl_xor(dt0, 8); dt1 += __shfl_xor(dt1, 8);
    if (li == 0) *(float2*)&nd[(size_t)d * 4 + grp * 2] = make_float2(dt0, dt1);
}

// ---------------- loss (merged doms) ----------------

__device__ __forceinline__ float sp100(float z) {   // min(softplus(z),100)
    float sp = (z > 0.f) ? (z + log1pf(expf(-z))) : log1pf(expf(z));
    return fminf(sp, 100.f);
}
__device__ __forceinline__ float wred64(float x) {
    #pragma unroll
    for (int o = 32; o > 0; o >>= 1) x += __shfl_xor(x, o);
    return x;
}

__global__ __launch_bounds__(256) void loss_k(
        const float4* __restrict__ nd1_0, const float4* __restrict__ nd1_1,
        const float4* __restrict__ nd2_0, const float4* __restrict__ nd2_1,
        const int* __restrict__ user0, const int* __restrict__ user1,
        const int* __restrict__ item0, const int* __restrict__ item1,
        const int* __restrict__ lab0, const int* __restrict__ lab1,
        const float* __restrict__ bp, const float* __restrict__ bdu, const float* __restrict__ bdi,
        float* __restrict__ acc, int B, int gHalf) {
    __shared__ float sh[3][4];
    int bid = blockIdx.x;
    int dom = bid >= gHalf;
    bid -= dom * gHalf;
    const float4* nd1 = dom ? nd1_1 : nd1_0;
    const float4* nd2 = dom ? nd2_1 : nd2_0;
    const int* user = dom ? user1 : user0;
    const int* item = dom ? item1 : item0;
    const int* labels = dom ? lab1 : lab0;
    int gtid = bid * blockDim.x + threadIdx.x;
    int nth = gHalf * blockDim.x;
    float bpv = bp[0], bduv = bdu[0], bdiv = bdi[0];
    float lp = 0.f, lu = 0.f, li = 0.f;
    for (int s = gtid; s < B; s += nth) {
        int u = user[s];
        int it = item[s] + NUM_USER;
        float4 a = nd1[u], b = nd2[u], c = nd1[it], dd = nd2[it];
        float zp = a.x + b.x + c.y + dd.y + bpv;
        float zu = a.z + b.z + bduv;
        float zi = c.w + dd.w + bdiv;
        lp += labels[s] ? sp100(-zp) : sp100(zp);
        lu += dom ? sp100(-zu) : sp100(zu);
        li += dom ? sp100(-zi) : sp100(zi);
    }
    lp = wred64(lp); lu = wred64(lu); li = wred64(li);
    int lane = threadIdx.x & 63, w = threadIdx.x >> 6;
    if (lane == 0) { sh[0][w] = lp; sh[1][w] = lu; sh[2][w] = li; }
    __syncthreads();
    if (threadIdx.x == 0) {
        float s0 = 0.f, s1 = 0.f, s2 = 0.f;
        for (int j = 0; j < 4; j++) { s0 += sh[0][j]; s1 += sh[1][j]; s2 += sh[2][j]; }
        atomicAdd(&acc[dom], s0);
        atomicAdd(&acc[2], s1);
        atomicAdd(&acc[3], s2);
    }
}

__global__ void fin_k(const float* __restrict__ acc, float* __restrict__ out, int B) {
    float invB = 1.f / (float)B;
    out[0] = acc[0] * invB + acc[1] * invB + 0.1f * ((acc[2] + acc[3]) * (0.5f * invB));
}

// ---------------- orchestration ----------------

extern "C" void kernel_launch(void* const* d_in, const int* in_sizes, int n_in,
                              void* d_out, int out_size, void* d_ws, size_t ws_size,
                              hipStream_t stream) {
    const float* feats[2] = {(const float*)d_in[0], (const float*)d_in[1]};
    const int* adj[2]    = {(const int*)d_in[2], (const int*)d_in[3]};
    const int* user[2]   = {(const int*)d_in[4], (const int*)d_in[7]};
    const int* item[2]   = {(const int*)d_in[5], (const int*)d_in[8]};
    const int* labels[2] = {(const int*)d_in[6], (const int*)d_in[9]};
    const float* Wl[2] = {(const float*)d_in[10], (const float*)d_in[12]};
    const float* bl[2] = {(const float*)d_in[11], (const float*)d_in[13]};
    const float* Wp  = (const float*)d_in[14];
    const float* bp  = (const float*)d_in[15];
    const float* Wdu = (const float*)d_in[16];
    const float* bdu = (const float*)d_in[17];
    const float* Wdi = (const float*)d_in[18];
    const float* bdi = (const float*)d_in[19];

    const int E = in_sizes[2] / 2;
    const int B = in_sizes[4];
    const int N = N_NODES;

    char* w = (char*)d_ws;
    unsigned char* Tp0 = (unsigned char*)w; w += (size_t)MPAD * 128;
    unsigned char* Tp1 = (unsigned char*)w; w += (size_t)MPAD * 128;
    ushort* Fhi0 = (ushort*)w; w += (size_t)MPAD * 128 * 2;
    ushort* Fhi1 = (ushort*)w; w += (size_t)MPAD * 128 * 2;
    ushort* W1h  = (ushort*)w; w += 16384 * 2;
    ushort* W1l  = (ushort*)w; w += 16384 * 2;
    ushort* W2h  = (ushort*)w; w += 16384 * 2;
    ushort* W2l  = (ushort*)w; w += 16384 * 2;
    float* nd1_0 = (float*)w; w += (size_t)MPAD * 16;
    float* nd1_1 = (float*)w; w += (size_t)MPAD * 16;
    float* nd2_0 = (float*)w; w += (size_t)MPAD * 16;
    float* nd2_1 = (float*)w; w += (size_t)MPAD * 16;
    int*   deg  = (int*)w;   w += (size_t)2 * N * 4;
    float* dinv = (float*)w; w += (size_t)2 * N * 4;
    int*   off  = (int*)w;   w += (size_t)2 * N * 4;
    int*   idxb = (int*)w;   w += (size_t)2 * NBUCK * SCAP * 4;
    unsigned int* stg = (unsigned int*)w; w += (size_t)2 * NBUCK * SCAP * 4;
    int*   bcnt = (int*)w;   w += 2 * NBUCK * 4;
    float* acc  = (float*)w; w += 64;

    int nbE = (E + EPB - 1) / EPB;
    int nbB = (N + NPB - 1) / NPB;
    int gMM = MPAD / 128;
    int gAG = MPAD / 8;   // 8 dsts per block (2 per wave)

    init_k<<<131, 256, 0, stream>>>(Wl[0], Wl[1], W1h, W1l, W2h, W2l, Tp0, Tp1, acc, bcnt);

    bin2_k<<<2 * nbE, 256, 0, stream>>>(adj[0], adj[1], bcnt, stg, E, nbE);
    csr_k<<<2 * nbB, 256, 0, stream>>>(stg, bcnt, deg, dinv, off, idxb, N, nbB);

    // layer 1 (both domains merged per stage)
    mm_k<true><<<2 * gMM, 256, 0, stream>>>(feats[0], feats[1], nullptr, nullptr,
                                            W1h, W1l, dinv, Tp0, Tp1, N, gMM);
    aggregate_k<true><<<2 * gAG, 256, 0, stream>>>(Tp0, Tp1, idxb, off, deg, dinv, bl[0],
                                                   Wp, Wdu, Wdi, 0, nd1_0, nd1_1, Fhi0, Fhi1, N, gAG);
    // layer 2
    mm_k<false><<<2 * gMM, 256, 0, stream>>>(nullptr, nullptr, Fhi0, Fhi1,
                                             W2h, W2l, dinv, Tp0, Tp1, N, gMM);
    aggregate_k<false><<<2 * gAG, 256, 0, stream>>>(Tp0, Tp1, idxb, off, deg, dinv, bl[1],
                                                    Wp, Wdu, Wdi, 128, nd2_0, nd2_1, nullptr, nullptr, N, gAG);

    loss_k<<<256, 256, 0, stream>>>((const float4*)nd1_0, (const float4*)nd1_1,
                                    (const float4*)nd2_0, (const float4*)nd2_1,
                                    user[0], user[1], item[0], item[1], labels[0], labels[1],
                                    bp, bdu, bdi, acc, B, 128);
    fin_k<<<1, 1, 0, stream>>>(acc, (float*)d_out, B);
}